// Round 1
// baseline (25561.987 us; speedup 1.0000x reference)
//
#include <hip/hip_runtime.h>
#include <hip/hip_bf16.h>
#include <math.h>

// ---------------------------------------------------------------------------
// EEGMamba forward, fp32 correctness-first implementation.
// Model dims
#define D_MODEL   200
#define N_LAYER   12
#define NHEADS    8
#define HEADDIM   50
#define D_STATE   64
#define D_INNER   400          // 2*D_MODEL
#define CONV_DIM  528          // D_INNER + 2*D_STATE
#define D_IN_PROJ 936          // 2*D_INNER + 2*D_STATE + NHEADS
#define D_CONV    4
#define EPS       1e-5f

#define BATCH 16
#define CH    19
#define LLEN  30
#define SEQ   570              // CH*LLEN
#define NTOK  9120             // BATCH*SEQ
#define NFREQ 101

// ---------------------------------------------------------------------------
// Generic fp32 GEMM:  C[M,N] = A[M,K] @ W[N,K]^T  (+ bias[n]) (+ C if accum)
// A row-major MxK, W row-major NxK (i.e. "W.T" matmul as in ref x @ w.T)
// 128x128 tile, 8x8 micro-tile, BK=16, 256 threads.
__global__ __launch_bounds__(256) void gemm_nt(
    const float* __restrict__ A, const float* __restrict__ W,
    const float* __restrict__ bias, float* __restrict__ C,
    int M, int N, int K, int accum)
{
    const int BM = 128, BN = 128, BK = 16;
    __shared__ float As[16][BM + 4];
    __shared__ float Ws[16][BN + 4];

    int bm = blockIdx.y * BM;
    int bn = blockIdx.x * BN;
    int tid = threadIdx.x;
    int lr = tid >> 1;            // 0..127 row of tile
    int lc = (tid & 1) * 8;       // 0 or 8 (k offset)
    int tx = tid & 15;            // 16 thread cols
    int ty = tid >> 4;            // 16 thread rows

    float acc[8][8];
#pragma unroll
    for (int i = 0; i < 8; i++)
#pragma unroll
        for (int j = 0; j < 8; j++) acc[i][j] = 0.f;

    for (int k0 = 0; k0 < K; k0 += BK) {
        // stage A tile (transposed into [k][m]) and W tile ([k][n])
#pragma unroll
        for (int i = 0; i < 8; i++) {
            int gr = bm + lr, gk = k0 + lc + i;
            As[lc + i][lr] = (gr < M && gk < K) ? A[(size_t)gr * K + gk] : 0.f;
        }
#pragma unroll
        for (int i = 0; i < 8; i++) {
            int gr = bn + lr, gk = k0 + lc + i;
            Ws[lc + i][lr] = (gr < N && gk < K) ? W[(size_t)gr * K + gk] : 0.f;
        }
        __syncthreads();
#pragma unroll
        for (int kk = 0; kk < BK; kk++) {
            float a[8], bv[8];
#pragma unroll
            for (int i = 0; i < 8; i++) a[i] = As[kk][ty * 8 + i];
#pragma unroll
            for (int j = 0; j < 8; j++) bv[j] = Ws[kk][tx * 8 + j];
#pragma unroll
            for (int i = 0; i < 8; i++)
#pragma unroll
                for (int j = 0; j < 8; j++)
                    acc[i][j] = fmaf(a[i], bv[j], acc[i][j]);
        }
        __syncthreads();
    }

#pragma unroll
    for (int i = 0; i < 8; i++) {
        int gm = bm + ty * 8 + i;
        if (gm >= M) continue;
#pragma unroll
        for (int j = 0; j < 8; j++) {
            int gn = bn + tx * 8 + j;
            if (gn >= N) continue;
            float v = acc[i][j];
            if (bias) v += bias[gn];
            if (accum) v += C[(size_t)gm * N + gn];
            C[(size_t)gm * N + gn] = v;
        }
    }
}

// ---------------------------------------------------------------------------
// patch embed: time conv  (16,1,570,200) * (25,1,1,49) stride(1,25) pad(0,24)
// -> traw[b][oc][row][j]   (16,25,570,8)
__global__ __launch_bounds__(256) void time_conv_kernel(
    const float* __restrict__ x, const float* __restrict__ pw,
    float* __restrict__ traw)
{
    int br = blockIdx.x;  // b*570+row
    __shared__ float xr[200];
    if (threadIdx.x < 200) xr[threadIdx.x] = x[(size_t)br * 200 + threadIdx.x];
    __syncthreads();
    if (threadIdx.x < 200) {
        int oc = threadIdx.x >> 3, j = threadIdx.x & 7;
        int start = j * 25 - 24;
        float acc = 0.f;
#pragma unroll
        for (int k = 0; k < 49; k++) {
            int d = start + k;
            if (d >= 0 && d < 200) acc = fmaf(xr[d], pw[oc * 49 + k], acc);
        }
        int b = br / SEQ, row = br % SEQ;
        traw[(((size_t)b * 25 + oc) * SEQ + row) * 8 + j] = acc;
    }
}

// groupnorm stats per (b, group): 5 channels x 570 x 8 = 22800 contiguous
__global__ __launch_bounds__(256) void gn_stats_kernel(
    const float* __restrict__ traw, float* __restrict__ stats)
{
    int bg = blockIdx.x;          // b*5+g
    int b = bg / 5, g = bg % 5;
    const float* base = traw + ((size_t)b * 25 + g * 5) * SEQ * 8;
    float s = 0.f, q = 0.f;
    for (int i = threadIdx.x; i < 5 * SEQ * 8; i += 256) {
        float v = base[i];
        s += v; q = fmaf(v, v, q);
    }
    __shared__ float rs[4], rq[4];
    int lane = threadIdx.x & 63, w = threadIdx.x >> 6;
#pragma unroll
    for (int o = 32; o; o >>= 1) { s += __shfl_xor(s, o, 64); q += __shfl_xor(q, o, 64); }
    if (lane == 0) { rs[w] = s; rq[w] = q; }
    __syncthreads();
    if (threadIdx.x == 0) {
        float S = rs[0] + rs[1] + rs[2] + rs[3];
        float Q = rq[0] + rq[1] + rq[2] + rq[3];
        float inv = 1.f / (5.f * SEQ * 8.f);
        float mean = S * inv;
        float var = Q * inv - mean * mean;
        stats[bg * 2] = mean;
        stats[bg * 2 + 1] = rsqrtf(var + EPS);
    }
}

// apply groupnorm + exact GELU, scatter into patch (b,c,l,d) layout
__global__ __launch_bounds__(256) void gn_gelu_kernel(
    const float* __restrict__ traw, const float* __restrict__ stats,
    const float* __restrict__ gn_g, const float* __restrict__ gn_b,
    float* __restrict__ patch)
{
    int idx = blockIdx.x * 256 + threadIdx.x;
    if (idx >= NTOK * 200) return;
    int d = idx % 200;
    int row = (idx / 200) % SEQ;
    int b = idx / (200 * SEQ);
    int oc = d >> 3, j = d & 7;
    float v = traw[(((size_t)b * 25 + oc) * SEQ + row) * 8 + j];
    int g = oc / 5;
    float mean = stats[(b * 5 + g) * 2];
    float rstd = stats[(b * 5 + g) * 2 + 1];
    v = (v - mean) * rstd * gn_g[oc] + gn_b[oc];
    float ge = 0.5f * v * (1.f + erff(v * 0.70710678118654752f));
    patch[idx] = ge;
}

// build stacked DFT matrix: rows 0..100 cos, 101..201 sin (202 x 200)
__global__ __launch_bounds__(256) void dft_init_kernel(float* __restrict__ CS)
{
    int idx = blockIdx.x * 256 + threadIdx.x;
    if (idx >= 202 * 200) return;
    int f = idx / 200, d = idx % 200;
    int fr = (f < NFREQ) ? f : (f - NFREQ);
    int m = (fr * d) % 200;
    float ang = -6.283185307179586f * (float)m * (1.f / 200.f);
    CS[idx] = (f < NFREQ) ? cosf(ang) : sinf(ang);
}

// magnitude: |rfft| with forward norm (1/200)
__global__ __launch_bounds__(256) void mag_kernel(
    const float* __restrict__ cs_out, float* __restrict__ magv)
{
    int idx = blockIdx.x * 256 + threadIdx.x;
    if (idx >= NTOK * NFREQ) return;
    int m = idx / NFREQ, f = idx % NFREQ;
    float re = cs_out[(size_t)m * 202 + f];
    float im = cs_out[(size_t)m * 202 + NFREQ + f];
    magv[idx] = sqrtf(re * re + im * im) * 0.005f;
}

// depthwise 7x7 pos conv over (c=19,l=30) grid + residual add -> hidden
__global__ __launch_bounds__(256) void pe_conv_kernel(
    const float* __restrict__ patch, const float* __restrict__ pw,
    float* __restrict__ hidden)
{
    int idx = blockIdx.x * 256 + threadIdx.x;
    if (idx >= NTOK * 200) return;
    int d = idx % 200;
    int l = (idx / 200) % LLEN;
    int c = (idx / (200 * LLEN)) % CH;
    int b = idx / (200 * LLEN * CH);
    float acc = patch[idx];
    const float* w = pw + d * 49;
#pragma unroll
    for (int i = 0; i < 7; i++) {
        int cc = c + i - 3;
        if (cc < 0 || cc >= CH) continue;
#pragma unroll
        for (int j = 0; j < 7; j++) {
            int ll = l + j - 3;
            if (ll < 0 || ll >= LLEN) continue;
            acc = fmaf(patch[(((size_t)b * CH + cc) * LLEN + ll) * 200 + d], w[i * 7 + j], acc);
        }
    }
    hidden[idx] = acc;
}

// ---------------------------------------------------------------------------
// residual = hidden + (first ? 0 : residual);  u = rmsnorm(residual)*wn
// one wave per token, D=200
__global__ __launch_bounds__(64) void add_rmsnorm_kernel(
    const float* __restrict__ hidden, float* __restrict__ residual,
    const float* __restrict__ wn, float* __restrict__ u, int first)
{
    int m = blockIdx.x;
    int lane = threadIdx.x;
    const float* hr = hidden + (size_t)m * 200;
    float* rr = residual + (size_t)m * 200;
    float v[4];
    float ss = 0.f;
#pragma unroll
    for (int i = 0; i < 4; i++) {
        int k = lane + i * 64;
        float xv = 0.f;
        if (k < 200) {
            xv = hr[k] + (first ? 0.f : rr[k]);
            rr[k] = xv;
        }
        v[i] = xv;
        ss = fmaf(xv, xv, ss);
    }
#pragma unroll
    for (int o = 32; o; o >>= 1) ss += __shfl_xor(ss, o, 64);
    float rstd = rsqrtf(ss * (1.f / 200.f) + EPS);
#pragma unroll
    for (int i = 0; i < 4; i++) {
        int k = lane + i * 64;
        if (k < 200) u[(size_t)m * 200 + k] = v[i] * rstd * wn[k];
    }
}

// ---------------------------------------------------------------------------
// dt = softplus(zxbcdt[...,928:936]+dt_bias); xBC = silu(causal depthwise conv4)
__global__ __launch_bounds__(256) void dtconv_kernel(
    const float* __restrict__ zxbcdt, const float* __restrict__ cw,
    const float* __restrict__ cb, const float* __restrict__ dt_bias,
    float* __restrict__ xBC, float* __restrict__ dtb, int layer)
{
    int bt = blockIdx.x;          // b*570+t
    int b = bt / SEQ, t = bt % SEQ;
    const float* cwl = cw + (size_t)layer * CONV_DIM * 4;
    const float* cbl = cb + (size_t)layer * CONV_DIM;
    for (int ch = threadIdx.x; ch < CONV_DIM; ch += 256) {
        float acc = cbl[ch];
#pragma unroll
        for (int k = 0; k < 4; k++) {
            int tt = t - 3 + k;
            if (tt >= 0)
                acc = fmaf(zxbcdt[(size_t)(b * SEQ + tt) * D_IN_PROJ + D_INNER + ch],
                           cwl[ch * 4 + k], acc);
        }
        float s = acc / (1.f + expf(-acc));     // silu
        xBC[(size_t)bt * CONV_DIM + ch] = s;
    }
    if (threadIdx.x < NHEADS) {
        int hh = threadIdx.x;
        float raw = zxbcdt[(size_t)bt * D_IN_PROJ + (D_INNER + CONV_DIM) + hh] +
                    dt_bias[layer * NHEADS + hh];
        float dtv = (raw > 20.f) ? raw : log1pf(expf(raw));
        dtb[bt * NHEADS + hh] = dtv;
    }
}

// ---------------------------------------------------------------------------
// sequential SSD scan. block per (b,h). 256 threads = 4 waves.
// lanes = n (64 states), wave w owns p in {w, w+4, ...} (12-13 each)
__global__ __launch_bounds__(256) void ssd_scan_kernel(
    const float* __restrict__ xBC, const float* __restrict__ dtb,
    const float* __restrict__ A_log, const float* __restrict__ Dv,
    float* __restrict__ y, int layer)
{
    int b = blockIdx.x;
    int h = blockIdx.y;
    int lane = threadIdx.x & 63;
    int w = threadIdx.x >> 6;
    float A = -expf(A_log[layer * NHEADS + h]);
    float Dh = Dv[layer * NHEADS + h];
    float s[13];
#pragma unroll
    for (int j = 0; j < 13; j++) s[j] = 0.f;

    for (int t = 0; t < SEQ; t++) {
        const float* row = xBC + (size_t)(b * SEQ + t) * CONV_DIM;
        float Bn = row[D_INNER + lane];
        float Cn = row[D_INNER + D_STATE + lane];
        float xv = (lane < HEADDIM) ? row[h * HEADDIM + lane] : 0.f;
        float dtv = dtb[(b * SEQ + t) * NHEADS + h];
        float dA = expf(dtv * A);
        float* yrow = y + (size_t)((b * SEQ + t) * NHEADS + h) * HEADDIM;
#pragma unroll
        for (int j = 0; j < 13; j++) {
            int p = w + 4 * j;
            if (p >= HEADDIM) continue;        // wave-uniform
            float xp = __shfl(xv, p, 64);
            s[j] = fmaf(s[j], dA, (dtv * xp) * Bn);
            float v = s[j] * Cn;
            v += __shfl_xor(v, 32, 64);
            v += __shfl_xor(v, 16, 64);
            v += __shfl_xor(v, 8, 64);
            v += __shfl_xor(v, 4, 64);
            v += __shfl_xor(v, 2, 64);
            v += __shfl_xor(v, 1, 64);
            if (lane == 0) yrow[p] = fmaf(xp, Dh, v);
        }
    }
}

// ---------------------------------------------------------------------------
// y = rmsnorm(y * silu(z), gnorm_w)   over 400 dims, in place
__global__ __launch_bounds__(256) void gate_norm_kernel(
    float* __restrict__ y, const float* __restrict__ zxbcdt,
    const float* __restrict__ gw, int layer)
{
    int m = blockIdx.x;
    __shared__ float buf[D_INNER];
    __shared__ float red[4];
    const float* z = zxbcdt + (size_t)m * D_IN_PROJ;
    float* yr = y + (size_t)m * D_INNER;
    const float* gwl = gw + (size_t)layer * D_INNER;
    float ss = 0.f;
    for (int k = threadIdx.x; k < D_INNER; k += 256) {
        float zv = z[k];
        float sz = zv / (1.f + expf(-zv));
        float g = yr[k] * sz;
        buf[k] = g;
        ss = fmaf(g, g, ss);
    }
    int lane = threadIdx.x & 63, w = threadIdx.x >> 6;
#pragma unroll
    for (int o = 32; o; o >>= 1) ss += __shfl_xor(ss, o, 64);
    if (lane == 0) red[w] = ss;
    __syncthreads();
    float tot = red[0] + red[1] + red[2] + red[3];
    float rstd = rsqrtf(tot * (1.f / D_INNER) + EPS);
    for (int k = threadIdx.x; k < D_INNER; k += 256)
        yr[k] = buf[k] * rstd * gwl[k];
}

// ---------------------------------------------------------------------------
extern "C" void kernel_launch(void* const* d_in, const int* in_sizes, int n_in,
                              void* d_out, int out_size, void* d_ws, size_t ws_size,
                              hipStream_t stream)
{
    const float* x         = (const float*)d_in[0];
    const float* pe_conv_w = (const float*)d_in[1];
    const float* proj_in_w = (const float*)d_in[2];
    const float* gn_g      = (const float*)d_in[3];
    const float* gn_b      = (const float*)d_in[4];
    const float* spec_w    = (const float*)d_in[5];
    const float* norm_w    = (const float*)d_in[6];
    const float* in_proj_w = (const float*)d_in[7];
    const float* conv_w    = (const float*)d_in[8];
    const float* conv_b    = (const float*)d_in[9];
    const float* dt_bias   = (const float*)d_in[10];
    const float* A_log     = (const float*)d_in[11];
    const float* Dv        = (const float*)d_in[12];
    const float* gnorm_w   = (const float*)d_in[13];
    const float* out_proj_w= (const float*)d_in[14];
    const float* norm_f_w  = (const float*)d_in[15];
    const float* head_w    = (const float*)d_in[16];
    const float* head_b    = (const float*)d_in[17];
    float* out = (float*)d_out;
    float* ws  = (float*)d_ws;

    // workspace layout (floats)
    float* residual = ws;                       // 1,824,000
    float* hidden   = ws + 1824000;             // 1,824,000
    float* ubuf     = ws + 3648000;             // 1,824,000
    float* zxbcdt   = ws + 5472000;             // 9120*936 = 8,536,320
    float* xBC      = ws + 14008320;            // 9120*528 = 4,815,360
    float* dtb      = ws + 18823680;            // 9120*8   = 72,960
    float* ybuf     = ws + 18896640;            // 9120*400 = 3,648,000
    // pre-layer aliases
    float* traw  = ybuf;                        // 1,824,000
    float* patch = zxbcdt;                      // 1,824,000
    float* csmat = xBC;                         // 202*200 = 40,400
    float* csout = xBC + 50000;                 // 9120*202 = 1,842,240
    float* magb  = xBC + 2000000;               // 9120*101 = 921,120
    float* stats = dtb;                         // 160

    // ---- patch embed ----
    time_conv_kernel<<<NTOK, 256, 0, stream>>>(x, proj_in_w, traw);
    gn_stats_kernel<<<80, 256, 0, stream>>>(traw, stats);
    gn_gelu_kernel<<<(NTOK * 200 + 255) / 256, 256, 0, stream>>>(traw, stats, gn_g, gn_b, patch);
    dft_init_kernel<<<(202 * 200 + 255) / 256, 256, 0, stream>>>(csmat);
    {
        dim3 g((202 + 127) / 128, (NTOK + 127) / 128);
        gemm_nt<<<g, 256, 0, stream>>>(x, csmat, nullptr, csout, NTOK, 202, 200, 0);
    }
    mag_kernel<<<(NTOK * NFREQ + 255) / 256, 256, 0, stream>>>(csout, magb);
    {
        dim3 g((200 + 127) / 128, (NTOK + 127) / 128);
        gemm_nt<<<g, 256, 0, stream>>>(magb, spec_w, nullptr, patch, NTOK, 200, NFREQ, 1);
    }
    pe_conv_kernel<<<(NTOK * 200 + 255) / 256, 256, 0, stream>>>(patch, pe_conv_w, hidden);

    // ---- layers ----
    for (int i = 0; i < N_LAYER; i++) {
        add_rmsnorm_kernel<<<NTOK, 64, 0, stream>>>(hidden, residual, norm_w + i * 200, ubuf,
                                                    (i == 0) ? 1 : 0);
        {
            dim3 g((D_IN_PROJ + 127) / 128, (NTOK + 127) / 128);
            gemm_nt<<<g, 256, 0, stream>>>(ubuf, in_proj_w + (size_t)i * D_IN_PROJ * 200,
                                           nullptr, zxbcdt, NTOK, D_IN_PROJ, 200, 0);
        }
        dtconv_kernel<<<NTOK, 256, 0, stream>>>(zxbcdt, conv_w, conv_b, dt_bias, xBC, dtb, i);
        {
            dim3 g(BATCH, NHEADS);
            ssd_scan_kernel<<<g, 256, 0, stream>>>(xBC, dtb, A_log, Dv, ybuf, i);
        }
        gate_norm_kernel<<<NTOK, 256, 0, stream>>>(ybuf, zxbcdt, gnorm_w, i);
        {
            dim3 g((200 + 127) / 128, (NTOK + 127) / 128);
            gemm_nt<<<g, 256, 0, stream>>>(ybuf, out_proj_w + (size_t)i * 200 * D_INNER,
                                           nullptr, hidden, NTOK, 200, D_INNER, 0);
        }
    }

    // ---- final norm + head ----
    add_rmsnorm_kernel<<<NTOK, 64, 0, stream>>>(hidden, residual, norm_f_w, ubuf, 0);
    {
        dim3 g((200 + 127) / 128, (NTOK + 127) / 128);
        gemm_nt<<<g, 256, 0, stream>>>(ubuf, head_w, head_b, out, NTOK, 200, 200, 0);
    }
}

// Round 2
// 7321.603 us; speedup vs baseline: 3.4913x; 3.4913x over previous
//
#include <hip/hip_runtime.h>
#include <hip/hip_bf16.h>
#include <math.h>

// ---------------------------------------------------------------------------
// EEGMamba forward. Round 2: chunked SSD scan (5 chunks x 114 steps),
// register-state formulation, no cross-lane ops.
#define D_MODEL   200
#define N_LAYER   12
#define NHEADS    8
#define HEADDIM   50
#define D_STATE   64
#define D_INNER   400
#define CONV_DIM  528
#define D_IN_PROJ 936
#define D_CONV    4
#define EPS       1e-5f

#define BATCH 16
#define CH    19
#define LLEN  30
#define SEQ   570
#define NTOK  9120
#define NFREQ 101

#define NCHUNK 5
#define LCHUNK 114           // 5*114 = 570

// ---------------------------------------------------------------------------
// Generic fp32 GEMM:  C[M,N] = A[M,K] @ W[N,K]^T  (+ bias[n]) (+ C if accum)
__global__ __launch_bounds__(256) void gemm_nt(
    const float* __restrict__ A, const float* __restrict__ W,
    const float* __restrict__ bias, float* __restrict__ C,
    int M, int N, int K, int accum)
{
    const int BM = 128, BN = 128, BK = 16;
    __shared__ float As[16][BM + 4];
    __shared__ float Ws[16][BN + 4];

    int bm = blockIdx.y * BM;
    int bn = blockIdx.x * BN;
    int tid = threadIdx.x;
    int lr = tid >> 1;
    int lc = (tid & 1) * 8;
    int tx = tid & 15;
    int ty = tid >> 4;

    float acc[8][8];
#pragma unroll
    for (int i = 0; i < 8; i++)
#pragma unroll
        for (int j = 0; j < 8; j++) acc[i][j] = 0.f;

    for (int k0 = 0; k0 < K; k0 += BK) {
#pragma unroll
        for (int i = 0; i < 8; i++) {
            int gr = bm + lr, gk = k0 + lc + i;
            As[lc + i][lr] = (gr < M && gk < K) ? A[(size_t)gr * K + gk] : 0.f;
        }
#pragma unroll
        for (int i = 0; i < 8; i++) {
            int gr = bn + lr, gk = k0 + lc + i;
            Ws[lc + i][lr] = (gr < N && gk < K) ? W[(size_t)gr * K + gk] : 0.f;
        }
        __syncthreads();
#pragma unroll
        for (int kk = 0; kk < BK; kk++) {
            float a[8], bv[8];
#pragma unroll
            for (int i = 0; i < 8; i++) a[i] = As[kk][ty * 8 + i];
#pragma unroll
            for (int j = 0; j < 8; j++) bv[j] = Ws[kk][tx * 8 + j];
#pragma unroll
            for (int i = 0; i < 8; i++)
#pragma unroll
                for (int j = 0; j < 8; j++)
                    acc[i][j] = fmaf(a[i], bv[j], acc[i][j]);
        }
        __syncthreads();
    }

#pragma unroll
    for (int i = 0; i < 8; i++) {
        int gm = bm + ty * 8 + i;
        if (gm >= M) continue;
#pragma unroll
        for (int j = 0; j < 8; j++) {
            int gn = bn + tx * 8 + j;
            if (gn >= N) continue;
            float v = acc[i][j];
            if (bias) v += bias[gn];
            if (accum) v += C[(size_t)gm * N + gn];
            C[(size_t)gm * N + gn] = v;
        }
    }
}

// ---------------------------------------------------------------------------
// patch embed: time conv
__global__ __launch_bounds__(256) void time_conv_kernel(
    const float* __restrict__ x, const float* __restrict__ pw,
    float* __restrict__ traw)
{
    int br = blockIdx.x;
    __shared__ float xr[200];
    if (threadIdx.x < 200) xr[threadIdx.x] = x[(size_t)br * 200 + threadIdx.x];
    __syncthreads();
    if (threadIdx.x < 200) {
        int oc = threadIdx.x >> 3, j = threadIdx.x & 7;
        int start = j * 25 - 24;
        float acc = 0.f;
#pragma unroll
        for (int k = 0; k < 49; k++) {
            int d = start + k;
            if (d >= 0 && d < 200) acc = fmaf(xr[d], pw[oc * 49 + k], acc);
        }
        int b = br / SEQ, row = br % SEQ;
        traw[(((size_t)b * 25 + oc) * SEQ + row) * 8 + j] = acc;
    }
}

__global__ __launch_bounds__(256) void gn_stats_kernel(
    const float* __restrict__ traw, float* __restrict__ stats)
{
    int bg = blockIdx.x;
    int b = bg / 5, g = bg % 5;
    const float* base = traw + ((size_t)b * 25 + g * 5) * SEQ * 8;
    float s = 0.f, q = 0.f;
    for (int i = threadIdx.x; i < 5 * SEQ * 8; i += 256) {
        float v = base[i];
        s += v; q = fmaf(v, v, q);
    }
    __shared__ float rs[4], rq[4];
    int lane = threadIdx.x & 63, w = threadIdx.x >> 6;
#pragma unroll
    for (int o = 32; o; o >>= 1) { s += __shfl_xor(s, o, 64); q += __shfl_xor(q, o, 64); }
    if (lane == 0) { rs[w] = s; rq[w] = q; }
    __syncthreads();
    if (threadIdx.x == 0) {
        float S = rs[0] + rs[1] + rs[2] + rs[3];
        float Q = rq[0] + rq[1] + rq[2] + rq[3];
        float inv = 1.f / (5.f * SEQ * 8.f);
        float mean = S * inv;
        float var = Q * inv - mean * mean;
        stats[bg * 2] = mean;
        stats[bg * 2 + 1] = rsqrtf(var + EPS);
    }
}

__global__ __launch_bounds__(256) void gn_gelu_kernel(
    const float* __restrict__ traw, const float* __restrict__ stats,
    const float* __restrict__ gn_g, const float* __restrict__ gn_b,
    float* __restrict__ patch)
{
    int idx = blockIdx.x * 256 + threadIdx.x;
    if (idx >= NTOK * 200) return;
    int d = idx % 200;
    int row = (idx / 200) % SEQ;
    int b = idx / (200 * SEQ);
    int oc = d >> 3, j = d & 7;
    float v = traw[(((size_t)b * 25 + oc) * SEQ + row) * 8 + j];
    int g = oc / 5;
    float mean = stats[(b * 5 + g) * 2];
    float rstd = stats[(b * 5 + g) * 2 + 1];
    v = (v - mean) * rstd * gn_g[oc] + gn_b[oc];
    float ge = 0.5f * v * (1.f + erff(v * 0.70710678118654752f));
    patch[idx] = ge;
}

__global__ __launch_bounds__(256) void dft_init_kernel(float* __restrict__ CS)
{
    int idx = blockIdx.x * 256 + threadIdx.x;
    if (idx >= 202 * 200) return;
    int f = idx / 200, d = idx % 200;
    int fr = (f < NFREQ) ? f : (f - NFREQ);
    int m = (fr * d) % 200;
    float ang = -6.283185307179586f * (float)m * (1.f / 200.f);
    CS[idx] = (f < NFREQ) ? cosf(ang) : sinf(ang);
}

__global__ __launch_bounds__(256) void mag_kernel(
    const float* __restrict__ cs_out, float* __restrict__ magv)
{
    int idx = blockIdx.x * 256 + threadIdx.x;
    if (idx >= NTOK * NFREQ) return;
    int m = idx / NFREQ, f = idx % NFREQ;
    float re = cs_out[(size_t)m * 202 + f];
    float im = cs_out[(size_t)m * 202 + NFREQ + f];
    magv[idx] = sqrtf(re * re + im * im) * 0.005f;
}

__global__ __launch_bounds__(256) void pe_conv_kernel(
    const float* __restrict__ patch, const float* __restrict__ pw,
    float* __restrict__ hidden)
{
    int idx = blockIdx.x * 256 + threadIdx.x;
    if (idx >= NTOK * 200) return;
    int d = idx % 200;
    int l = (idx / 200) % LLEN;
    int c = (idx / (200 * LLEN)) % CH;
    int b = idx / (200 * LLEN * CH);
    float acc = patch[idx];
    const float* w = pw + d * 49;
#pragma unroll
    for (int i = 0; i < 7; i++) {
        int cc = c + i - 3;
        if (cc < 0 || cc >= CH) continue;
#pragma unroll
        for (int j = 0; j < 7; j++) {
            int ll = l + j - 3;
            if (ll < 0 || ll >= LLEN) continue;
            acc = fmaf(patch[(((size_t)b * CH + cc) * LLEN + ll) * 200 + d], w[i * 7 + j], acc);
        }
    }
    hidden[idx] = acc;
}

// ---------------------------------------------------------------------------
__global__ __launch_bounds__(64) void add_rmsnorm_kernel(
    const float* __restrict__ hidden, float* __restrict__ residual,
    const float* __restrict__ wn, float* __restrict__ u, int first)
{
    int m = blockIdx.x;
    int lane = threadIdx.x;
    const float* hr = hidden + (size_t)m * 200;
    float* rr = residual + (size_t)m * 200;
    float v[4];
    float ss = 0.f;
#pragma unroll
    for (int i = 0; i < 4; i++) {
        int k = lane + i * 64;
        float xv = 0.f;
        if (k < 200) {
            xv = hr[k] + (first ? 0.f : rr[k]);
            rr[k] = xv;
        }
        v[i] = xv;
        ss = fmaf(xv, xv, ss);
    }
#pragma unroll
    for (int o = 32; o; o >>= 1) ss += __shfl_xor(ss, o, 64);
    float rstd = rsqrtf(ss * (1.f / 200.f) + EPS);
#pragma unroll
    for (int i = 0; i < 4; i++) {
        int k = lane + i * 64;
        if (k < 200) u[(size_t)m * 200 + k] = v[i] * rstd * wn[k];
    }
}

// ---------------------------------------------------------------------------
__global__ __launch_bounds__(256) void dtconv_kernel(
    const float* __restrict__ zxbcdt, const float* __restrict__ cw,
    const float* __restrict__ cb, const float* __restrict__ dt_bias,
    float* __restrict__ xBC, float* __restrict__ dtb, int layer)
{
    int bt = blockIdx.x;
    int b = bt / SEQ, t = bt % SEQ;
    const float* cwl = cw + (size_t)layer * CONV_DIM * 4;
    const float* cbl = cb + (size_t)layer * CONV_DIM;
    for (int ch = threadIdx.x; ch < CONV_DIM; ch += 256) {
        float acc = cbl[ch];
#pragma unroll
        for (int k = 0; k < 4; k++) {
            int tt = t - 3 + k;
            if (tt >= 0)
                acc = fmaf(zxbcdt[(size_t)(b * SEQ + tt) * D_IN_PROJ + D_INNER + ch],
                           cwl[ch * 4 + k], acc);
        }
        float s = acc / (1.f + expf(-acc));
        xBC[(size_t)bt * CONV_DIM + ch] = s;
    }
    if (threadIdx.x < NHEADS) {
        int hh = threadIdx.x;
        float raw = zxbcdt[(size_t)bt * D_IN_PROJ + (D_INNER + CONV_DIM) + hh] +
                    dt_bias[layer * NHEADS + hh];
        float dtv = (raw > 20.f) ? raw : log1pf(expf(raw));
        dtb[bt * NHEADS + hh] = dtv;
    }
}

// ---------------------------------------------------------------------------
// Chunked SSD scan.
// Pass 1: per (b,h,c) compute chunk-local end state L_c (from zero init) and
//         chunk decay product P_c. Lanes = p (0..49), state s[n] in registers.
__global__ __launch_bounds__(64) void ssd_chunk_state_kernel(
    const float* __restrict__ xBC, const float* __restrict__ dtb,
    const float* __restrict__ A_log, float* __restrict__ Sbuf,
    float* __restrict__ Pd, int layer)
{
    int b = blockIdx.x, h = blockIdx.y, c = blockIdx.z;
    int p = threadIdx.x;
    float A = -expf(A_log[layer * NHEADS + h]);
    float s[64];
#pragma unroll
    for (int n = 0; n < 64; n++) s[n] = 0.f;
    float pacc = 1.f;

    int t0 = c * LCHUNK;
    for (int t = t0; t < t0 + LCHUNK; t++) {
        const float* row = xBC + (size_t)(b * SEQ + t) * CONV_DIM;
        float dtv = dtb[(b * SEQ + t) * NHEADS + h];
        float dA = __expf(dtv * A);
        float xp = (p < HEADDIM) ? row[h * HEADDIM + p] : 0.f;
        float u = dtv * xp;
        pacc *= dA;
        const float4* B4 = (const float4*)(row + D_INNER);
#pragma unroll
        for (int n4 = 0; n4 < 16; n4++) {
            float4 bq = B4[n4];
            s[4 * n4 + 0] = fmaf(s[4 * n4 + 0], dA, u * bq.x);
            s[4 * n4 + 1] = fmaf(s[4 * n4 + 1], dA, u * bq.y);
            s[4 * n4 + 2] = fmaf(s[4 * n4 + 2], dA, u * bq.z);
            s[4 * n4 + 3] = fmaf(s[4 * n4 + 3], dA, u * bq.w);
        }
    }
    // store L_c
    if (p < HEADDIM) {
        float* Sb = Sbuf + ((size_t)((b * NHEADS + h) * NCHUNK + c)) * (HEADDIM * 64)
                    + p * 64;
#pragma unroll
        for (int n4 = 0; n4 < 16; n4++) {
            float4 v = make_float4(s[4 * n4], s[4 * n4 + 1], s[4 * n4 + 2], s[4 * n4 + 3]);
            ((float4*)Sb)[n4] = v;
        }
    }
    if (p == 0) Pd[(b * NHEADS + h) * NCHUNK + c] = pacc;
}

// Pass 2: inter-chunk scan (in place): S[c] becomes chunk-INITIAL state.
__global__ __launch_bounds__(256) void ssd_chunk_scan_kernel(
    float* __restrict__ Sbuf, const float* __restrict__ Pd)
{
    int bh = blockIdx.x;   // b*8+h
    float* base = Sbuf + (size_t)bh * NCHUNK * (HEADDIM * 64);
    const float* pd = Pd + bh * NCHUNK;
    for (int e = threadIdx.x; e < HEADDIM * 64; e += 256) {
        float cur = 0.f;
#pragma unroll
        for (int c = 0; c < NCHUNK; c++) {
            float l = base[(size_t)c * (HEADDIM * 64) + e];
            base[(size_t)c * (HEADDIM * 64) + e] = cur;
            cur = fmaf(pd[c], cur, l);
        }
    }
}

// Pass 3: per (b,h,c) run recurrence from chunk-initial state, emit y.
__global__ __launch_bounds__(64) void ssd_chunk_out_kernel(
    const float* __restrict__ xBC, const float* __restrict__ dtb,
    const float* __restrict__ A_log, const float* __restrict__ Dv,
    const float* __restrict__ Sbuf, float* __restrict__ y, int layer)
{
    int b = blockIdx.x, h = blockIdx.y, c = blockIdx.z;
    int p = threadIdx.x;
    float A = -expf(A_log[layer * NHEADS + h]);
    float Dh = Dv[layer * NHEADS + h];
    float s[64];
    {
        const float* Sb = Sbuf + ((size_t)((b * NHEADS + h) * NCHUNK + c)) * (HEADDIM * 64)
                          + ((p < HEADDIM) ? p : 0) * 64;
#pragma unroll
        for (int n4 = 0; n4 < 16; n4++) {
            float4 v = ((const float4*)Sb)[n4];
            s[4 * n4] = v.x; s[4 * n4 + 1] = v.y; s[4 * n4 + 2] = v.z; s[4 * n4 + 3] = v.w;
        }
    }

    int t0 = c * LCHUNK;
    for (int t = t0; t < t0 + LCHUNK; t++) {
        const float* row = xBC + (size_t)(b * SEQ + t) * CONV_DIM;
        float dtv = dtb[(b * SEQ + t) * NHEADS + h];
        float dA = __expf(dtv * A);
        float xp = (p < HEADDIM) ? row[h * HEADDIM + p] : 0.f;
        float u = dtv * xp;
        const float4* B4 = (const float4*)(row + D_INNER);
        const float4* C4 = (const float4*)(row + D_INNER + D_STATE);
        float y0 = 0.f, y1 = 0.f, y2 = 0.f, y3 = 0.f;
#pragma unroll
        for (int n4 = 0; n4 < 16; n4++) {
            float4 bq = B4[n4];
            float4 cq = C4[n4];
            float t0v = fmaf(s[4 * n4 + 0], dA, u * bq.x);
            float t1v = fmaf(s[4 * n4 + 1], dA, u * bq.y);
            float t2v = fmaf(s[4 * n4 + 2], dA, u * bq.z);
            float t3v = fmaf(s[4 * n4 + 3], dA, u * bq.w);
            s[4 * n4 + 0] = t0v; s[4 * n4 + 1] = t1v;
            s[4 * n4 + 2] = t2v; s[4 * n4 + 3] = t3v;
            y0 = fmaf(t0v, cq.x, y0);
            y1 = fmaf(t1v, cq.y, y1);
            y2 = fmaf(t2v, cq.z, y2);
            y3 = fmaf(t3v, cq.w, y3);
        }
        if (p < HEADDIM) {
            float yv = (y0 + y1) + (y2 + y3);
            y[(size_t)((b * SEQ + t) * NHEADS + h) * HEADDIM + p] = fmaf(xp, Dh, yv);
        }
    }
}

// ---------------------------------------------------------------------------
__global__ __launch_bounds__(256) void gate_norm_kernel(
    float* __restrict__ y, const float* __restrict__ zxbcdt,
    const float* __restrict__ gw, int layer)
{
    int m = blockIdx.x;
    __shared__ float buf[D_INNER];
    __shared__ float red[4];
    const float* z = zxbcdt + (size_t)m * D_IN_PROJ;
    float* yr = y + (size_t)m * D_INNER;
    const float* gwl = gw + (size_t)layer * D_INNER;
    float ss = 0.f;
    for (int k = threadIdx.x; k < D_INNER; k += 256) {
        float zv = z[k];
        float sz = zv / (1.f + expf(-zv));
        float g = yr[k] * sz;
        buf[k] = g;
        ss = fmaf(g, g, ss);
    }
    int lane = threadIdx.x & 63, w = threadIdx.x >> 6;
#pragma unroll
    for (int o = 32; o; o >>= 1) ss += __shfl_xor(ss, o, 64);
    if (lane == 0) red[w] = ss;
    __syncthreads();
    float tot = red[0] + red[1] + red[2] + red[3];
    float rstd = rsqrtf(tot * (1.f / D_INNER) + EPS);
    for (int k = threadIdx.x; k < D_INNER; k += 256)
        yr[k] = buf[k] * rstd * gwl[k];
}

// ---------------------------------------------------------------------------
extern "C" void kernel_launch(void* const* d_in, const int* in_sizes, int n_in,
                              void* d_out, int out_size, void* d_ws, size_t ws_size,
                              hipStream_t stream)
{
    const float* x         = (const float*)d_in[0];
    const float* pe_conv_w = (const float*)d_in[1];
    const float* proj_in_w = (const float*)d_in[2];
    const float* gn_g      = (const float*)d_in[3];
    const float* gn_b      = (const float*)d_in[4];
    const float* spec_w    = (const float*)d_in[5];
    const float* norm_w    = (const float*)d_in[6];
    const float* in_proj_w = (const float*)d_in[7];
    const float* conv_w    = (const float*)d_in[8];
    const float* conv_b    = (const float*)d_in[9];
    const float* dt_bias   = (const float*)d_in[10];
    const float* A_log     = (const float*)d_in[11];
    const float* Dv        = (const float*)d_in[12];
    const float* gnorm_w   = (const float*)d_in[13];
    const float* out_proj_w= (const float*)d_in[14];
    const float* norm_f_w  = (const float*)d_in[15];
    const float* head_w    = (const float*)d_in[16];
    const float* head_b    = (const float*)d_in[17];
    float* out = (float*)d_out;
    float* ws  = (float*)d_ws;

    // workspace layout (floats)
    float* residual = ws;                       // 1,824,000
    float* hidden   = ws + 1824000;             // 1,824,000
    float* ubuf     = ws + 3648000;             // 1,824,000
    float* zxbcdt   = ws + 5472000;             // 9120*936
    float* xBC      = ws + 14008320;            // 9120*528
    float* dtb      = ws + 18823680;            // 9120*8
    float* ybuf     = ws + 18896640;            // 9120*400
    // scan scratch: hidden (+start of ubuf) is dead during the scan
    float* Sbuf  = ws + 1824000;                // 5*128*3200 = 2,048,000
    float* Pd    = ws + 3872000;                // 640 (inside dead ubuf)
    // pre-layer aliases
    float* traw  = ybuf;
    float* patch = zxbcdt;
    float* csmat = xBC;
    float* csout = xBC + 50000;
    float* magb  = xBC + 2000000;
    float* stats = dtb;

    // ---- patch embed ----
    time_conv_kernel<<<NTOK, 256, 0, stream>>>(x, proj_in_w, traw);
    gn_stats_kernel<<<80, 256, 0, stream>>>(traw, stats);
    gn_gelu_kernel<<<(NTOK * 200 + 255) / 256, 256, 0, stream>>>(traw, stats, gn_g, gn_b, patch);
    dft_init_kernel<<<(202 * 200 + 255) / 256, 256, 0, stream>>>(csmat);
    {
        dim3 g((202 + 127) / 128, (NTOK + 127) / 128);
        gemm_nt<<<g, 256, 0, stream>>>(x, csmat, nullptr, csout, NTOK, 202, 200, 0);
    }
    mag_kernel<<<(NTOK * NFREQ + 255) / 256, 256, 0, stream>>>(csout, magb);
    {
        dim3 g((200 + 127) / 128, (NTOK + 127) / 128);
        gemm_nt<<<g, 256, 0, stream>>>(magb, spec_w, nullptr, patch, NTOK, 200, NFREQ, 1);
    }
    pe_conv_kernel<<<(NTOK * 200 + 255) / 256, 256, 0, stream>>>(patch, pe_conv_w, hidden);

    // ---- layers ----
    for (int i = 0; i < N_LAYER; i++) {
        add_rmsnorm_kernel<<<NTOK, 64, 0, stream>>>(hidden, residual, norm_w + i * 200, ubuf,
                                                    (i == 0) ? 1 : 0);
        {
            dim3 g((D_IN_PROJ + 127) / 128, (NTOK + 127) / 128);
            gemm_nt<<<g, 256, 0, stream>>>(ubuf, in_proj_w + (size_t)i * D_IN_PROJ * 200,
                                           nullptr, zxbcdt, NTOK, D_IN_PROJ, 200, 0);
        }
        dtconv_kernel<<<NTOK, 256, 0, stream>>>(zxbcdt, conv_w, conv_b, dt_bias, xBC, dtb, i);
        {
            dim3 g(BATCH, NHEADS, NCHUNK);
            ssd_chunk_state_kernel<<<g, 64, 0, stream>>>(xBC, dtb, A_log, Sbuf, Pd, i);
            ssd_chunk_scan_kernel<<<BATCH * NHEADS, 256, 0, stream>>>(Sbuf, Pd);
            ssd_chunk_out_kernel<<<g, 64, 0, stream>>>(xBC, dtb, A_log, Dv, Sbuf, ybuf, i);
        }
        gate_norm_kernel<<<NTOK, 256, 0, stream>>>(ybuf, zxbcdt, gnorm_w, i);
        {
            dim3 g((200 + 127) / 128, (NTOK + 127) / 128);
            gemm_nt<<<g, 256, 0, stream>>>(ybuf, out_proj_w + (size_t)i * 200 * D_INNER,
                                           nullptr, hidden, NTOK, 200, D_INNER, 0);
        }
    }

    // ---- final norm + head ----
    add_rmsnorm_kernel<<<NTOK, 64, 0, stream>>>(hidden, residual, norm_f_w, ubuf, 0);
    {
        dim3 g((200 + 127) / 128, (NTOK + 127) / 128);
        gemm_nt<<<g, 256, 0, stream>>>(ubuf, head_w, head_b, out, NTOK, 200, 200, 0);
    }
}

// Round 3
// 5116.089 us; speedup vs baseline: 4.9964x; 1.4311x over previous
//
#include <hip/hip_runtime.h>
#include <hip/hip_bf16.h>
#include <math.h>

// ---------------------------------------------------------------------------
// EEGMamba forward. Round 3: LDS-staged multi-head chunked SSD scan
// (runtime chunk count, 8 heads per block, single-barrier double buffer).
#define D_MODEL   200
#define N_LAYER   12
#define NHEADS    8
#define HEADDIM   50
#define D_STATE   64
#define D_INNER   400
#define CONV_DIM  528
#define D_IN_PROJ 936
#define D_CONV    4
#define EPS       1e-5f

#define BATCH 16
#define CH    19
#define LLEN  30
#define SEQ   570
#define NTOK  9120
#define NFREQ 101

// ---------------------------------------------------------------------------
// Generic fp32 GEMM:  C[M,N] = A[M,K] @ W[N,K]^T  (+ bias[n]) (+ C if accum)
__global__ __launch_bounds__(256) void gemm_nt(
    const float* __restrict__ A, const float* __restrict__ W,
    const float* __restrict__ bias, float* __restrict__ C,
    int M, int N, int K, int accum)
{
    const int BM = 128, BN = 128, BK = 16;
    __shared__ float As[16][BM + 4];
    __shared__ float Ws[16][BN + 4];

    int bm = blockIdx.y * BM;
    int bn = blockIdx.x * BN;
    int tid = threadIdx.x;
    int lr = tid >> 1;
    int lc = (tid & 1) * 8;
    int tx = tid & 15;
    int ty = tid >> 4;

    float acc[8][8];
#pragma unroll
    for (int i = 0; i < 8; i++)
#pragma unroll
        for (int j = 0; j < 8; j++) acc[i][j] = 0.f;

    for (int k0 = 0; k0 < K; k0 += BK) {
#pragma unroll
        for (int i = 0; i < 8; i++) {
            int gr = bm + lr, gk = k0 + lc + i;
            As[lc + i][lr] = (gr < M && gk < K) ? A[(size_t)gr * K + gk] : 0.f;
        }
#pragma unroll
        for (int i = 0; i < 8; i++) {
            int gr = bn + lr, gk = k0 + lc + i;
            Ws[lc + i][lr] = (gr < N && gk < K) ? W[(size_t)gr * K + gk] : 0.f;
        }
        __syncthreads();
#pragma unroll
        for (int kk = 0; kk < BK; kk++) {
            float a[8], bv[8];
#pragma unroll
            for (int i = 0; i < 8; i++) a[i] = As[kk][ty * 8 + i];
#pragma unroll
            for (int j = 0; j < 8; j++) bv[j] = Ws[kk][tx * 8 + j];
#pragma unroll
            for (int i = 0; i < 8; i++)
#pragma unroll
                for (int j = 0; j < 8; j++)
                    acc[i][j] = fmaf(a[i], bv[j], acc[i][j]);
        }
        __syncthreads();
    }

#pragma unroll
    for (int i = 0; i < 8; i++) {
        int gm = bm + ty * 8 + i;
        if (gm >= M) continue;
#pragma unroll
        for (int j = 0; j < 8; j++) {
            int gn = bn + tx * 8 + j;
            if (gn >= N) continue;
            float v = acc[i][j];
            if (bias) v += bias[gn];
            if (accum) v += C[(size_t)gm * N + gn];
            C[(size_t)gm * N + gn] = v;
        }
    }
}

// ---------------------------------------------------------------------------
// patch embed: time conv
__global__ __launch_bounds__(256) void time_conv_kernel(
    const float* __restrict__ x, const float* __restrict__ pw,
    float* __restrict__ traw)
{
    int br = blockIdx.x;
    __shared__ float xr[200];
    if (threadIdx.x < 200) xr[threadIdx.x] = x[(size_t)br * 200 + threadIdx.x];
    __syncthreads();
    if (threadIdx.x < 200) {
        int oc = threadIdx.x >> 3, j = threadIdx.x & 7;
        int start = j * 25 - 24;
        float acc = 0.f;
#pragma unroll
        for (int k = 0; k < 49; k++) {
            int d = start + k;
            if (d >= 0 && d < 200) acc = fmaf(xr[d], pw[oc * 49 + k], acc);
        }
        int b = br / SEQ, row = br % SEQ;
        traw[(((size_t)b * 25 + oc) * SEQ + row) * 8 + j] = acc;
    }
}

__global__ __launch_bounds__(256) void gn_stats_kernel(
    const float* __restrict__ traw, float* __restrict__ stats)
{
    int bg = blockIdx.x;
    int b = bg / 5, g = bg % 5;
    const float* base = traw + ((size_t)b * 25 + g * 5) * SEQ * 8;
    float s = 0.f, q = 0.f;
    for (int i = threadIdx.x; i < 5 * SEQ * 8; i += 256) {
        float v = base[i];
        s += v; q = fmaf(v, v, q);
    }
    __shared__ float rs[4], rq[4];
    int lane = threadIdx.x & 63, w = threadIdx.x >> 6;
#pragma unroll
    for (int o = 32; o; o >>= 1) { s += __shfl_xor(s, o, 64); q += __shfl_xor(q, o, 64); }
    if (lane == 0) { rs[w] = s; rq[w] = q; }
    __syncthreads();
    if (threadIdx.x == 0) {
        float S = rs[0] + rs[1] + rs[2] + rs[3];
        float Q = rq[0] + rq[1] + rq[2] + rq[3];
        float inv = 1.f / (5.f * SEQ * 8.f);
        float mean = S * inv;
        float var = Q * inv - mean * mean;
        stats[bg * 2] = mean;
        stats[bg * 2 + 1] = rsqrtf(var + EPS);
    }
}

__global__ __launch_bounds__(256) void gn_gelu_kernel(
    const float* __restrict__ traw, const float* __restrict__ stats,
    const float* __restrict__ gn_g, const float* __restrict__ gn_b,
    float* __restrict__ patch)
{
    int idx = blockIdx.x * 256 + threadIdx.x;
    if (idx >= NTOK * 200) return;
    int d = idx % 200;
    int row = (idx / 200) % SEQ;
    int b = idx / (200 * SEQ);
    int oc = d >> 3, j = d & 7;
    float v = traw[(((size_t)b * 25 + oc) * SEQ + row) * 8 + j];
    int g = oc / 5;
    float mean = stats[(b * 5 + g) * 2];
    float rstd = stats[(b * 5 + g) * 2 + 1];
    v = (v - mean) * rstd * gn_g[oc] + gn_b[oc];
    float ge = 0.5f * v * (1.f + erff(v * 0.70710678118654752f));
    patch[idx] = ge;
}

__global__ __launch_bounds__(256) void dft_init_kernel(float* __restrict__ CS)
{
    int idx = blockIdx.x * 256 + threadIdx.x;
    if (idx >= 202 * 200) return;
    int f = idx / 200, d = idx % 200;
    int fr = (f < NFREQ) ? f : (f - NFREQ);
    int m = (fr * d) % 200;
    float ang = -6.283185307179586f * (float)m * (1.f / 200.f);
    CS[idx] = (f < NFREQ) ? cosf(ang) : sinf(ang);
}

__global__ __launch_bounds__(256) void mag_kernel(
    const float* __restrict__ cs_out, float* __restrict__ magv)
{
    int idx = blockIdx.x * 256 + threadIdx.x;
    if (idx >= NTOK * NFREQ) return;
    int m = idx / NFREQ, f = idx % NFREQ;
    float re = cs_out[(size_t)m * 202 + f];
    float im = cs_out[(size_t)m * 202 + NFREQ + f];
    magv[idx] = sqrtf(re * re + im * im) * 0.005f;
}

__global__ __launch_bounds__(256) void pe_conv_kernel(
    const float* __restrict__ patch, const float* __restrict__ pw,
    float* __restrict__ hidden)
{
    int idx = blockIdx.x * 256 + threadIdx.x;
    if (idx >= NTOK * 200) return;
    int d = idx % 200;
    int l = (idx / 200) % LLEN;
    int c = (idx / (200 * LLEN)) % CH;
    int b = idx / (200 * LLEN * CH);
    float acc = patch[idx];
    const float* w = pw + d * 49;
#pragma unroll
    for (int i = 0; i < 7; i++) {
        int cc = c + i - 3;
        if (cc < 0 || cc >= CH) continue;
#pragma unroll
        for (int j = 0; j < 7; j++) {
            int ll = l + j - 3;
            if (ll < 0 || ll >= LLEN) continue;
            acc = fmaf(patch[(((size_t)b * CH + cc) * LLEN + ll) * 200 + d], w[i * 7 + j], acc);
        }
    }
    hidden[idx] = acc;
}

// ---------------------------------------------------------------------------
__global__ __launch_bounds__(64) void add_rmsnorm_kernel(
    const float* __restrict__ hidden, float* __restrict__ residual,
    const float* __restrict__ wn, float* __restrict__ u, int first)
{
    int m = blockIdx.x;
    int lane = threadIdx.x;
    const float* hr = hidden + (size_t)m * 200;
    float* rr = residual + (size_t)m * 200;
    float v[4];
    float ss = 0.f;
#pragma unroll
    for (int i = 0; i < 4; i++) {
        int k = lane + i * 64;
        float xv = 0.f;
        if (k < 200) {
            xv = hr[k] + (first ? 0.f : rr[k]);
            rr[k] = xv;
        }
        v[i] = xv;
        ss = fmaf(xv, xv, ss);
    }
#pragma unroll
    for (int o = 32; o; o >>= 1) ss += __shfl_xor(ss, o, 64);
    float rstd = rsqrtf(ss * (1.f / 200.f) + EPS);
#pragma unroll
    for (int i = 0; i < 4; i++) {
        int k = lane + i * 64;
        if (k < 200) u[(size_t)m * 200 + k] = v[i] * rstd * wn[k];
    }
}

// ---------------------------------------------------------------------------
__global__ __launch_bounds__(256) void dtconv_kernel(
    const float* __restrict__ zxbcdt, const float* __restrict__ cw,
    const float* __restrict__ cb, const float* __restrict__ dt_bias,
    float* __restrict__ xBC, float* __restrict__ dtb, int layer)
{
    int bt = blockIdx.x;
    int b = bt / SEQ, t = bt % SEQ;
    const float* cwl = cw + (size_t)layer * CONV_DIM * 4;
    const float* cbl = cb + (size_t)layer * CONV_DIM;
    for (int ch = threadIdx.x; ch < CONV_DIM; ch += 256) {
        float acc = cbl[ch];
#pragma unroll
        for (int k = 0; k < 4; k++) {
            int tt = t - 3 + k;
            if (tt >= 0)
                acc = fmaf(zxbcdt[(size_t)(b * SEQ + tt) * D_IN_PROJ + D_INNER + ch],
                           cwl[ch * 4 + k], acc);
        }
        float s = acc / (1.f + expf(-acc));
        xBC[(size_t)bt * CONV_DIM + ch] = s;
    }
    if (threadIdx.x < NHEADS) {
        int hh = threadIdx.x;
        float raw = zxbcdt[(size_t)bt * D_IN_PROJ + (D_INNER + CONV_DIM) + hh] +
                    dt_bias[layer * NHEADS + hh];
        float dtv = (raw > 20.f) ? raw : log1pf(expf(raw));
        dtb[bt * NHEADS + hh] = dtv;
    }
}

// ---------------------------------------------------------------------------
// Chunked SSD scan, LDS-staged, 8 heads per block.
// Block = (b, chunk), 512 threads = 8 waves; wave w = head h = w; lane = p.
// LDS row: [0..527] = xBC row (x 400 | B 64 | C 64), [528..535] = dt row.
// Single-barrier double buffer; prefetch t+1 during compute of t.

// Pass 1: chunk-local end state (zero init) -> Sbuf[c]; chunk decay -> Pd[c].
__global__ __launch_bounds__(512) void ssd_state_kernel(
    const float* __restrict__ xBC, const float* __restrict__ dtb,
    const float* __restrict__ A_log, float* __restrict__ Sbuf,
    float* __restrict__ Pd, int layer, int lchunk, int nchunk)
{
    int b = blockIdx.x, c = blockIdx.y;
    int tid = threadIdx.x;
    int h = tid >> 6, p = tid & 63;
    float A = -expf(A_log[layer * NHEADS + h]);

    __shared__ float sh[2][544];
    int t0 = c * lchunk, tend = t0 + lchunk;

    {   // prologue: stage row t0
        const float* base = xBC + (size_t)(b * SEQ + t0) * CONV_DIM;
        sh[0][tid] = base[tid];
        if (tid < 24) {
            int e2 = 512 + tid;
            sh[0][e2] = (e2 < 528) ? base[e2]
                                   : dtb[(size_t)(b * SEQ + t0) * NHEADS + (e2 - 528)];
        }
    }
    __syncthreads();

    float s[64];
#pragma unroll
    for (int n = 0; n < 64; n++) s[n] = 0.f;
    float pacc = 1.f;

    for (int t = t0; t < tend; t++) {
        int cur = (t - t0) & 1, nxt = cur ^ 1;
        float pf0 = 0.f, pf1 = 0.f;
        if (t + 1 < tend) {     // issue prefetch early
            const float* base = xBC + (size_t)(b * SEQ + t + 1) * CONV_DIM;
            pf0 = base[tid];
            if (tid < 24) {
                int e2 = 512 + tid;
                pf1 = (e2 < 528) ? base[e2]
                                 : dtb[(size_t)(b * SEQ + t + 1) * NHEADS + (e2 - 528)];
            }
        }
        float dtv = sh[cur][528 + h];
        float xp  = (p < HEADDIM) ? sh[cur][h * HEADDIM + p] : 0.f;
        float dA = __expf(dtv * A);
        float u  = dtv * xp;
        pacc *= dA;
        const float4* B4 = (const float4*)&sh[cur][D_INNER];
#pragma unroll
        for (int n4 = 0; n4 < 16; n4++) {
            float4 bq = B4[n4];
            s[4 * n4 + 0] = fmaf(s[4 * n4 + 0], dA, u * bq.x);
            s[4 * n4 + 1] = fmaf(s[4 * n4 + 1], dA, u * bq.y);
            s[4 * n4 + 2] = fmaf(s[4 * n4 + 2], dA, u * bq.z);
            s[4 * n4 + 3] = fmaf(s[4 * n4 + 3], dA, u * bq.w);
        }
        if (t + 1 < tend) {
            sh[nxt][tid] = pf0;
            if (tid < 24) sh[nxt][512 + tid] = pf1;
        }
        __syncthreads();
    }

    if (p < HEADDIM) {
        float* Sb = Sbuf + ((size_t)((b * NHEADS + h) * nchunk + c)) * (HEADDIM * 64)
                    + p * 64;
#pragma unroll
        for (int n4 = 0; n4 < 16; n4++)
            ((float4*)Sb)[n4] = make_float4(s[4 * n4], s[4 * n4 + 1],
                                            s[4 * n4 + 2], s[4 * n4 + 3]);
    }
    if (p == 0) Pd[(b * NHEADS + h) * nchunk + c] = pacc;
}

// Pass 2: inter-chunk scan in place: Sbuf[c] becomes chunk-INITIAL state.
__global__ __launch_bounds__(256) void ssd_scan2_kernel(
    float* __restrict__ Sbuf, const float* __restrict__ Pd, int nchunk)
{
    int bh = blockIdx.x;
    float* base = Sbuf + (size_t)bh * nchunk * (HEADDIM * 64);
    const float* pd = Pd + bh * nchunk;
    for (int e = threadIdx.x; e < HEADDIM * 64; e += 256) {
        float cur = 0.f;
        for (int c = 0; c < nchunk; c++) {
            float l = base[(size_t)c * (HEADDIM * 64) + e];
            base[(size_t)c * (HEADDIM * 64) + e] = cur;
            cur = fmaf(pd[c], cur, l);
        }
    }
}

// Pass 3: re-run recurrence from chunk-initial state, emit y.
__global__ __launch_bounds__(512) void ssd_out_kernel(
    const float* __restrict__ xBC, const float* __restrict__ dtb,
    const float* __restrict__ A_log, const float* __restrict__ Dv,
    const float* __restrict__ Sbuf, float* __restrict__ y,
    int layer, int lchunk, int nchunk)
{
    int b = blockIdx.x, c = blockIdx.y;
    int tid = threadIdx.x;
    int h = tid >> 6, p = tid & 63;
    float A = -expf(A_log[layer * NHEADS + h]);
    float Dh = Dv[layer * NHEADS + h];

    __shared__ float sh[2][544];
    int t0 = c * lchunk, tend = t0 + lchunk;

    {   // prologue: stage row t0
        const float* base = xBC + (size_t)(b * SEQ + t0) * CONV_DIM;
        sh[0][tid] = base[tid];
        if (tid < 24) {
            int e2 = 512 + tid;
            sh[0][e2] = (e2 < 528) ? base[e2]
                                   : dtb[(size_t)(b * SEQ + t0) * NHEADS + (e2 - 528)];
        }
    }

    float s[64];
    if (p < HEADDIM) {
        const float* Sb = Sbuf + ((size_t)((b * NHEADS + h) * nchunk + c)) * (HEADDIM * 64)
                          + p * 64;
#pragma unroll
        for (int n4 = 0; n4 < 16; n4++) {
            float4 v = ((const float4*)Sb)[n4];
            s[4 * n4] = v.x; s[4 * n4 + 1] = v.y; s[4 * n4 + 2] = v.z; s[4 * n4 + 3] = v.w;
        }
    } else {
#pragma unroll
        for (int n = 0; n < 64; n++) s[n] = 0.f;
    }
    __syncthreads();

    for (int t = t0; t < tend; t++) {
        int cur = (t - t0) & 1, nxt = cur ^ 1;
        float pf0 = 0.f, pf1 = 0.f;
        if (t + 1 < tend) {
            const float* base = xBC + (size_t)(b * SEQ + t + 1) * CONV_DIM;
            pf0 = base[tid];
            if (tid < 24) {
                int e2 = 512 + tid;
                pf1 = (e2 < 528) ? base[e2]
                                 : dtb[(size_t)(b * SEQ + t + 1) * NHEADS + (e2 - 528)];
            }
        }
        float dtv = sh[cur][528 + h];
        float xp  = (p < HEADDIM) ? sh[cur][h * HEADDIM + p] : 0.f;
        float dA = __expf(dtv * A);
        float u  = dtv * xp;
        const float4* B4 = (const float4*)&sh[cur][D_INNER];
        const float4* C4 = (const float4*)&sh[cur][D_INNER + D_STATE];
        float y0 = 0.f, y1 = 0.f, y2 = 0.f, y3 = 0.f;
#pragma unroll
        for (int n4 = 0; n4 < 16; n4++) {
            float4 bq = B4[n4];
            float4 cq = C4[n4];
            float t0v = fmaf(s[4 * n4 + 0], dA, u * bq.x);
            float t1v = fmaf(s[4 * n4 + 1], dA, u * bq.y);
            float t2v = fmaf(s[4 * n4 + 2], dA, u * bq.z);
            float t3v = fmaf(s[4 * n4 + 3], dA, u * bq.w);
            s[4 * n4 + 0] = t0v; s[4 * n4 + 1] = t1v;
            s[4 * n4 + 2] = t2v; s[4 * n4 + 3] = t3v;
            y0 = fmaf(t0v, cq.x, y0);
            y1 = fmaf(t1v, cq.y, y1);
            y2 = fmaf(t2v, cq.z, y2);
            y3 = fmaf(t3v, cq.w, y3);
        }
        if (p < HEADDIM) {
            float yv = (y0 + y1) + (y2 + y3);
            y[(size_t)(b * SEQ + t) * D_INNER + h * HEADDIM + p] = fmaf(xp, Dh, yv);
        }
        if (t + 1 < tend) {
            sh[nxt][tid] = pf0;
            if (tid < 24) sh[nxt][512 + tid] = pf1;
        }
        __syncthreads();
    }
}

// ---------------------------------------------------------------------------
__global__ __launch_bounds__(256) void gate_norm_kernel(
    float* __restrict__ y, const float* __restrict__ zxbcdt,
    const float* __restrict__ gw, int layer)
{
    int m = blockIdx.x;
    __shared__ float buf[D_INNER];
    __shared__ float red[4];
    const float* z = zxbcdt + (size_t)m * D_IN_PROJ;
    float* yr = y + (size_t)m * D_INNER;
    const float* gwl = gw + (size_t)layer * D_INNER;
    float ss = 0.f;
    for (int k = threadIdx.x; k < D_INNER; k += 256) {
        float zv = z[k];
        float sz = zv / (1.f + expf(-zv));
        float g = yr[k] * sz;
        buf[k] = g;
        ss = fmaf(g, g, ss);
    }
    int lane = threadIdx.x & 63, w = threadIdx.x >> 6;
#pragma unroll
    for (int o = 32; o; o >>= 1) ss += __shfl_xor(ss, o, 64);
    if (lane == 0) red[w] = ss;
    __syncthreads();
    float tot = red[0] + red[1] + red[2] + red[3];
    float rstd = rsqrtf(tot * (1.f / D_INNER) + EPS);
    for (int k = threadIdx.x; k < D_INNER; k += 256)
        yr[k] = buf[k] * rstd * gwl[k];
}

// ---------------------------------------------------------------------------
extern "C" void kernel_launch(void* const* d_in, const int* in_sizes, int n_in,
                              void* d_out, int out_size, void* d_ws, size_t ws_size,
                              hipStream_t stream)
{
    const float* x         = (const float*)d_in[0];
    const float* pe_conv_w = (const float*)d_in[1];
    const float* proj_in_w = (const float*)d_in[2];
    const float* gn_g      = (const float*)d_in[3];
    const float* gn_b      = (const float*)d_in[4];
    const float* spec_w    = (const float*)d_in[5];
    const float* norm_w    = (const float*)d_in[6];
    const float* in_proj_w = (const float*)d_in[7];
    const float* conv_w    = (const float*)d_in[8];
    const float* conv_b    = (const float*)d_in[9];
    const float* dt_bias   = (const float*)d_in[10];
    const float* A_log     = (const float*)d_in[11];
    const float* Dv        = (const float*)d_in[12];
    const float* gnorm_w   = (const float*)d_in[13];
    const float* out_proj_w= (const float*)d_in[14];
    const float* norm_f_w  = (const float*)d_in[15];
    const float* head_w    = (const float*)d_in[16];
    const float* head_b    = (const float*)d_in[17];
    float* out = (float*)d_out;
    float* ws  = (float*)d_ws;

    // workspace layout (floats)
    float* residual = ws;                       // 1,824,000
    float* hidden   = ws + 1824000;             // 1,824,000
    float* ubuf     = ws + 3648000;             // 1,824,000
    float* zxbcdt   = ws + 5472000;             // 9120*936
    float* xBC      = ws + 14008320;            // 9120*528
    float* dtb      = ws + 18823680;            // 9120*8
    float* ybuf     = ws + 18896640;            // 9120*400 (ends 22,544,640)

    // SSD chunking: prefer 15 chunks with state buffer at ws tail; fall back
    // to 6 chunks fitting inside dead hidden/ubuf region. Branch depends only
    // on ws_size (constant across calls) -> graph-capture safe.
    int nchunk, lchunk;
    float *Sbuf, *Pd;
    const size_t baseEnd = 22544640;
    const size_t need15 = (baseEnd + (size_t)15 * 128 * 3200 + 1920) * sizeof(float);
    if (ws_size >= need15) {
        nchunk = 15; lchunk = 38;               // 15*38 = 570
        Sbuf = ws + baseEnd;                    // 6,144,000 floats
        Pd   = Sbuf + (size_t)15 * 128 * 3200;  // 1920 floats
    } else {
        nchunk = 6; lchunk = 95;                // 6*95 = 570
        Sbuf = ws + 1824000;                    // 2,457,600 floats (dead hidden+ubuf)
        Pd   = ws + 5470000;                    // 768 floats (dead ubuf tail)
    }

    // pre-layer aliases
    float* traw  = ybuf;
    float* patch = zxbcdt;
    float* csmat = xBC;
    float* csout = xBC + 50000;
    float* magb  = xBC + 2000000;
    float* stats = dtb;

    // ---- patch embed ----
    time_conv_kernel<<<NTOK, 256, 0, stream>>>(x, proj_in_w, traw);
    gn_stats_kernel<<<80, 256, 0, stream>>>(traw, stats);
    gn_gelu_kernel<<<(NTOK * 200 + 255) / 256, 256, 0, stream>>>(traw, stats, gn_g, gn_b, patch);
    dft_init_kernel<<<(202 * 200 + 255) / 256, 256, 0, stream>>>(csmat);
    {
        dim3 g((202 + 127) / 128, (NTOK + 127) / 128);
        gemm_nt<<<g, 256, 0, stream>>>(x, csmat, nullptr, csout, NTOK, 202, 200, 0);
    }
    mag_kernel<<<(NTOK * NFREQ + 255) / 256, 256, 0, stream>>>(csout, magb);
    {
        dim3 g((200 + 127) / 128, (NTOK + 127) / 128);
        gemm_nt<<<g, 256, 0, stream>>>(magb, spec_w, nullptr, patch, NTOK, 200, NFREQ, 1);
    }
    pe_conv_kernel<<<(NTOK * 200 + 255) / 256, 256, 0, stream>>>(patch, pe_conv_w, hidden);

    // ---- layers ----
    for (int i = 0; i < N_LAYER; i++) {
        add_rmsnorm_kernel<<<NTOK, 64, 0, stream>>>(hidden, residual, norm_w + i * 200, ubuf,
                                                    (i == 0) ? 1 : 0);
        {
            dim3 g((D_IN_PROJ + 127) / 128, (NTOK + 127) / 128);
            gemm_nt<<<g, 256, 0, stream>>>(ubuf, in_proj_w + (size_t)i * D_IN_PROJ * 200,
                                           nullptr, zxbcdt, NTOK, D_IN_PROJ, 200, 0);
        }
        dtconv_kernel<<<NTOK, 256, 0, stream>>>(zxbcdt, conv_w, conv_b, dt_bias, xBC, dtb, i);
        {
            dim3 g(BATCH, nchunk);
            ssd_state_kernel<<<g, 512, 0, stream>>>(xBC, dtb, A_log, Sbuf, Pd, i, lchunk, nchunk);
            ssd_scan2_kernel<<<BATCH * NHEADS, 256, 0, stream>>>(Sbuf, Pd, nchunk);
            ssd_out_kernel<<<g, 512, 0, stream>>>(xBC, dtb, A_log, Dv, Sbuf, ybuf, i, lchunk, nchunk);
        }
        gate_norm_kernel<<<NTOK, 256, 0, stream>>>(ybuf, zxbcdt, gnorm_w, i);
        {
            dim3 g((200 + 127) / 128, (NTOK + 127) / 128);
            gemm_nt<<<g, 256, 0, stream>>>(ybuf, out_proj_w + (size_t)i * 200 * D_INNER,
                                           nullptr, hidden, NTOK, 200, D_INNER, 0);
        }
    }

    // ---- final norm + head ----
    add_rmsnorm_kernel<<<NTOK, 64, 0, stream>>>(hidden, residual, norm_f_w, ubuf, 0);
    {
        dim3 g((200 + 127) / 128, (NTOK + 127) / 128);
        gemm_nt<<<g, 256, 0, stream>>>(ubuf, head_w, head_b, out, NTOK, 200, 200, 0);
    }
}

// Round 4
// 3265.540 us; speedup vs baseline: 7.8278x; 1.5667x over previous
//
#include <hip/hip_runtime.h>
#include <hip/hip_bf16.h>
#include <math.h>

// ---------------------------------------------------------------------------
// EEGMamba forward. Round 4: bf16 MFMA GEMMs (fp32 dt GEMV for accuracy),
// LDS-tiled pe_conv, 15-chunk SSD scan. ws_size-gated fallback to R3 path.
#define D_MODEL   200
#define N_LAYER   12
#define NHEADS    8
#define HEADDIM   50
#define D_STATE   64
#define D_INNER   400
#define CONV_DIM  528
#define D_IN_PROJ 936
#define D_CONV    4
#define EPS       1e-5f

#define BATCH 16
#define CH    19
#define LLEN  30
#define SEQ   570
#define NTOK  9120
#define NFREQ 101

typedef __attribute__((ext_vector_type(8))) short s8v;
typedef __attribute__((ext_vector_type(4))) float f32x4;

__device__ __forceinline__ short f2bf(float f) {
    unsigned u = __float_as_uint(f);
    u += 0x7FFFu + ((u >> 16) & 1u);      // RNE
    return (short)(u >> 16);
}

// ---------------------------------------------------------------------------
// bf16 MFMA GEMM: C[M,N] = A[M,Kp] @ W[N,Kp]^T (+bias) (+C if accum)
// A,W bf16 row-major with row stride Kp (multiple of 32, zero-padded).
// 128x128 block tile, 4 waves in 2x2, each wave 64x64 via 4x4 MFMA tiles.
__global__ __launch_bounds__(256) void gemm_bf16(
    const short* __restrict__ A, const short* __restrict__ W,
    const float* __restrict__ bias, float* __restrict__ C,
    int M, int N, int Kp, int accum)
{
    __shared__ __align__(16) short As[128][40];
    __shared__ __align__(16) short Ws[128][40];

    int bm = blockIdx.y * 128;
    int bn = blockIdx.x * 128;
    int tid = threadIdx.x;
    int lane = tid & 63;
    int wv = tid >> 6;
    int wm = wv & 1, wn = wv >> 1;        // 2x2 wave grid
    int lm = lane & 15, lg = lane >> 4;

    int sr = tid >> 1;                    // staging row 0..127
    int sh_ = (tid & 1) * 16;             // staging k offset 0 or 16

    f32x4 acc[4][4];
#pragma unroll
    for (int i = 0; i < 4; i++)
#pragma unroll
        for (int j = 0; j < 4; j++) acc[i][j] = (f32x4)0.f;

    for (int k0 = 0; k0 < Kp; k0 += 32) {
        {   // stage A
            s8v v0 = (s8v)0, v1 = (s8v)0;
            if (bm + sr < M) {
                const short* ga = A + (size_t)(bm + sr) * Kp + k0 + sh_;
                v0 = *(const s8v*)ga;
                v1 = *(const s8v*)(ga + 8);
            }
            *(s8v*)&As[sr][sh_] = v0;
            *(s8v*)&As[sr][sh_ + 8] = v1;
        }
        {   // stage W
            s8v v0 = (s8v)0, v1 = (s8v)0;
            if (bn + sr < N) {
                const short* gw = W + (size_t)(bn + sr) * Kp + k0 + sh_;
                v0 = *(const s8v*)gw;
                v1 = *(const s8v*)(gw + 8);
            }
            *(s8v*)&Ws[sr][sh_] = v0;
            *(s8v*)&Ws[sr][sh_ + 8] = v1;
        }
        __syncthreads();

        s8v af[4], bf[4];
#pragma unroll
        for (int i = 0; i < 4; i++)
            af[i] = *(const s8v*)&As[wm * 64 + i * 16 + lm][lg * 8];
#pragma unroll
        for (int j = 0; j < 4; j++)
            bf[j] = *(const s8v*)&Ws[wn * 64 + j * 16 + lm][lg * 8];
#pragma unroll
        for (int i = 0; i < 4; i++)
#pragma unroll
            for (int j = 0; j < 4; j++)
                acc[i][j] = __builtin_amdgcn_mfma_f32_16x16x32_bf16(
                    af[i], bf[j], acc[i][j], 0, 0, 0);
        __syncthreads();
    }

    // epilogue: D row m=(lane>>4)*4+r (from A), col n=lane&15 (from W)
#pragma unroll
    for (int j = 0; j < 4; j++) {
        int n = bn + wn * 64 + j * 16 + lm;
        if (n >= N) continue;
        float bv = bias ? bias[n] : 0.f;
#pragma unroll
        for (int i = 0; i < 4; i++) {
            int mbase = bm + wm * 64 + i * 16 + lg * 4;
#pragma unroll
            for (int r = 0; r < 4; r++) {
                int m = mbase + r;
                if (m >= M) continue;
                size_t idx = (size_t)m * N + n;
                float v = acc[i][j][r] + bv;
                if (accum) v += C[idx];
                C[idx] = v;
            }
        }
    }
}

// ---------------------------------------------------------------------------
// fp32 GEMM (fallback path):  C[M,N] = A[M,K] @ W[N,K]^T (+bias) (+C)
__global__ __launch_bounds__(256) void gemm_nt(
    const float* __restrict__ A, const float* __restrict__ W,
    const float* __restrict__ bias, float* __restrict__ C,
    int M, int N, int K, int accum)
{
    const int BM = 128, BK = 16;
    __shared__ float As[16][BM + 4];
    __shared__ float Ws[16][BM + 4];

    int bm = blockIdx.y * BM;
    int bn = blockIdx.x * BM;
    int tid = threadIdx.x;
    int lr = tid >> 1;
    int lc = (tid & 1) * 8;
    int tx = tid & 15;
    int ty = tid >> 4;

    float acc[8][8];
#pragma unroll
    for (int i = 0; i < 8; i++)
#pragma unroll
        for (int j = 0; j < 8; j++) acc[i][j] = 0.f;

    for (int k0 = 0; k0 < K; k0 += BK) {
#pragma unroll
        for (int i = 0; i < 8; i++) {
            int gr = bm + lr, gk = k0 + lc + i;
            As[lc + i][lr] = (gr < M && gk < K) ? A[(size_t)gr * K + gk] : 0.f;
        }
#pragma unroll
        for (int i = 0; i < 8; i++) {
            int gr = bn + lr, gk = k0 + lc + i;
            Ws[lc + i][lr] = (gr < N && gk < K) ? W[(size_t)gr * K + gk] : 0.f;
        }
        __syncthreads();
#pragma unroll
        for (int kk = 0; kk < BK; kk++) {
            float a[8], bv[8];
#pragma unroll
            for (int i = 0; i < 8; i++) a[i] = As[kk][ty * 8 + i];
#pragma unroll
            for (int j = 0; j < 8; j++) bv[j] = Ws[kk][tx * 8 + j];
#pragma unroll
            for (int i = 0; i < 8; i++)
#pragma unroll
                for (int j = 0; j < 8; j++)
                    acc[i][j] = fmaf(a[i], bv[j], acc[i][j]);
        }
        __syncthreads();
    }

#pragma unroll
    for (int i = 0; i < 8; i++) {
        int gm = bm + ty * 8 + i;
        if (gm >= M) continue;
#pragma unroll
        for (int j = 0; j < 8; j++) {
            int gn = bn + tx * 8 + j;
            if (gn >= N) continue;
            float v = acc[i][j];
            if (bias) v += bias[gn];
            if (accum) v += C[(size_t)gm * N + gn];
            C[(size_t)gm * N + gn] = v;
        }
    }
}

// ---------------------------------------------------------------------------
// cast fp32 [R][K] -> bf16 [R][Kp] zero-padded
__global__ __launch_bounds__(256) void cast_pad_kernel(
    const float* __restrict__ src, short* __restrict__ dst,
    int R, int K, int Kp)
{
    int idx = blockIdx.x * 256 + threadIdx.x;
    if (idx >= R * Kp) return;
    int r = idx / Kp, k = idx - r * Kp;
    dst[idx] = (k < K) ? f2bf(src[(size_t)r * K + k]) : (short)0;
}

// ---------------------------------------------------------------------------
// patch embed: time conv
__global__ __launch_bounds__(256) void time_conv_kernel(
    const float* __restrict__ x, const float* __restrict__ pw,
    float* __restrict__ traw)
{
    int br = blockIdx.x;
    __shared__ float xr[200];
    if (threadIdx.x < 200) xr[threadIdx.x] = x[(size_t)br * 200 + threadIdx.x];
    __syncthreads();
    if (threadIdx.x < 200) {
        int oc = threadIdx.x >> 3, j = threadIdx.x & 7;
        int start = j * 25 - 24;
        float acc = 0.f;
#pragma unroll
        for (int k = 0; k < 49; k++) {
            int d = start + k;
            if (d >= 0 && d < 200) acc = fmaf(xr[d], pw[oc * 49 + k], acc);
        }
        int b = br / SEQ, row = br % SEQ;
        traw[(((size_t)b * 25 + oc) * SEQ + row) * 8 + j] = acc;
    }
}

__global__ __launch_bounds__(256) void gn_stats_kernel(
    const float* __restrict__ traw, float* __restrict__ stats)
{
    int bg = blockIdx.x;
    int b = bg / 5, g = bg % 5;
    const float* base = traw + ((size_t)b * 25 + g * 5) * SEQ * 8;
    float s = 0.f, q = 0.f;
    for (int i = threadIdx.x; i < 5 * SEQ * 8; i += 256) {
        float v = base[i];
        s += v; q = fmaf(v, v, q);
    }
    __shared__ float rs[4], rq[4];
    int lane = threadIdx.x & 63, w = threadIdx.x >> 6;
#pragma unroll
    for (int o = 32; o; o >>= 1) { s += __shfl_xor(s, o, 64); q += __shfl_xor(q, o, 64); }
    if (lane == 0) { rs[w] = s; rq[w] = q; }
    __syncthreads();
    if (threadIdx.x == 0) {
        float S = rs[0] + rs[1] + rs[2] + rs[3];
        float Q = rq[0] + rq[1] + rq[2] + rq[3];
        float inv = 1.f / (5.f * SEQ * 8.f);
        float mean = S * inv;
        float var = Q * inv - mean * mean;
        stats[bg * 2] = mean;
        stats[bg * 2 + 1] = rsqrtf(var + EPS);
    }
}

__global__ __launch_bounds__(256) void gn_gelu_kernel(
    const float* __restrict__ traw, const float* __restrict__ stats,
    const float* __restrict__ gn_g, const float* __restrict__ gn_b,
    float* __restrict__ patch)
{
    int idx = blockIdx.x * 256 + threadIdx.x;
    if (idx >= NTOK * 200) return;
    int d = idx % 200;
    int row = (idx / 200) % SEQ;
    int b = idx / (200 * SEQ);
    int oc = d >> 3, j = d & 7;
    float v = traw[(((size_t)b * 25 + oc) * SEQ + row) * 8 + j];
    int g = oc / 5;
    float mean = stats[(b * 5 + g) * 2];
    float rstd = stats[(b * 5 + g) * 2 + 1];
    v = (v - mean) * rstd * gn_g[oc] + gn_b[oc];
    float ge = 0.5f * v * (1.f + erff(v * 0.70710678118654752f));
    patch[idx] = ge;
}

// DFT matrix, fp32 (fallback)
__global__ __launch_bounds__(256) void dft_init_kernel(float* __restrict__ CS)
{
    int idx = blockIdx.x * 256 + threadIdx.x;
    if (idx >= 202 * 200) return;
    int f = idx / 200, d = idx % 200;
    int fr = (f < NFREQ) ? f : (f - NFREQ);
    int m = (fr * d) % 200;
    float ang = -6.283185307179586f * (float)m * (1.f / 200.f);
    CS[idx] = (f < NFREQ) ? cosf(ang) : sinf(ang);
}

// DFT matrix, bf16 padded [202][224] (fast)
__global__ __launch_bounds__(256) void dft_init_bf_kernel(short* __restrict__ CS)
{
    int idx = blockIdx.x * 256 + threadIdx.x;
    if (idx >= 202 * 224) return;
    int f = idx / 224, d = idx - f * 224;
    short out = 0;
    if (d < 200) {
        int fr = (f < NFREQ) ? f : (f - NFREQ);
        int m = (fr * d) % 200;
        float ang = -6.283185307179586f * (float)m * (1.f / 200.f);
        out = f2bf((f < NFREQ) ? cosf(ang) : sinf(ang));
    }
    CS[idx] = out;
}

// magnitude fp32 (fallback)
__global__ __launch_bounds__(256) void mag_kernel(
    const float* __restrict__ cs_out, float* __restrict__ magv)
{
    int idx = blockIdx.x * 256 + threadIdx.x;
    if (idx >= NTOK * NFREQ) return;
    int m = idx / NFREQ, f = idx % NFREQ;
    float re = cs_out[(size_t)m * 202 + f];
    float im = cs_out[(size_t)m * 202 + NFREQ + f];
    magv[idx] = sqrtf(re * re + im * im) * 0.005f;
}

// magnitude bf16 padded [NTOK][128] (fast)
__global__ __launch_bounds__(256) void mag_bf_kernel(
    const float* __restrict__ cs_out, short* __restrict__ magv)
{
    int idx = blockIdx.x * 256 + threadIdx.x;
    if (idx >= NTOK * 128) return;
    int m = idx >> 7, f = idx & 127;
    short out = 0;
    if (f < NFREQ) {
        float re = cs_out[(size_t)m * 202 + f];
        float im = cs_out[(size_t)m * 202 + NFREQ + f];
        out = f2bf(sqrtf(re * re + im * im) * 0.005f);
    }
    magv[idx] = out;
}

// ---------------------------------------------------------------------------
// depthwise 7x7 pos conv + residual, LDS-tiled: block = (b, 16-d slice)
__global__ __launch_bounds__(256) void pe_conv2_kernel(
    const float* __restrict__ patch, const float* __restrict__ pw,
    float* __restrict__ hidden)
{
    int b = blockIdx.x, dc = blockIdx.y;
    int d0 = dc * 16;
    __shared__ float pl[SEQ * 16];
    __shared__ float wl[49][16];
    int tid = threadIdx.x;
    int dd = tid & 15, grp = tid >> 4;
    int d = d0 + dd;

    for (int i = tid; i < SEQ * 16; i += 256) {
        int cl = i >> 4, dl = d0 + (i & 15);
        pl[i] = (dl < 200) ? patch[((size_t)b * SEQ + cl) * 200 + dl] : 0.f;
    }
    for (int i = tid; i < 49 * 16; i += 256) {
        int k = i >> 4; int dl = d0 + (i & 15);
        wl[k][i & 15] = (dl < 200) ? pw[(size_t)dl * 49 + k] : 0.f;
    }
    __syncthreads();

    float wreg[49];
#pragma unroll
    for (int k = 0; k < 49; k++) wreg[k] = wl[k][dd];

    for (int ocl = grp; ocl < SEQ; ocl += 16) {
        int c = ocl / LLEN, l = ocl % LLEN;
        float acc = pl[ocl * 16 + dd];
#pragma unroll
        for (int i = 0; i < 7; i++) {
            int cc = c + i - 3;
            if (cc < 0 || cc >= CH) continue;
#pragma unroll
            for (int j = 0; j < 7; j++) {
                int ll = l + j - 3;
                if (ll < 0 || ll >= LLEN) continue;
                acc = fmaf(pl[(cc * LLEN + ll) * 16 + dd], wreg[i * 7 + j], acc);
            }
        }
        if (d < 200) hidden[((size_t)b * SEQ + ocl) * 200 + d] = acc;
    }
}

// ---------------------------------------------------------------------------
// residual += hidden; u = rmsnorm(residual)*wn; optional padded bf16 copy
__global__ __launch_bounds__(64) void add_rmsnorm_kernel(
    const float* __restrict__ hidden, float* __restrict__ residual,
    const float* __restrict__ wn, float* __restrict__ u,
    short* __restrict__ ubf, int first)
{
    int m = blockIdx.x;
    int lane = threadIdx.x;
    const float* hr = hidden + (size_t)m * 200;
    float* rr = residual + (size_t)m * 200;
    float v[4];
    float ss = 0.f;
#pragma unroll
    for (int i = 0; i < 4; i++) {
        int k = lane + i * 64;
        float xv = 0.f;
        if (k < 200) {
            xv = hr[k] + (first ? 0.f : rr[k]);
            rr[k] = xv;
        }
        v[i] = xv;
        ss = fmaf(xv, xv, ss);
    }
#pragma unroll
    for (int o = 32; o; o >>= 1) ss += __shfl_xor(ss, o, 64);
    float rstd = rsqrtf(ss * (1.f / 200.f) + EPS);
#pragma unroll
    for (int i = 0; i < 4; i++) {
        int k = lane + i * 64;
        float val = v[i] * rstd * ((k < 200) ? wn[k] : 0.f);
        if (k < 200) u[(size_t)m * 200 + k] = val;
        if (ubf) {
            if (k < 200) ubf[(size_t)m * 224 + k] = f2bf(val);
            else if (k < 224) ubf[(size_t)m * 224 + k] = 0;
        }
    }
}

// ---------------------------------------------------------------------------
// fp32 dt GEMV: dtb[bt][h] = softplus(u[bt]·Win[928+h] + dt_bias[h])
// grid NTOK/4, 256 thr: wave=token, (tid>>3)&7=head, tid&7=k-lane
__global__ __launch_bounds__(256) void dt_gemv_kernel(
    const float* __restrict__ u, const float* __restrict__ Win,
    const float* __restrict__ dt_bias, float* __restrict__ dtb, int layer)
{
    int tid = threadIdx.x;
    int tok = blockIdx.x * 4 + (tid >> 6);
    int head = (tid >> 3) & 7;
    int l8 = tid & 7;
    const float* ur = u + (size_t)tok * 200;
    const float* wr = Win + (size_t)layer * D_IN_PROJ * 200 + (size_t)(928 + head) * 200;
    float s = 0.f;
    for (int k = l8; k < 200; k += 8) s = fmaf(ur[k], wr[k], s);
    s += __shfl_xor(s, 1, 64);
    s += __shfl_xor(s, 2, 64);
    s += __shfl_xor(s, 4, 64);
    if (l8 == 0) {
        float raw = s + dt_bias[layer * NHEADS + head];
        dtb[(size_t)tok * NHEADS + head] = (raw > 20.f) ? raw : log1pf(expf(raw));
    }
}

// ---------------------------------------------------------------------------
// xBC = silu(causal depthwise conv4 of zxbcdt cols [400,928))
__global__ __launch_bounds__(256) void dtconv_kernel(
    const float* __restrict__ zxbcdt, const float* __restrict__ cw,
    const float* __restrict__ cb, float* __restrict__ xBC, int layer)
{
    int bt = blockIdx.x;
    int b = bt / SEQ, t = bt % SEQ;
    const float* cwl = cw + (size_t)layer * CONV_DIM * 4;
    const float* cbl = cb + (size_t)layer * CONV_DIM;
    for (int ch = threadIdx.x; ch < CONV_DIM; ch += 256) {
        float acc = cbl[ch];
#pragma unroll
        for (int k = 0; k < 4; k++) {
            int tt = t - 3 + k;
            if (tt >= 0)
                acc = fmaf(zxbcdt[(size_t)(b * SEQ + tt) * D_IN_PROJ + D_INNER + ch],
                           cwl[ch * 4 + k], acc);
        }
        float s = acc / (1.f + expf(-acc));
        xBC[(size_t)bt * CONV_DIM + ch] = s;
    }
}

// ---------------------------------------------------------------------------
// Chunked SSD scan (LDS-staged, 8 heads per 512-thr block)
__global__ __launch_bounds__(512) void ssd_state_kernel(
    const float* __restrict__ xBC, const float* __restrict__ dtb,
    const float* __restrict__ A_log, float* __restrict__ Sbuf,
    float* __restrict__ Pd, int layer, int lchunk, int nchunk)
{
    int b = blockIdx.x, c = blockIdx.y;
    int tid = threadIdx.x;
    int h = tid >> 6, p = tid & 63;
    float A = -expf(A_log[layer * NHEADS + h]);

    __shared__ float sh[2][544];
    int t0 = c * lchunk, tend = t0 + lchunk;

    {
        const float* base = xBC + (size_t)(b * SEQ + t0) * CONV_DIM;
        sh[0][tid] = base[tid];
        if (tid < 24) {
            int e2 = 512 + tid;
            sh[0][e2] = (e2 < 528) ? base[e2]
                                   : dtb[(size_t)(b * SEQ + t0) * NHEADS + (e2 - 528)];
        }
    }
    __syncthreads();

    float s[64];
#pragma unroll
    for (int n = 0; n < 64; n++) s[n] = 0.f;
    float pacc = 1.f;

    for (int t = t0; t < tend; t++) {
        int cur = (t - t0) & 1, nxt = cur ^ 1;
        float pf0 = 0.f, pf1 = 0.f;
        if (t + 1 < tend) {
            const float* base = xBC + (size_t)(b * SEQ + t + 1) * CONV_DIM;
            pf0 = base[tid];
            if (tid < 24) {
                int e2 = 512 + tid;
                pf1 = (e2 < 528) ? base[e2]
                                 : dtb[(size_t)(b * SEQ + t + 1) * NHEADS + (e2 - 528)];
            }
        }
        float dtv = sh[cur][528 + h];
        float xp  = (p < HEADDIM) ? sh[cur][h * HEADDIM + p] : 0.f;
        float dA = __expf(dtv * A);
        float u  = dtv * xp;
        pacc *= dA;
        const float4* B4 = (const float4*)&sh[cur][D_INNER];
#pragma unroll
        for (int n4 = 0; n4 < 16; n4++) {
            float4 bq = B4[n4];
            s[4 * n4 + 0] = fmaf(s[4 * n4 + 0], dA, u * bq.x);
            s[4 * n4 + 1] = fmaf(s[4 * n4 + 1], dA, u * bq.y);
            s[4 * n4 + 2] = fmaf(s[4 * n4 + 2], dA, u * bq.z);
            s[4 * n4 + 3] = fmaf(s[4 * n4 + 3], dA, u * bq.w);
        }
        if (t + 1 < tend) {
            sh[nxt][tid] = pf0;
            if (tid < 24) sh[nxt][512 + tid] = pf1;
        }
        __syncthreads();
    }

    if (p < HEADDIM) {
        float* Sb = Sbuf + ((size_t)((b * NHEADS + h) * nchunk + c)) * (HEADDIM * 64)
                    + p * 64;
#pragma unroll
        for (int n4 = 0; n4 < 16; n4++)
            ((float4*)Sb)[n4] = make_float4(s[4 * n4], s[4 * n4 + 1],
                                            s[4 * n4 + 2], s[4 * n4 + 3]);
    }
    if (p == 0) Pd[(b * NHEADS + h) * nchunk + c] = pacc;
}

__global__ __launch_bounds__(256) void ssd_scan2_kernel(
    float* __restrict__ Sbuf, const float* __restrict__ Pd, int nchunk)
{
    int bh = blockIdx.x;
    float* base = Sbuf + (size_t)bh * nchunk * (HEADDIM * 64);
    const float* pd = Pd + bh * nchunk;
    for (int e = threadIdx.x; e < HEADDIM * 64; e += 256) {
        float cur = 0.f;
        for (int c = 0; c < nchunk; c++) {
            float l = base[(size_t)c * (HEADDIM * 64) + e];
            base[(size_t)c * (HEADDIM * 64) + e] = cur;
            cur = fmaf(pd[c], cur, l);
        }
    }
}

__global__ __launch_bounds__(512) void ssd_out_kernel(
    const float* __restrict__ xBC, const float* __restrict__ dtb,
    const float* __restrict__ A_log, const float* __restrict__ Dv,
    const float* __restrict__ Sbuf, float* __restrict__ y,
    int layer, int lchunk, int nchunk)
{
    int b = blockIdx.x, c = blockIdx.y;
    int tid = threadIdx.x;
    int h = tid >> 6, p = tid & 63;
    float A = -expf(A_log[layer * NHEADS + h]);
    float Dh = Dv[layer * NHEADS + h];

    __shared__ float sh[2][544];
    int t0 = c * lchunk, tend = t0 + lchunk;

    {
        const float* base = xBC + (size_t)(b * SEQ + t0) * CONV_DIM;
        sh[0][tid] = base[tid];
        if (tid < 24) {
            int e2 = 512 + tid;
            sh[0][e2] = (e2 < 528) ? base[e2]
                                   : dtb[(size_t)(b * SEQ + t0) * NHEADS + (e2 - 528)];
        }
    }

    float s[64];
    if (p < HEADDIM) {
        const float* Sb = Sbuf + ((size_t)((b * NHEADS + h) * nchunk + c)) * (HEADDIM * 64)
                          + p * 64;
#pragma unroll
        for (int n4 = 0; n4 < 16; n4++) {
            float4 v = ((const float4*)Sb)[n4];
            s[4 * n4] = v.x; s[4 * n4 + 1] = v.y; s[4 * n4 + 2] = v.z; s[4 * n4 + 3] = v.w;
        }
    } else {
#pragma unroll
        for (int n = 0; n < 64; n++) s[n] = 0.f;
    }
    __syncthreads();

    for (int t = t0; t < tend; t++) {
        int cur = (t - t0) & 1, nxt = cur ^ 1;
        float pf0 = 0.f, pf1 = 0.f;
        if (t + 1 < tend) {
            const float* base = xBC + (size_t)(b * SEQ + t + 1) * CONV_DIM;
            pf0 = base[tid];
            if (tid < 24) {
                int e2 = 512 + tid;
                pf1 = (e2 < 528) ? base[e2]
                                 : dtb[(size_t)(b * SEQ + t + 1) * NHEADS + (e2 - 528)];
            }
        }
        float dtv = sh[cur][528 + h];
        float xp  = (p < HEADDIM) ? sh[cur][h * HEADDIM + p] : 0.f;
        float dA = __expf(dtv * A);
        float u  = dtv * xp;
        const float4* B4 = (const float4*)&sh[cur][D_INNER];
        const float4* C4 = (const float4*)&sh[cur][D_INNER + D_STATE];
        float y0 = 0.f, y1 = 0.f, y2 = 0.f, y3 = 0.f;
#pragma unroll
        for (int n4 = 0; n4 < 16; n4++) {
            float4 bq = B4[n4];
            float4 cq = C4[n4];
            float t0v = fmaf(s[4 * n4 + 0], dA, u * bq.x);
            float t1v = fmaf(s[4 * n4 + 1], dA, u * bq.y);
            float t2v = fmaf(s[4 * n4 + 2], dA, u * bq.z);
            float t3v = fmaf(s[4 * n4 + 3], dA, u * bq.w);
            s[4 * n4 + 0] = t0v; s[4 * n4 + 1] = t1v;
            s[4 * n4 + 2] = t2v; s[4 * n4 + 3] = t3v;
            y0 = fmaf(t0v, cq.x, y0);
            y1 = fmaf(t1v, cq.y, y1);
            y2 = fmaf(t2v, cq.z, y2);
            y3 = fmaf(t3v, cq.w, y3);
        }
        if (p < HEADDIM) {
            float yv = (y0 + y1) + (y2 + y3);
            y[(size_t)(b * SEQ + t) * D_INNER + h * HEADDIM + p] = fmaf(xp, Dh, yv);
        }
        if (t + 1 < tend) {
            sh[nxt][tid] = pf0;
            if (tid < 24) sh[nxt][512 + tid] = pf1;
        }
        __syncthreads();
    }
}

// ---------------------------------------------------------------------------
// y = rmsnorm(y * silu(z), gw); optional padded bf16 copy (stride 416)
__global__ __launch_bounds__(256) void gate_norm_kernel(
    float* __restrict__ y, const float* __restrict__ zxbcdt,
    const float* __restrict__ gw, short* __restrict__ ybf, int layer)
{
    int m = blockIdx.x;
    __shared__ float buf[D_INNER];
    __shared__ float red[4];
    const float* z = zxbcdt + (size_t)m * D_IN_PROJ;
    float* yr = y + (size_t)m * D_INNER;
    const float* gwl = gw + (size_t)layer * D_INNER;
    float ss = 0.f;
    for (int k = threadIdx.x; k < D_INNER; k += 256) {
        float zv = z[k];
        float sz = zv / (1.f + expf(-zv));
        float g = yr[k] * sz;
        buf[k] = g;
        ss = fmaf(g, g, ss);
    }
    int lane = threadIdx.x & 63, w = threadIdx.x >> 6;
#pragma unroll
    for (int o = 32; o; o >>= 1) ss += __shfl_xor(ss, o, 64);
    if (lane == 0) red[w] = ss;
    __syncthreads();
    float tot = red[0] + red[1] + red[2] + red[3];
    float rstd = rsqrtf(tot * (1.f / D_INNER) + EPS);
    for (int k = threadIdx.x; k < 416; k += 256) {
        if (k < D_INNER) {
            float v = buf[k] * rstd * gwl[k];
            yr[k] = v;
            if (ybf) ybf[(size_t)m * 416 + k] = f2bf(v);
        } else if (ybf) {
            ybf[(size_t)m * 416 + k] = 0;
        }
    }
}

// ---------------------------------------------------------------------------
extern "C" void kernel_launch(void* const* d_in, const int* in_sizes, int n_in,
                              void* d_out, int out_size, void* d_ws, size_t ws_size,
                              hipStream_t stream)
{
    const float* x         = (const float*)d_in[0];
    const float* pe_conv_w = (const float*)d_in[1];
    const float* proj_in_w = (const float*)d_in[2];
    const float* gn_g      = (const float*)d_in[3];
    const float* gn_b      = (const float*)d_in[4];
    const float* spec_w    = (const float*)d_in[5];
    const float* norm_w    = (const float*)d_in[6];
    const float* in_proj_w = (const float*)d_in[7];
    const float* conv_w    = (const float*)d_in[8];
    const float* conv_b    = (const float*)d_in[9];
    const float* dt_bias   = (const float*)d_in[10];
    const float* A_log     = (const float*)d_in[11];
    const float* Dv        = (const float*)d_in[12];
    const float* gnorm_w   = (const float*)d_in[13];
    const float* out_proj_w= (const float*)d_in[14];
    const float* norm_f_w  = (const float*)d_in[15];
    const float* head_w    = (const float*)d_in[16];
    const float* head_b    = (const float*)d_in[17];
    float* out = (float*)d_out;
    float* ws  = (float*)d_ws;

    // fp32 region (both paths)
    float* residual = ws;                       // 1,824,000
    float* hidden   = ws + 1824000;             // 1,824,000
    float* ubuf     = ws + 3648000;             // 1,824,000
    float* zxbcdt   = ws + 5472000;             // 8,536,320
    float* xBC      = ws + 14008320;            // 4,815,360
    float* dtb      = ws + 18823680;            // 72,960
    float* ybuf     = ws + 18896640;            // 3,648,000 -> ends 22,544,640

    // fast-path tail: 15-chunk Sbuf + bf16 pool. Deterministic in ws_size.
    const size_t needA = 35029088ull * sizeof(float);   // ~140.1 MB
    int fast = (ws_size >= needA) ? 1 : 0;

    int nchunk, lchunk;
    float *Sbuf, *Pd;
    short *w_in_bf = nullptr, *w_out_bf = nullptr, *w_head_bf = nullptr,
          *w_spec_bf = nullptr, *csmat_bf = nullptr, *x_bf = nullptr,
          *ubuf_bf = nullptr, *ybuf_bf = nullptr, *magb_bf = nullptr;
    if (fast) {
        nchunk = 15; lchunk = 38;
        Sbuf = ws + 22544640;                   // 6,144,000
        Pd   = ws + 28688640;                   // 1,920
        short* pool = (short*)(ws + 28690560);
        w_in_bf   = pool;                       // 12*936*224 = 2,515,968
        w_out_bf  = pool + 2515968;             // 12*200*416 =   998,400
        w_head_bf = pool + 3514368;             // 200*224    =    44,800
        w_spec_bf = pool + 3559168;             // 200*128    =    25,600
        csmat_bf  = pool + 3584768;             // 202*224    =    45,248
        x_bf      = pool + 3630016;             // 9120*224   = 2,042,880
        ubuf_bf   = pool + 5672896;             // 9120*224   = 2,042,880
        ybuf_bf   = pool + 7715776;             // 9120*416   = 3,793,920
        magb_bf   = pool + 11509696;            // 9120*128   = 1,167,360
    } else {
        nchunk = 6; lchunk = 95;
        Sbuf = ws + 1824000;                    // dead hidden(+ubuf head)
        Pd   = ws + 5470000;                    // dead ubuf tail
    }

    // pre-layer aliases (dead layer buffers)
    float* traw  = ybuf;
    float* patch = zxbcdt;
    float* csmat = xBC;                         // fallback fp32 DFT matrix
    float* csout = xBC + 50000;                 // 9120*202
    float* magb  = xBC + 2000000;               // fallback fp32 magnitudes
    float* stats = dtb;

    // ---- weight / input casts (fast) ----
    if (fast) {
        cast_pad_kernel<<<(12 * 936 * 224 + 255) / 256, 256, 0, stream>>>(
            in_proj_w, w_in_bf, 12 * 936, 200, 224);
        cast_pad_kernel<<<(12 * 200 * 416 + 255) / 256, 256, 0, stream>>>(
            out_proj_w, w_out_bf, 12 * 200, 400, 416);
        cast_pad_kernel<<<(200 * 224 + 255) / 256, 256, 0, stream>>>(
            head_w, w_head_bf, 200, 200, 224);
        cast_pad_kernel<<<(200 * 128 + 255) / 256, 256, 0, stream>>>(
            spec_w, w_spec_bf, 200, 101, 128);
        cast_pad_kernel<<<(9120 * 224 + 255) / 256, 256, 0, stream>>>(
            x, x_bf, 9120, 200, 224);
        dft_init_bf_kernel<<<(202 * 224 + 255) / 256, 256, 0, stream>>>(csmat_bf);
    } else {
        dft_init_kernel<<<(202 * 200 + 255) / 256, 256, 0, stream>>>(csmat);
    }

    // ---- patch embed ----
    time_conv_kernel<<<NTOK, 256, 0, stream>>>(x, proj_in_w, traw);
    gn_stats_kernel<<<80, 256, 0, stream>>>(traw, stats);
    gn_gelu_kernel<<<(NTOK * 200 + 255) / 256, 256, 0, stream>>>(traw, stats, gn_g, gn_b, patch);
    if (fast) {
        gemm_bf16<<<dim3(2, 72), 256, 0, stream>>>(x_bf, csmat_bf, nullptr, csout,
                                                   NTOK, 202, 224, 0);
        mag_bf_kernel<<<(NTOK * 128 + 255) / 256, 256, 0, stream>>>(csout, magb_bf);
        gemm_bf16<<<dim3(2, 72), 256, 0, stream>>>(magb_bf, w_spec_bf, nullptr, patch,
                                                   NTOK, 200, 128, 1);
    } else {
        gemm_nt<<<dim3(2, 72), 256, 0, stream>>>(x, csmat, nullptr, csout, NTOK, 202, 200, 0);
        mag_kernel<<<(NTOK * NFREQ + 255) / 256, 256, 0, stream>>>(csout, magb);
        gemm_nt<<<dim3(2, 72), 256, 0, stream>>>(magb, spec_w, nullptr, patch,
                                                 NTOK, 200, NFREQ, 1);
    }
    pe_conv2_kernel<<<dim3(16, 13), 256, 0, stream>>>(patch, pe_conv_w, hidden);

    // ---- layers ----
    for (int i = 0; i < N_LAYER; i++) {
        add_rmsnorm_kernel<<<NTOK, 64, 0, stream>>>(hidden, residual, norm_w + i * 200,
                                                    ubuf, ubuf_bf, (i == 0) ? 1 : 0);
        dt_gemv_kernel<<<NTOK / 4, 256, 0, stream>>>(ubuf, in_proj_w, dt_bias, dtb, i);
        if (fast) {
            gemm_bf16<<<dim3(8, 72), 256, 0, stream>>>(
                ubuf_bf, w_in_bf + (size_t)i * 936 * 224, nullptr, zxbcdt,
                NTOK, D_IN_PROJ, 224, 0);
        } else {
            gemm_nt<<<dim3(8, 72), 256, 0, stream>>>(
                ubuf, in_proj_w + (size_t)i * D_IN_PROJ * 200, nullptr, zxbcdt,
                NTOK, D_IN_PROJ, 200, 0);
        }
        dtconv_kernel<<<NTOK, 256, 0, stream>>>(zxbcdt, conv_w, conv_b, xBC, i);
        {
            dim3 g(BATCH, nchunk);
            ssd_state_kernel<<<g, 512, 0, stream>>>(xBC, dtb, A_log, Sbuf, Pd, i, lchunk, nchunk);
            ssd_scan2_kernel<<<BATCH * NHEADS, 256, 0, stream>>>(Sbuf, Pd, nchunk);
            ssd_out_kernel<<<g, 512, 0, stream>>>(xBC, dtb, A_log, Dv, Sbuf, ybuf, i, lchunk, nchunk);
        }
        gate_norm_kernel<<<NTOK, 256, 0, stream>>>(ybuf, zxbcdt, gnorm_w, ybuf_bf, i);
        if (fast) {
            gemm_bf16<<<dim3(2, 72), 256, 0, stream>>>(
                ybuf_bf, w_out_bf + (size_t)i * 200 * 416, nullptr, hidden,
                NTOK, 200, 416, 0);
        } else {
            gemm_nt<<<dim3(2, 72), 256, 0, stream>>>(
                ybuf, out_proj_w + (size_t)i * 200 * D_INNER, nullptr, hidden,
                NTOK, 200, D_INNER, 0);
        }
    }

    // ---- final norm + head ----
    add_rmsnorm_kernel<<<NTOK, 64, 0, stream>>>(hidden, residual, norm_f_w, ubuf, ubuf_bf, 0);
    if (fast) {
        gemm_bf16<<<dim3(2, 72), 256, 0, stream>>>(ubuf_bf, w_head_bf, head_b, out,
                                                   NTOK, 200, 224, 0);
    } else {
        gemm_nt<<<dim3(2, 72), 256, 0, stream>>>(ubuf, head_w, head_b, out,
                                                 NTOK, 200, 200, 0);
    }
}

// Round 5
// 3157.808 us; speedup vs baseline: 8.0949x; 1.0341x over previous
//
#include <hip/hip_runtime.h>
#include <hip/hip_bf16.h>
#include <math.h>

// ---------------------------------------------------------------------------
// EEGMamba forward. Round 5: tiled pe_conv, norm+dt fusion, tiled dtconv,
// gate/rmsnorm fused into SSD pass-3 (ybf written directly by the scan).
#define D_MODEL   200
#define N_LAYER   12
#define NHEADS    8
#define HEADDIM   50
#define D_STATE   64
#define D_INNER   400
#define CONV_DIM  528
#define D_IN_PROJ 936
#define D_CONV    4
#define EPS       1e-5f

#define BATCH 16
#define CH    19
#define LLEN  30
#define SEQ   570
#define NTOK  9120
#define NFREQ 101

typedef __attribute__((ext_vector_type(8))) short s8v;
typedef __attribute__((ext_vector_type(4))) float f32x4;

__device__ __forceinline__ short f2bf(float f) {
    unsigned u = __float_as_uint(f);
    u += 0x7FFFu + ((u >> 16) & 1u);      // RNE
    return (short)(u >> 16);
}

// ---------------------------------------------------------------------------
// bf16 MFMA GEMM: C[M,N] = A[M,Kp] @ W[N,Kp]^T (+bias) (+C if accum)
__global__ __launch_bounds__(256) void gemm_bf16(
    const short* __restrict__ A, const short* __restrict__ W,
    const float* __restrict__ bias, float* __restrict__ C,
    int M, int N, int Kp, int accum)
{
    __shared__ __align__(16) short As[128][40];
    __shared__ __align__(16) short Ws[128][40];

    int bm = blockIdx.y * 128;
    int bn = blockIdx.x * 128;
    int tid = threadIdx.x;
    int lane = tid & 63;
    int wv = tid >> 6;
    int wm = wv & 1, wn = wv >> 1;
    int lm = lane & 15, lg = lane >> 4;

    int sr = tid >> 1;
    int sh_ = (tid & 1) * 16;

    f32x4 acc[4][4];
#pragma unroll
    for (int i = 0; i < 4; i++)
#pragma unroll
        for (int j = 0; j < 4; j++) acc[i][j] = (f32x4)0.f;

    for (int k0 = 0; k0 < Kp; k0 += 32) {
        {
            s8v v0 = (s8v)0, v1 = (s8v)0;
            if (bm + sr < M) {
                const short* ga = A + (size_t)(bm + sr) * Kp + k0 + sh_;
                v0 = *(const s8v*)ga;
                v1 = *(const s8v*)(ga + 8);
            }
            *(s8v*)&As[sr][sh_] = v0;
            *(s8v*)&As[sr][sh_ + 8] = v1;
        }
        {
            s8v v0 = (s8v)0, v1 = (s8v)0;
            if (bn + sr < N) {
                const short* gw = W + (size_t)(bn + sr) * Kp + k0 + sh_;
                v0 = *(const s8v*)gw;
                v1 = *(const s8v*)(gw + 8);
            }
            *(s8v*)&Ws[sr][sh_] = v0;
            *(s8v*)&Ws[sr][sh_ + 8] = v1;
        }
        __syncthreads();

        s8v af[4], bf[4];
#pragma unroll
        for (int i = 0; i < 4; i++)
            af[i] = *(const s8v*)&As[wm * 64 + i * 16 + lm][lg * 8];
#pragma unroll
        for (int j = 0; j < 4; j++)
            bf[j] = *(const s8v*)&Ws[wn * 64 + j * 16 + lm][lg * 8];
#pragma unroll
        for (int i = 0; i < 4; i++)
#pragma unroll
            for (int j = 0; j < 4; j++)
                acc[i][j] = __builtin_amdgcn_mfma_f32_16x16x32_bf16(
                    af[i], bf[j], acc[i][j], 0, 0, 0);
        __syncthreads();
    }

#pragma unroll
    for (int j = 0; j < 4; j++) {
        int n = bn + wn * 64 + j * 16 + lm;
        if (n >= N) continue;
        float bv = bias ? bias[n] : 0.f;
#pragma unroll
        for (int i = 0; i < 4; i++) {
            int mbase = bm + wm * 64 + i * 16 + lg * 4;
#pragma unroll
            for (int r = 0; r < 4; r++) {
                int m = mbase + r;
                if (m >= M) continue;
                size_t idx = (size_t)m * N + n;
                float v = acc[i][j][r] + bv;
                if (accum) v += C[idx];
                C[idx] = v;
            }
        }
    }
}

// ---------------------------------------------------------------------------
// fp32 GEMM (fallback path)
__global__ __launch_bounds__(256) void gemm_nt(
    const float* __restrict__ A, const float* __restrict__ W,
    const float* __restrict__ bias, float* __restrict__ C,
    int M, int N, int K, int accum)
{
    const int BM = 128, BK = 16;
    __shared__ float As[16][BM + 4];
    __shared__ float Ws[16][BM + 4];

    int bm = blockIdx.y * BM;
    int bn = blockIdx.x * BM;
    int tid = threadIdx.x;
    int lr = tid >> 1;
    int lc = (tid & 1) * 8;
    int tx = tid & 15;
    int ty = tid >> 4;

    float acc[8][8];
#pragma unroll
    for (int i = 0; i < 8; i++)
#pragma unroll
        for (int j = 0; j < 8; j++) acc[i][j] = 0.f;

    for (int k0 = 0; k0 < K; k0 += BK) {
#pragma unroll
        for (int i = 0; i < 8; i++) {
            int gr = bm + lr, gk = k0 + lc + i;
            As[lc + i][lr] = (gr < M && gk < K) ? A[(size_t)gr * K + gk] : 0.f;
        }
#pragma unroll
        for (int i = 0; i < 8; i++) {
            int gr = bn + lr, gk = k0 + lc + i;
            Ws[lc + i][lr] = (gr < N && gk < K) ? W[(size_t)gr * K + gk] : 0.f;
        }
        __syncthreads();
#pragma unroll
        for (int kk = 0; kk < BK; kk++) {
            float a[8], bv[8];
#pragma unroll
            for (int i = 0; i < 8; i++) a[i] = As[kk][ty * 8 + i];
#pragma unroll
            for (int j = 0; j < 8; j++) bv[j] = Ws[kk][tx * 8 + j];
#pragma unroll
            for (int i = 0; i < 8; i++)
#pragma unroll
                for (int j = 0; j < 8; j++)
                    acc[i][j] = fmaf(a[i], bv[j], acc[i][j]);
        }
        __syncthreads();
    }

#pragma unroll
    for (int i = 0; i < 8; i++) {
        int gm = bm + ty * 8 + i;
        if (gm >= M) continue;
#pragma unroll
        for (int j = 0; j < 8; j++) {
            int gn = bn + tx * 8 + j;
            if (gn >= N) continue;
            float v = acc[i][j];
            if (bias) v += bias[gn];
            if (accum) v += C[(size_t)gm * N + gn];
            C[(size_t)gm * N + gn] = v;
        }
    }
}

// ---------------------------------------------------------------------------
__global__ __launch_bounds__(256) void cast_pad_kernel(
    const float* __restrict__ src, short* __restrict__ dst,
    int R, int K, int Kp)
{
    int idx = blockIdx.x * 256 + threadIdx.x;
    if (idx >= R * Kp) return;
    int r = idx / Kp, k = idx - r * Kp;
    dst[idx] = (k < K) ? f2bf(src[(size_t)r * K + k]) : (short)0;
}

// ---------------------------------------------------------------------------
__global__ __launch_bounds__(256) void time_conv_kernel(
    const float* __restrict__ x, const float* __restrict__ pw,
    float* __restrict__ traw)
{
    int br = blockIdx.x;
    __shared__ float xr[200];
    if (threadIdx.x < 200) xr[threadIdx.x] = x[(size_t)br * 200 + threadIdx.x];
    __syncthreads();
    if (threadIdx.x < 200) {
        int oc = threadIdx.x >> 3, j = threadIdx.x & 7;
        int start = j * 25 - 24;
        float acc = 0.f;
#pragma unroll
        for (int k = 0; k < 49; k++) {
            int d = start + k;
            if (d >= 0 && d < 200) acc = fmaf(xr[d], pw[oc * 49 + k], acc);
        }
        int b = br / SEQ, row = br % SEQ;
        traw[(((size_t)b * 25 + oc) * SEQ + row) * 8 + j] = acc;
    }
}

__global__ __launch_bounds__(256) void gn_stats_kernel(
    const float* __restrict__ traw, float* __restrict__ stats)
{
    int bg = blockIdx.x;
    int b = bg / 5, g = bg % 5;
    const float* base = traw + ((size_t)b * 25 + g * 5) * SEQ * 8;
    float s = 0.f, q = 0.f;
    for (int i = threadIdx.x; i < 5 * SEQ * 8; i += 256) {
        float v = base[i];
        s += v; q = fmaf(v, v, q);
    }
    __shared__ float rs[4], rq[4];
    int lane = threadIdx.x & 63, w = threadIdx.x >> 6;
#pragma unroll
    for (int o = 32; o; o >>= 1) { s += __shfl_xor(s, o, 64); q += __shfl_xor(q, o, 64); }
    if (lane == 0) { rs[w] = s; rq[w] = q; }
    __syncthreads();
    if (threadIdx.x == 0) {
        float S = rs[0] + rs[1] + rs[2] + rs[3];
        float Q = rq[0] + rq[1] + rq[2] + rq[3];
        float inv = 1.f / (5.f * SEQ * 8.f);
        float mean = S * inv;
        float var = Q * inv - mean * mean;
        stats[bg * 2] = mean;
        stats[bg * 2 + 1] = rsqrtf(var + EPS);
    }
}

__global__ __launch_bounds__(256) void gn_gelu_kernel(
    const float* __restrict__ traw, const float* __restrict__ stats,
    const float* __restrict__ gn_g, const float* __restrict__ gn_b,
    float* __restrict__ patch)
{
    int idx = blockIdx.x * 256 + threadIdx.x;
    if (idx >= NTOK * 200) return;
    int d = idx % 200;
    int row = (idx / 200) % SEQ;
    int b = idx / (200 * SEQ);
    int oc = d >> 3, j = d & 7;
    float v = traw[(((size_t)b * 25 + oc) * SEQ + row) * 8 + j];
    int g = oc / 5;
    float mean = stats[(b * 5 + g) * 2];
    float rstd = stats[(b * 5 + g) * 2 + 1];
    v = (v - mean) * rstd * gn_g[oc] + gn_b[oc];
    float ge = 0.5f * v * (1.f + erff(v * 0.70710678118654752f));
    patch[idx] = ge;
}

__global__ __launch_bounds__(256) void dft_init_kernel(float* __restrict__ CS)
{
    int idx = blockIdx.x * 256 + threadIdx.x;
    if (idx >= 202 * 200) return;
    int f = idx / 200, d = idx % 200;
    int fr = (f < NFREQ) ? f : (f - NFREQ);
    int m = (fr * d) % 200;
    float ang = -6.283185307179586f * (float)m * (1.f / 200.f);
    CS[idx] = (f < NFREQ) ? cosf(ang) : sinf(ang);
}

__global__ __launch_bounds__(256) void dft_init_bf_kernel(short* __restrict__ CS)
{
    int idx = blockIdx.x * 256 + threadIdx.x;
    if (idx >= 202 * 224) return;
    int f = idx / 224, d = idx - f * 224;
    short out = 0;
    if (d < 200) {
        int fr = (f < NFREQ) ? f : (f - NFREQ);
        int m = (fr * d) % 200;
        float ang = -6.283185307179586f * (float)m * (1.f / 200.f);
        out = f2bf((f < NFREQ) ? cosf(ang) : sinf(ang));
    }
    CS[idx] = out;
}

__global__ __launch_bounds__(256) void mag_kernel(
    const float* __restrict__ cs_out, float* __restrict__ magv)
{
    int idx = blockIdx.x * 256 + threadIdx.x;
    if (idx >= NTOK * NFREQ) return;
    int m = idx / NFREQ, f = idx % NFREQ;
    float re = cs_out[(size_t)m * 202 + f];
    float im = cs_out[(size_t)m * 202 + NFREQ + f];
    magv[idx] = sqrtf(re * re + im * im) * 0.005f;
}

__global__ __launch_bounds__(256) void mag_bf_kernel(
    const float* __restrict__ cs_out, short* __restrict__ magv)
{
    int idx = blockIdx.x * 256 + threadIdx.x;
    if (idx >= NTOK * 128) return;
    int m = idx >> 7, f = idx & 127;
    short out = 0;
    if (f < NFREQ) {
        float re = cs_out[(size_t)m * 202 + f];
        float im = cs_out[(size_t)m * 202 + NFREQ + f];
        out = f2bf(sqrtf(re * re + im * im) * 0.005f);
    }
    magv[idx] = out;
}

// ---------------------------------------------------------------------------
// depthwise 7x7 pos conv + residual. block = (b, 16-d slice, 4-c tile+halo)
__global__ __launch_bounds__(256) void pe_conv3_kernel(
    const float* __restrict__ patch, const float* __restrict__ pw,
    float* __restrict__ hidden)
{
    int b = blockIdx.x, dc = blockIdx.y, ct = blockIdx.z;
    int d0 = dc * 16, c0 = ct * 4;
    __shared__ float pl[10 * 30 * 16];
    __shared__ float wl[49 * 16];
    int tid = threadIdx.x;
    int dd = tid & 15;
    int d = d0 + dd;

    for (int i = tid; i < 10 * 30 * 16; i += 256) {
        int ddl = i & 15, r = i >> 4;
        int l = r % 30, cr = r / 30;
        int cc = c0 + cr - 3, dl = d0 + ddl;
        pl[i] = (cc >= 0 && cc < CH && dl < 200)
                    ? patch[((size_t)(b * CH + cc) * LLEN + l) * 200 + dl] : 0.f;
    }
    for (int i = tid; i < 49 * 16; i += 256) {
        int k = i >> 4, dl = d0 + (i & 15);
        wl[i] = (dl < 200) ? pw[(size_t)dl * 49 + k] : 0.f;
    }
    __syncthreads();

    float wreg[49];
#pragma unroll
    for (int k = 0; k < 49; k++) wreg[k] = wl[k * 16 + dd];

    for (int o = tid; o < 4 * 30 * 16; o += 256) {
        int r2 = o >> 4;               // o&15 == dd (stride 256 preserves low 4)
        int l = r2 % 30, ci = r2 / 30;
        int c = c0 + ci;
        if (c >= CH) continue;
        float acc = pl[((ci + 3) * 30 + l) * 16 + dd];
#pragma unroll
        for (int i = 0; i < 7; i++) {
#pragma unroll
            for (int j = 0; j < 7; j++) {
                int ll = l + j - 3;
                if (ll < 0 || ll >= LLEN) continue;
                acc = fmaf(pl[((ci + i) * 30 + ll) * 16 + dd], wreg[i * 7 + j], acc);
            }
        }
        if (d < 200) hidden[((size_t)(b * CH + c) * LLEN + l) * 200 + d] = acc;
    }
}

// ---------------------------------------------------------------------------
// residual += hidden; u = rmsnorm(residual)*wn; writes u fp32 + padded bf16
__global__ __launch_bounds__(64) void add_rmsnorm_kernel(
    const float* __restrict__ hidden, float* __restrict__ residual,
    const float* __restrict__ wn, float* __restrict__ u,
    short* __restrict__ ubf, int first)
{
    int m = blockIdx.x;
    int lane = threadIdx.x;
    const float* hr = hidden + (size_t)m * 200;
    float* rr = residual + (size_t)m * 200;
    float v[4];
    float ss = 0.f;
#pragma unroll
    for (int i = 0; i < 4; i++) {
        int k = lane + i * 64;
        float xv = 0.f;
        if (k < 200) {
            xv = hr[k] + (first ? 0.f : rr[k]);
            rr[k] = xv;
        }
        v[i] = xv;
        ss = fmaf(xv, xv, ss);
    }
#pragma unroll
    for (int o = 32; o; o >>= 1) ss += __shfl_xor(ss, o, 64);
    float rstd = rsqrtf(ss * (1.f / 200.f) + EPS);
#pragma unroll
    for (int i = 0; i < 4; i++) {
        int k = lane + i * 64;
        float val = v[i] * rstd * ((k < 200) ? wn[k] : 0.f);
        if (k < 200 && u) u[(size_t)m * 200 + k] = val;
        if (ubf) {
            if (k < 200) ubf[(size_t)m * 224 + k] = f2bf(val);
            else if (k < 224) ubf[(size_t)m * 224 + k] = 0;
        }
    }
}

// ---------------------------------------------------------------------------
// Fused: residual += hidden; u = rmsnorm*wn -> ubf (bf16 padded);
// dt[h] = softplus(u · Win[928+h] + dt_bias[h]) in fp32.
__global__ __launch_bounds__(256) void norm_dt_kernel(
    const float* __restrict__ hidden, float* __restrict__ residual,
    const float* __restrict__ wn, short* __restrict__ ubf,
    const float* __restrict__ Win, const float* __restrict__ dt_bias,
    float* __restrict__ dtb, int layer, int first)
{
    int m = blockIdx.x;
    int tid = threadIdx.x;
    __shared__ float su[200];
    __shared__ float rs[4];
    float xv = 0.f;
    if (tid < 200) {
        xv = hidden[(size_t)m * 200 + tid] + (first ? 0.f : residual[(size_t)m * 200 + tid]);
        residual[(size_t)m * 200 + tid] = xv;
    }
    float ss = xv * xv;
#pragma unroll
    for (int o = 32; o; o >>= 1) ss += __shfl_xor(ss, o, 64);
    int lane = tid & 63, w = tid >> 6;
    if (lane == 0) rs[w] = ss;
    __syncthreads();
    float rstd = rsqrtf((rs[0] + rs[1] + rs[2] + rs[3]) * (1.f / 200.f) + EPS);
    if (tid < 200) {
        float val = xv * rstd * wn[tid];
        su[tid] = val;
        ubf[(size_t)m * 224 + tid] = f2bf(val);
    } else if (tid < 224) {
        ubf[(size_t)m * 224 + tid] = 0;
    }
    __syncthreads();
    int h = tid >> 5, l = tid & 31;
    const float* wr = Win + (size_t)layer * D_IN_PROJ * 200 + (size_t)(928 + h) * 200;
    float s = 0.f;
    for (int k = l; k < 200; k += 32) s = fmaf(su[k], wr[k], s);
    s += __shfl_xor(s, 16, 32);
    s += __shfl_xor(s, 8, 32);
    s += __shfl_xor(s, 4, 32);
    s += __shfl_xor(s, 2, 32);
    s += __shfl_xor(s, 1, 32);
    if (l == 0) {
        float raw = s + dt_bias[layer * NHEADS + h];
        dtb[(size_t)m * NHEADS + h] = (raw > 20.f) ? raw : log1pf(expf(raw));
    }
}

// fp32 dt GEMV (fallback path)
__global__ __launch_bounds__(256) void dt_gemv_kernel(
    const float* __restrict__ u, const float* __restrict__ Win,
    const float* __restrict__ dt_bias, float* __restrict__ dtb, int layer)
{
    int tid = threadIdx.x;
    int tok = blockIdx.x * 4 + (tid >> 6);
    int head = (tid >> 3) & 7;
    int l8 = tid & 7;
    const float* ur = u + (size_t)tok * 200;
    const float* wr = Win + (size_t)layer * D_IN_PROJ * 200 + (size_t)(928 + head) * 200;
    float s = 0.f;
    for (int k = l8; k < 200; k += 8) s = fmaf(ur[k], wr[k], s);
    s += __shfl_xor(s, 1, 64);
    s += __shfl_xor(s, 2, 64);
    s += __shfl_xor(s, 4, 64);
    if (l8 == 0) {
        float raw = s + dt_bias[layer * NHEADS + head];
        dtb[(size_t)tok * NHEADS + head] = (raw > 20.f) ? raw : log1pf(expf(raw));
    }
}

// ---------------------------------------------------------------------------
// xBC = silu(causal depthwise conv4), t-tiled: block = (b, 8-t tile + 3 halo)
__global__ __launch_bounds__(256) void dtconv2_kernel(
    const float* __restrict__ zxbcdt, const float* __restrict__ cw,
    const float* __restrict__ cb, float* __restrict__ xBC, int layer)
{
    int b = blockIdx.x, tt = blockIdx.y;
    int t0 = tt * 8;
    __shared__ float zs[11][528];
    const float* cwl = cw + (size_t)layer * CONV_DIM * 4;
    const float* cbl = cb + (size_t)layer * CONV_DIM;
    for (int i = threadIdx.x; i < 11 * 528; i += 256) {
        int r = i / 528, ch = i - r * 528;
        int t = t0 - 3 + r;
        zs[r][ch] = (t >= 0 && t < SEQ)
                        ? zxbcdt[(size_t)(b * SEQ + t) * D_IN_PROJ + D_INNER + ch] : 0.f;
    }
    __syncthreads();
    for (int o = threadIdx.x; o < 8 * 528; o += 256) {
        int tr = o / 528, ch = o - tr * 528;
        int t = t0 + tr;
        if (t >= SEQ) continue;
        float acc = cbl[ch];
#pragma unroll
        for (int k = 0; k < 4; k++)
            acc = fmaf(zs[tr + k][ch], cwl[ch * 4 + k], acc);
        xBC[(size_t)(b * SEQ + t) * CONV_DIM + ch] = acc / (1.f + expf(-acc));
    }
}

// ---------------------------------------------------------------------------
// Chunked SSD scan (LDS-staged, 8 heads per 512-thr block)
__global__ __launch_bounds__(512) void ssd_state_kernel(
    const float* __restrict__ xBC, const float* __restrict__ dtb,
    const float* __restrict__ A_log, float* __restrict__ Sbuf,
    float* __restrict__ Pd, int layer, int lchunk, int nchunk)
{
    int b = blockIdx.x, c = blockIdx.y;
    int tid = threadIdx.x;
    int h = tid >> 6, p = tid & 63;
    float A = -expf(A_log[layer * NHEADS + h]);

    __shared__ float sh[2][544];
    int t0 = c * lchunk, tend = t0 + lchunk;

    {
        const float* base = xBC + (size_t)(b * SEQ + t0) * CONV_DIM;
        sh[0][tid] = base[tid];
        if (tid < 24) {
            int e2 = 512 + tid;
            sh[0][e2] = (e2 < 528) ? base[e2]
                                   : dtb[(size_t)(b * SEQ + t0) * NHEADS + (e2 - 528)];
        }
    }
    __syncthreads();

    float s[64];
#pragma unroll
    for (int n = 0; n < 64; n++) s[n] = 0.f;
    float pacc = 1.f;

    for (int t = t0; t < tend; t++) {
        int cur = (t - t0) & 1, nxt = cur ^ 1;
        float pf0 = 0.f, pf1 = 0.f;
        if (t + 1 < tend) {
            const float* base = xBC + (size_t)(b * SEQ + t + 1) * CONV_DIM;
            pf0 = base[tid];
            if (tid < 24) {
                int e2 = 512 + tid;
                pf1 = (e2 < 528) ? base[e2]
                                 : dtb[(size_t)(b * SEQ + t + 1) * NHEADS + (e2 - 528)];
            }
        }
        float dtv = sh[cur][528 + h];
        float xp  = (p < HEADDIM) ? sh[cur][h * HEADDIM + p] : 0.f;
        float dA = __expf(dtv * A);
        float u  = dtv * xp;
        pacc *= dA;
        const float4* B4 = (const float4*)&sh[cur][D_INNER];
#pragma unroll
        for (int n4 = 0; n4 < 16; n4++) {
            float4 bq = B4[n4];
            s[4 * n4 + 0] = fmaf(s[4 * n4 + 0], dA, u * bq.x);
            s[4 * n4 + 1] = fmaf(s[4 * n4 + 1], dA, u * bq.y);
            s[4 * n4 + 2] = fmaf(s[4 * n4 + 2], dA, u * bq.z);
            s[4 * n4 + 3] = fmaf(s[4 * n4 + 3], dA, u * bq.w);
        }
        if (t + 1 < tend) {
            sh[nxt][tid] = pf0;
            if (tid < 24) sh[nxt][512 + tid] = pf1;
        }
        __syncthreads();
    }

    if (p < HEADDIM) {
        float* Sb = Sbuf + ((size_t)((b * NHEADS + h) * nchunk + c)) * (HEADDIM * 64)
                    + p * 64;
#pragma unroll
        for (int n4 = 0; n4 < 16; n4++)
            ((float4*)Sb)[n4] = make_float4(s[4 * n4], s[4 * n4 + 1],
                                            s[4 * n4 + 2], s[4 * n4 + 3]);
    }
    if (p == 0) Pd[(b * NHEADS + h) * nchunk + c] = pacc;
}

__global__ __launch_bounds__(256) void ssd_scan2_kernel(
    float* __restrict__ Sbuf, const float* __restrict__ Pd, int nchunk)
{
    int bh = blockIdx.x;
    float* base = Sbuf + (size_t)bh * nchunk * (HEADDIM * 64);
    const float* pd = Pd + bh * nchunk;
    for (int e = threadIdx.x; e < HEADDIM * 64; e += 256) {
        float cur = 0.f;
        for (int c = 0; c < nchunk; c++) {
            float l = base[(size_t)c * (HEADDIM * 64) + e];
            base[(size_t)c * (HEADDIM * 64) + e] = cur;
            cur = fmaf(pd[c], cur, l);
        }
    }
}

// Pass 3 FUSED: recurrence + D-add + gate (silu(z)) + rmsnorm + bf16 pack.
// Writes ybf[tok][416] directly (cols 400..415 zeroed).
__global__ __launch_bounds__(512) void ssd_out_fused_kernel(
    const float* __restrict__ xBC, const float* __restrict__ dtb,
    const float* __restrict__ zxbcdt, const float* __restrict__ A_log,
    const float* __restrict__ Dv, const float* __restrict__ Sbuf,
    const float* __restrict__ gw, short* __restrict__ ybf,
    int layer, int lchunk, int nchunk)
{
    int b = blockIdx.x, c = blockIdx.y;
    int tid = threadIdx.x;
    int h = tid >> 6, p = tid & 63;
    float A = -expf(A_log[layer * NHEADS + h]);
    float Dh = Dv[layer * NHEADS + h];
    float gval = (p < HEADDIM) ? gw[(size_t)layer * D_INNER + h * HEADDIM + p] : 0.f;

    __shared__ float sh[2][544];
    __shared__ float shz[2][400];
    __shared__ float red[8];
    int t0 = c * lchunk, tend = t0 + lchunk;

    {
        const float* base = xBC + (size_t)(b * SEQ + t0) * CONV_DIM;
        sh[0][tid] = base[tid];
        if (tid < 24) {
            int e2 = 512 + tid;
            sh[0][e2] = (e2 < 528) ? base[e2]
                                   : dtb[(size_t)(b * SEQ + t0) * NHEADS + (e2 - 528)];
        }
        if (tid < 400) shz[0][tid] = zxbcdt[(size_t)(b * SEQ + t0) * D_IN_PROJ + tid];
    }

    float s[64];
    if (p < HEADDIM) {
        const float* Sb = Sbuf + ((size_t)((b * NHEADS + h) * nchunk + c)) * (HEADDIM * 64)
                          + p * 64;
#pragma unroll
        for (int n4 = 0; n4 < 16; n4++) {
            float4 v = ((const float4*)Sb)[n4];
            s[4 * n4] = v.x; s[4 * n4 + 1] = v.y; s[4 * n4 + 2] = v.z; s[4 * n4 + 3] = v.w;
        }
    } else {
#pragma unroll
        for (int n = 0; n < 64; n++) s[n] = 0.f;
    }
    __syncthreads();

    for (int t = t0; t < tend; t++) {
        int cur = (t - t0) & 1, nxt = cur ^ 1;
        float pf0 = 0.f, pf1 = 0.f, pfz = 0.f;
        if (t + 1 < tend) {
            const float* base = xBC + (size_t)(b * SEQ + t + 1) * CONV_DIM;
            pf0 = base[tid];
            if (tid < 24) {
                int e2 = 512 + tid;
                pf1 = (e2 < 528) ? base[e2]
                                 : dtb[(size_t)(b * SEQ + t + 1) * NHEADS + (e2 - 528)];
            }
            if (tid < 400) pfz = zxbcdt[(size_t)(b * SEQ + t + 1) * D_IN_PROJ + tid];
        }
        float dtv = sh[cur][528 + h];
        float xp  = (p < HEADDIM) ? sh[cur][h * HEADDIM + p] : 0.f;
        float dA = __expf(dtv * A);
        float u  = dtv * xp;
        const float4* B4 = (const float4*)&sh[cur][D_INNER];
        const float4* C4 = (const float4*)&sh[cur][D_INNER + D_STATE];
        float y0 = 0.f, y1 = 0.f, y2 = 0.f, y3 = 0.f;
#pragma unroll
        for (int n4 = 0; n4 < 16; n4++) {
            float4 bq = B4[n4];
            float4 cq = C4[n4];
            float t0v = fmaf(s[4 * n4 + 0], dA, u * bq.x);
            float t1v = fmaf(s[4 * n4 + 1], dA, u * bq.y);
            float t2v = fmaf(s[4 * n4 + 2], dA, u * bq.z);
            float t3v = fmaf(s[4 * n4 + 3], dA, u * bq.w);
            s[4 * n4 + 0] = t0v; s[4 * n4 + 1] = t1v;
            s[4 * n4 + 2] = t2v; s[4 * n4 + 3] = t3v;
            y0 = fmaf(t0v, cq.x, y0);
            y1 = fmaf(t1v, cq.y, y1);
            y2 = fmaf(t2v, cq.z, y2);
            y3 = fmaf(t3v, cq.w, y3);
        }
        float g = 0.f;
        if (p < HEADDIM) {
            float yv = (y0 + y1) + (y2 + y3);
            yv = fmaf(xp, Dh, yv);
            float zv = shz[cur][h * HEADDIM + p];
            g = yv * (zv / (1.f + expf(-zv)));
        }
        float gs = g * g;
#pragma unroll
        for (int o = 32; o; o >>= 1) gs += __shfl_xor(gs, o, 64);
        if (p == 0) red[h] = gs;
        __syncthreads();
        float tot = (red[0] + red[1]) + (red[2] + red[3]) +
                    (red[4] + red[5]) + (red[6] + red[7]);
        float rstd = rsqrtf(tot * (1.f / D_INNER) + EPS);
        size_t row = (size_t)(b * SEQ + t) * 416;
        if (p < HEADDIM) {
            ybf[row + h * HEADDIM + p] = f2bf(g * rstd * gval);
        } else {
            int widx = h * 14 + (p - HEADDIM);
            if (widx < 16) ybf[row + 400 + widx] = 0;
        }
        if (t + 1 < tend) {
            sh[nxt][tid] = pf0;
            if (tid < 24) sh[nxt][512 + tid] = pf1;
            if (tid < 400) shz[nxt][tid] = pfz;
        }
        __syncthreads();
    }
}

// Pass 3 (fallback, fp32 y out)
__global__ __launch_bounds__(512) void ssd_out_kernel(
    const float* __restrict__ xBC, const float* __restrict__ dtb,
    const float* __restrict__ A_log, const float* __restrict__ Dv,
    const float* __restrict__ Sbuf, float* __restrict__ y,
    int layer, int lchunk, int nchunk)
{
    int b = blockIdx.x, c = blockIdx.y;
    int tid = threadIdx.x;
    int h = tid >> 6, p = tid & 63;
    float A = -expf(A_log[layer * NHEADS + h]);
    float Dh = Dv[layer * NHEADS + h];

    __shared__ float sh[2][544];
    int t0 = c * lchunk, tend = t0 + lchunk;

    {
        const float* base = xBC + (size_t)(b * SEQ + t0) * CONV_DIM;
        sh[0][tid] = base[tid];
        if (tid < 24) {
            int e2 = 512 + tid;
            sh[0][e2] = (e2 < 528) ? base[e2]
                                   : dtb[(size_t)(b * SEQ + t0) * NHEADS + (e2 - 528)];
        }
    }

    float s[64];
    if (p < HEADDIM) {
        const float* Sb = Sbuf + ((size_t)((b * NHEADS + h) * nchunk + c)) * (HEADDIM * 64)
                          + p * 64;
#pragma unroll
        for (int n4 = 0; n4 < 16; n4++) {
            float4 v = ((const float4*)Sb)[n4];
            s[4 * n4] = v.x; s[4 * n4 + 1] = v.y; s[4 * n4 + 2] = v.z; s[4 * n4 + 3] = v.w;
        }
    } else {
#pragma unroll
        for (int n = 0; n < 64; n++) s[n] = 0.f;
    }
    __syncthreads();

    for (int t = t0; t < tend; t++) {
        int cur = (t - t0) & 1, nxt = cur ^ 1;
        float pf0 = 0.f, pf1 = 0.f;
        if (t + 1 < tend) {
            const float* base = xBC + (size_t)(b * SEQ + t + 1) * CONV_DIM;
            pf0 = base[tid];
            if (tid < 24) {
                int e2 = 512 + tid;
                pf1 = (e2 < 528) ? base[e2]
                                 : dtb[(size_t)(b * SEQ + t + 1) * NHEADS + (e2 - 528)];
            }
        }
        float dtv = sh[cur][528 + h];
        float xp  = (p < HEADDIM) ? sh[cur][h * HEADDIM + p] : 0.f;
        float dA = __expf(dtv * A);
        float u  = dtv * xp;
        const float4* B4 = (const float4*)&sh[cur][D_INNER];
        const float4* C4 = (const float4*)&sh[cur][D_INNER + D_STATE];
        float y0 = 0.f, y1 = 0.f, y2 = 0.f, y3 = 0.f;
#pragma unroll
        for (int n4 = 0; n4 < 16; n4++) {
            float4 bq = B4[n4];
            float4 cq = C4[n4];
            float t0v = fmaf(s[4 * n4 + 0], dA, u * bq.x);
            float t1v = fmaf(s[4 * n4 + 1], dA, u * bq.y);
            float t2v = fmaf(s[4 * n4 + 2], dA, u * bq.z);
            float t3v = fmaf(s[4 * n4 + 3], dA, u * bq.w);
            s[4 * n4 + 0] = t0v; s[4 * n4 + 1] = t1v;
            s[4 * n4 + 2] = t2v; s[4 * n4 + 3] = t3v;
            y0 = fmaf(t0v, cq.x, y0);
            y1 = fmaf(t1v, cq.y, y1);
            y2 = fmaf(t2v, cq.z, y2);
            y3 = fmaf(t3v, cq.w, y3);
        }
        if (p < HEADDIM) {
            float yv = (y0 + y1) + (y2 + y3);
            y[(size_t)(b * SEQ + t) * D_INNER + h * HEADDIM + p] = fmaf(xp, Dh, yv);
        }
        if (t + 1 < tend) {
            sh[nxt][tid] = pf0;
            if (tid < 24) sh[nxt][512 + tid] = pf1;
        }
        __syncthreads();
    }
}

// ---------------------------------------------------------------------------
// fallback gate+norm
__global__ __launch_bounds__(256) void gate_norm_kernel(
    float* __restrict__ y, const float* __restrict__ zxbcdt,
    const float* __restrict__ gw, short* __restrict__ ybf, int layer)
{
    int m = blockIdx.x;
    __shared__ float buf[D_INNER];
    __shared__ float red[4];
    const float* z = zxbcdt + (size_t)m * D_IN_PROJ;
    float* yr = y + (size_t)m * D_INNER;
    const float* gwl = gw + (size_t)layer * D_INNER;
    float ss = 0.f;
    for (int k = threadIdx.x; k < D_INNER; k += 256) {
        float zv = z[k];
        float sz = zv / (1.f + expf(-zv));
        float g = yr[k] * sz;
        buf[k] = g;
        ss = fmaf(g, g, ss);
    }
    int lane = threadIdx.x & 63, w = threadIdx.x >> 6;
#pragma unroll
    for (int o = 32; o; o >>= 1) ss += __shfl_xor(ss, o, 64);
    if (lane == 0) red[w] = ss;
    __syncthreads();
    float tot = red[0] + red[1] + red[2] + red[3];
    float rstd = rsqrtf(tot * (1.f / D_INNER) + EPS);
    for (int k = threadIdx.x; k < 416; k += 256) {
        if (k < D_INNER) {
            float v = buf[k] * rstd * gwl[k];
            yr[k] = v;
            if (ybf) ybf[(size_t)m * 416 + k] = f2bf(v);
        } else if (ybf) {
            ybf[(size_t)m * 416 + k] = 0;
        }
    }
}

// ---------------------------------------------------------------------------
extern "C" void kernel_launch(void* const* d_in, const int* in_sizes, int n_in,
                              void* d_out, int out_size, void* d_ws, size_t ws_size,
                              hipStream_t stream)
{
    const float* x         = (const float*)d_in[0];
    const float* pe_conv_w = (const float*)d_in[1];
    const float* proj_in_w = (const float*)d_in[2];
    const float* gn_g      = (const float*)d_in[3];
    const float* gn_b      = (const float*)d_in[4];
    const float* spec_w    = (const float*)d_in[5];
    const float* norm_w    = (const float*)d_in[6];
    const float* in_proj_w = (const float*)d_in[7];
    const float* conv_w    = (const float*)d_in[8];
    const float* conv_b    = (const float*)d_in[9];
    const float* dt_bias   = (const float*)d_in[10];
    const float* A_log     = (const float*)d_in[11];
    const float* Dv        = (const float*)d_in[12];
    const float* gnorm_w   = (const float*)d_in[13];
    const float* out_proj_w= (const float*)d_in[14];
    const float* norm_f_w  = (const float*)d_in[15];
    const float* head_w    = (const float*)d_in[16];
    const float* head_b    = (const float*)d_in[17];
    float* out = (float*)d_out;
    float* ws  = (float*)d_ws;

    // fp32 region (both paths)
    float* residual = ws;                       // 1,824,000
    float* hidden   = ws + 1824000;             // 1,824,000
    float* ubuf     = ws + 3648000;             // 1,824,000
    float* zxbcdt   = ws + 5472000;             // 8,536,320
    float* xBC      = ws + 14008320;            // 4,815,360
    float* dtb      = ws + 18823680;            // 72,960
    float* ybuf     = ws + 18896640;            // 3,648,000 -> ends 22,544,640

    const size_t needA = 35029088ull * sizeof(float);   // ~140.1 MB
    int fast = (ws_size >= needA) ? 1 : 0;

    int nchunk, lchunk;
    float *Sbuf, *Pd;
    short *w_in_bf = nullptr, *w_out_bf = nullptr, *w_head_bf = nullptr,
          *w_spec_bf = nullptr, *csmat_bf = nullptr, *x_bf = nullptr,
          *ubuf_bf = nullptr, *ybuf_bf = nullptr, *magb_bf = nullptr;
    if (fast) {
        nchunk = 15; lchunk = 38;
        Sbuf = ws + 22544640;                   // 6,144,000
        Pd   = ws + 28688640;                   // 1,920
        short* pool = (short*)(ws + 28690560);
        w_in_bf   = pool;                       // 2,515,968
        w_out_bf  = pool + 2515968;             //   998,400
        w_head_bf = pool + 3514368;             //    44,800
        w_spec_bf = pool + 3559168;             //    25,600
        csmat_bf  = pool + 3584768;             //    45,248
        x_bf      = pool + 3630016;             // 2,042,880
        ubuf_bf   = pool + 5672896;             // 2,042,880
        ybuf_bf   = pool + 7715776;             // 3,793,920
        magb_bf   = pool + 11509696;            // 1,167,360
    } else {
        nchunk = 6; lchunk = 95;
        Sbuf = ws + 1824000;
        Pd   = ws + 5470000;
    }

    // pre-layer aliases (dead layer buffers)
    float* traw  = ybuf;
    float* patch = zxbcdt;
    float* csmat = xBC;
    float* csout = xBC + 50000;
    float* magb  = xBC + 2000000;
    float* stats = dtb;

    // ---- weight / input casts (fast) ----
    if (fast) {
        cast_pad_kernel<<<(12 * 936 * 224 + 255) / 256, 256, 0, stream>>>(
            in_proj_w, w_in_bf, 12 * 936, 200, 224);
        cast_pad_kernel<<<(12 * 200 * 416 + 255) / 256, 256, 0, stream>>>(
            out_proj_w, w_out_bf, 12 * 200, 400, 416);
        cast_pad_kernel<<<(200 * 224 + 255) / 256, 256, 0, stream>>>(
            head_w, w_head_bf, 200, 200, 224);
        cast_pad_kernel<<<(200 * 128 + 255) / 256, 256, 0, stream>>>(
            spec_w, w_spec_bf, 200, 101, 128);
        cast_pad_kernel<<<(9120 * 224 + 255) / 256, 256, 0, stream>>>(
            x, x_bf, 9120, 200, 224);
        dft_init_bf_kernel<<<(202 * 224 + 255) / 256, 256, 0, stream>>>(csmat_bf);
    } else {
        dft_init_kernel<<<(202 * 200 + 255) / 256, 256, 0, stream>>>(csmat);
    }

    // ---- patch embed ----
    time_conv_kernel<<<NTOK, 256, 0, stream>>>(x, proj_in_w, traw);
    gn_stats_kernel<<<80, 256, 0, stream>>>(traw, stats);
    gn_gelu_kernel<<<(NTOK * 200 + 255) / 256, 256, 0, stream>>>(traw, stats, gn_g, gn_b, patch);
    if (fast) {
        gemm_bf16<<<dim3(2, 72), 256, 0, stream>>>(x_bf, csmat_bf, nullptr, csout,
                                                   NTOK, 202, 224, 0);
        mag_bf_kernel<<<(NTOK * 128 + 255) / 256, 256, 0, stream>>>(csout, magb_bf);
        gemm_bf16<<<dim3(2, 72), 256, 0, stream>>>(magb_bf, w_spec_bf, nullptr, patch,
                                                   NTOK, 200, 128, 1);
    } else {
        gemm_nt<<<dim3(2, 72), 256, 0, stream>>>(x, csmat, nullptr, csout, NTOK, 202, 200, 0);
        mag_kernel<<<(NTOK * NFREQ + 255) / 256, 256, 0, stream>>>(csout, magb);
        gemm_nt<<<dim3(2, 72), 256, 0, stream>>>(magb, spec_w, nullptr, patch,
                                                 NTOK, 200, NFREQ, 1);
    }
    pe_conv3_kernel<<<dim3(16, 13, 5), 256, 0, stream>>>(patch, pe_conv_w, hidden);

    // ---- layers ----
    for (int i = 0; i < N_LAYER; i++) {
        if (fast) {
            norm_dt_kernel<<<NTOK, 256, 0, stream>>>(hidden, residual, norm_w + i * 200,
                                                     ubuf_bf, in_proj_w, dt_bias, dtb,
                                                     i, (i == 0) ? 1 : 0);
            gemm_bf16<<<dim3(8, 72), 256, 0, stream>>>(
                ubuf_bf, w_in_bf + (size_t)i * 936 * 224, nullptr, zxbcdt,
                NTOK, D_IN_PROJ, 224, 0);
        } else {
            add_rmsnorm_kernel<<<NTOK, 64, 0, stream>>>(hidden, residual, norm_w + i * 200,
                                                        ubuf, nullptr, (i == 0) ? 1 : 0);
            dt_gemv_kernel<<<NTOK / 4, 256, 0, stream>>>(ubuf, in_proj_w, dt_bias, dtb, i);
            gemm_nt<<<dim3(8, 72), 256, 0, stream>>>(
                ubuf, in_proj_w + (size_t)i * D_IN_PROJ * 200, nullptr, zxbcdt,
                NTOK, D_IN_PROJ, 200, 0);
        }
        dtconv2_kernel<<<dim3(16, 72), 256, 0, stream>>>(zxbcdt, conv_w, conv_b, xBC, i);
        {
            dim3 g(BATCH, nchunk);
            ssd_state_kernel<<<g, 512, 0, stream>>>(xBC, dtb, A_log, Sbuf, Pd, i, lchunk, nchunk);
            ssd_scan2_kernel<<<BATCH * NHEADS, 256, 0, stream>>>(Sbuf, Pd, nchunk);
            if (fast) {
                ssd_out_fused_kernel<<<g, 512, 0, stream>>>(
                    xBC, dtb, zxbcdt, A_log, Dv, Sbuf, gnorm_w, ybuf_bf, i, lchunk, nchunk);
                gemm_bf16<<<dim3(2, 72), 256, 0, stream>>>(
                    ybuf_bf, w_out_bf + (size_t)i * 200 * 416, nullptr, hidden,
                    NTOK, 200, 416, 0);
            } else {
                ssd_out_kernel<<<g, 512, 0, stream>>>(xBC, dtb, A_log, Dv, Sbuf, ybuf,
                                                      i, lchunk, nchunk);
                gate_norm_kernel<<<NTOK, 256, 0, stream>>>(ybuf, zxbcdt, gnorm_w, nullptr, i);
                gemm_nt<<<dim3(2, 72), 256, 0, stream>>>(
                    ybuf, out_proj_w + (size_t)i * 200 * D_INNER, nullptr, hidden,
                    NTOK, 200, D_INNER, 0);
            }
        }
    }

    // ---- final norm + head ----
    add_rmsnorm_kernel<<<NTOK, 64, 0, stream>>>(hidden, residual, norm_f_w, ubuf,
                                                fast ? ubuf_bf : nullptr, 0);
    if (fast) {
        gemm_bf16<<<dim3(2, 72), 256, 0, stream>>>(ubuf_bf, w_head_bf, head_b, out,
                                                   NTOK, 200, 224, 0);
    } else {
        gemm_nt<<<dim3(2, 72), 256, 0, stream>>>(ubuf, head_w, head_b, out,
                                                 NTOK, 200, 200, 0);
    }
}

// Round 6
// 3154.253 us; speedup vs baseline: 8.1040x; 1.0011x over previous
//
#include <hip/hip_runtime.h>
#include <hip/hip_bf16.h>
#include <math.h>

// ---------------------------------------------------------------------------
// EEGMamba forward. Round 6: pair-unrolled SSD scan (2 timesteps / barrier),
// parity-banked reduction pipeline. Rest as Round 5.
#define D_MODEL   200
#define N_LAYER   12
#define NHEADS    8
#define HEADDIM   50
#define D_STATE   64
#define D_INNER   400
#define CONV_DIM  528
#define D_IN_PROJ 936
#define D_CONV    4
#define EPS       1e-5f

#define BATCH 16
#define CH    19
#define LLEN  30
#define SEQ   570
#define NTOK  9120
#define NFREQ 101

typedef __attribute__((ext_vector_type(8))) short s8v;
typedef __attribute__((ext_vector_type(4))) float f32x4;

__device__ __forceinline__ short f2bf(float f) {
    unsigned u = __float_as_uint(f);
    u += 0x7FFFu + ((u >> 16) & 1u);      // RNE
    return (short)(u >> 16);
}

// ---------------------------------------------------------------------------
// bf16 MFMA GEMM: C[M,N] = A[M,Kp] @ W[N,Kp]^T (+bias) (+C if accum)
__global__ __launch_bounds__(256) void gemm_bf16(
    const short* __restrict__ A, const short* __restrict__ W,
    const float* __restrict__ bias, float* __restrict__ C,
    int M, int N, int Kp, int accum)
{
    __shared__ __align__(16) short As[128][40];
    __shared__ __align__(16) short Ws[128][40];

    int bm = blockIdx.y * 128;
    int bn = blockIdx.x * 128;
    int tid = threadIdx.x;
    int lane = tid & 63;
    int wv = tid >> 6;
    int wm = wv & 1, wn = wv >> 1;
    int lm = lane & 15, lg = lane >> 4;

    int sr = tid >> 1;
    int sh_ = (tid & 1) * 16;

    f32x4 acc[4][4];
#pragma unroll
    for (int i = 0; i < 4; i++)
#pragma unroll
        for (int j = 0; j < 4; j++) acc[i][j] = (f32x4)0.f;

    for (int k0 = 0; k0 < Kp; k0 += 32) {
        {
            s8v v0 = (s8v)0, v1 = (s8v)0;
            if (bm + sr < M) {
                const short* ga = A + (size_t)(bm + sr) * Kp + k0 + sh_;
                v0 = *(const s8v*)ga;
                v1 = *(const s8v*)(ga + 8);
            }
            *(s8v*)&As[sr][sh_] = v0;
            *(s8v*)&As[sr][sh_ + 8] = v1;
        }
        {
            s8v v0 = (s8v)0, v1 = (s8v)0;
            if (bn + sr < N) {
                const short* gw = W + (size_t)(bn + sr) * Kp + k0 + sh_;
                v0 = *(const s8v*)gw;
                v1 = *(const s8v*)(gw + 8);
            }
            *(s8v*)&Ws[sr][sh_] = v0;
            *(s8v*)&Ws[sr][sh_ + 8] = v1;
        }
        __syncthreads();

        s8v af[4], bf[4];
#pragma unroll
        for (int i = 0; i < 4; i++)
            af[i] = *(const s8v*)&As[wm * 64 + i * 16 + lm][lg * 8];
#pragma unroll
        for (int j = 0; j < 4; j++)
            bf[j] = *(const s8v*)&Ws[wn * 64 + j * 16 + lm][lg * 8];
#pragma unroll
        for (int i = 0; i < 4; i++)
#pragma unroll
            for (int j = 0; j < 4; j++)
                acc[i][j] = __builtin_amdgcn_mfma_f32_16x16x32_bf16(
                    af[i], bf[j], acc[i][j], 0, 0, 0);
        __syncthreads();
    }

#pragma unroll
    for (int j = 0; j < 4; j++) {
        int n = bn + wn * 64 + j * 16 + lm;
        if (n >= N) continue;
        float bv = bias ? bias[n] : 0.f;
#pragma unroll
        for (int i = 0; i < 4; i++) {
            int mbase = bm + wm * 64 + i * 16 + lg * 4;
#pragma unroll
            for (int r = 0; r < 4; r++) {
                int m = mbase + r;
                if (m >= M) continue;
                size_t idx = (size_t)m * N + n;
                float v = acc[i][j][r] + bv;
                if (accum) v += C[idx];
                C[idx] = v;
            }
        }
    }
}

// ---------------------------------------------------------------------------
// fp32 GEMM (fallback path)
__global__ __launch_bounds__(256) void gemm_nt(
    const float* __restrict__ A, const float* __restrict__ W,
    const float* __restrict__ bias, float* __restrict__ C,
    int M, int N, int K, int accum)
{
    const int BM = 128, BK = 16;
    __shared__ float As[16][BM + 4];
    __shared__ float Ws[16][BM + 4];

    int bm = blockIdx.y * BM;
    int bn = blockIdx.x * BM;
    int tid = threadIdx.x;
    int lr = tid >> 1;
    int lc = (tid & 1) * 8;
    int tx = tid & 15;
    int ty = tid >> 4;

    float acc[8][8];
#pragma unroll
    for (int i = 0; i < 8; i++)
#pragma unroll
        for (int j = 0; j < 8; j++) acc[i][j] = 0.f;

    for (int k0 = 0; k0 < K; k0 += BK) {
#pragma unroll
        for (int i = 0; i < 8; i++) {
            int gr = bm + lr, gk = k0 + lc + i;
            As[lc + i][lr] = (gr < M && gk < K) ? A[(size_t)gr * K + gk] : 0.f;
        }
#pragma unroll
        for (int i = 0; i < 8; i++) {
            int gr = bn + lr, gk = k0 + lc + i;
            Ws[lc + i][lr] = (gr < N && gk < K) ? W[(size_t)gr * K + gk] : 0.f;
        }
        __syncthreads();
#pragma unroll
        for (int kk = 0; kk < BK; kk++) {
            float a[8], bv[8];
#pragma unroll
            for (int i = 0; i < 8; i++) a[i] = As[kk][ty * 8 + i];
#pragma unroll
            for (int j = 0; j < 8; j++) bv[j] = Ws[kk][tx * 8 + j];
#pragma unroll
            for (int i = 0; i < 8; i++)
#pragma unroll
                for (int j = 0; j < 8; j++)
                    acc[i][j] = fmaf(a[i], bv[j], acc[i][j]);
        }
        __syncthreads();
    }

#pragma unroll
    for (int i = 0; i < 8; i++) {
        int gm = bm + ty * 8 + i;
        if (gm >= M) continue;
#pragma unroll
        for (int j = 0; j < 8; j++) {
            int gn = bn + tx * 8 + j;
            if (gn >= N) continue;
            float v = acc[i][j];
            if (bias) v += bias[gn];
            if (accum) v += C[(size_t)gm * N + gn];
            C[(size_t)gm * N + gn] = v;
        }
    }
}

// ---------------------------------------------------------------------------
__global__ __launch_bounds__(256) void cast_pad_kernel(
    const float* __restrict__ src, short* __restrict__ dst,
    int R, int K, int Kp)
{
    int idx = blockIdx.x * 256 + threadIdx.x;
    if (idx >= R * Kp) return;
    int r = idx / Kp, k = idx - r * Kp;
    dst[idx] = (k < K) ? f2bf(src[(size_t)r * K + k]) : (short)0;
}

// ---------------------------------------------------------------------------
__global__ __launch_bounds__(256) void time_conv_kernel(
    const float* __restrict__ x, const float* __restrict__ pw,
    float* __restrict__ traw)
{
    int br = blockIdx.x;
    __shared__ float xr[200];
    if (threadIdx.x < 200) xr[threadIdx.x] = x[(size_t)br * 200 + threadIdx.x];
    __syncthreads();
    if (threadIdx.x < 200) {
        int oc = threadIdx.x >> 3, j = threadIdx.x & 7;
        int start = j * 25 - 24;
        float acc = 0.f;
#pragma unroll
        for (int k = 0; k < 49; k++) {
            int d = start + k;
            if (d >= 0 && d < 200) acc = fmaf(xr[d], pw[oc * 49 + k], acc);
        }
        int b = br / SEQ, row = br % SEQ;
        traw[(((size_t)b * 25 + oc) * SEQ + row) * 8 + j] = acc;
    }
}

__global__ __launch_bounds__(256) void gn_stats_kernel(
    const float* __restrict__ traw, float* __restrict__ stats)
{
    int bg = blockIdx.x;
    int b = bg / 5, g = bg % 5;
    const float* base = traw + ((size_t)b * 25 + g * 5) * SEQ * 8;
    float s = 0.f, q = 0.f;
    for (int i = threadIdx.x; i < 5 * SEQ * 8; i += 256) {
        float v = base[i];
        s += v; q = fmaf(v, v, q);
    }
    __shared__ float rs[4], rq[4];
    int lane = threadIdx.x & 63, w = threadIdx.x >> 6;
#pragma unroll
    for (int o = 32; o; o >>= 1) { s += __shfl_xor(s, o, 64); q += __shfl_xor(q, o, 64); }
    if (lane == 0) { rs[w] = s; rq[w] = q; }
    __syncthreads();
    if (threadIdx.x == 0) {
        float S = rs[0] + rs[1] + rs[2] + rs[3];
        float Q = rq[0] + rq[1] + rq[2] + rq[3];
        float inv = 1.f / (5.f * SEQ * 8.f);
        float mean = S * inv;
        float var = Q * inv - mean * mean;
        stats[bg * 2] = mean;
        stats[bg * 2 + 1] = rsqrtf(var + EPS);
    }
}

__global__ __launch_bounds__(256) void gn_gelu_kernel(
    const float* __restrict__ traw, const float* __restrict__ stats,
    const float* __restrict__ gn_g, const float* __restrict__ gn_b,
    float* __restrict__ patch)
{
    int idx = blockIdx.x * 256 + threadIdx.x;
    if (idx >= NTOK * 200) return;
    int d = idx % 200;
    int row = (idx / 200) % SEQ;
    int b = idx / (200 * SEQ);
    int oc = d >> 3, j = d & 7;
    float v = traw[(((size_t)b * 25 + oc) * SEQ + row) * 8 + j];
    int g = oc / 5;
    float mean = stats[(b * 5 + g) * 2];
    float rstd = stats[(b * 5 + g) * 2 + 1];
    v = (v - mean) * rstd * gn_g[oc] + gn_b[oc];
    float ge = 0.5f * v * (1.f + erff(v * 0.70710678118654752f));
    patch[idx] = ge;
}

__global__ __launch_bounds__(256) void dft_init_kernel(float* __restrict__ CS)
{
    int idx = blockIdx.x * 256 + threadIdx.x;
    if (idx >= 202 * 200) return;
    int f = idx / 200, d = idx % 200;
    int fr = (f < NFREQ) ? f : (f - NFREQ);
    int m = (fr * d) % 200;
    float ang = -6.283185307179586f * (float)m * (1.f / 200.f);
    CS[idx] = (f < NFREQ) ? cosf(ang) : sinf(ang);
}

__global__ __launch_bounds__(256) void dft_init_bf_kernel(short* __restrict__ CS)
{
    int idx = blockIdx.x * 256 + threadIdx.x;
    if (idx >= 202 * 224) return;
    int f = idx / 224, d = idx - f * 224;
    short out = 0;
    if (d < 200) {
        int fr = (f < NFREQ) ? f : (f - NFREQ);
        int m = (fr * d) % 200;
        float ang = -6.283185307179586f * (float)m * (1.f / 200.f);
        out = f2bf((f < NFREQ) ? cosf(ang) : sinf(ang));
    }
    CS[idx] = out;
}

__global__ __launch_bounds__(256) void mag_kernel(
    const float* __restrict__ cs_out, float* __restrict__ magv)
{
    int idx = blockIdx.x * 256 + threadIdx.x;
    if (idx >= NTOK * NFREQ) return;
    int m = idx / NFREQ, f = idx % NFREQ;
    float re = cs_out[(size_t)m * 202 + f];
    float im = cs_out[(size_t)m * 202 + NFREQ + f];
    magv[idx] = sqrtf(re * re + im * im) * 0.005f;
}

__global__ __launch_bounds__(256) void mag_bf_kernel(
    const float* __restrict__ cs_out, short* __restrict__ magv)
{
    int idx = blockIdx.x * 256 + threadIdx.x;
    if (idx >= NTOK * 128) return;
    int m = idx >> 7, f = idx & 127;
    short out = 0;
    if (f < NFREQ) {
        float re = cs_out[(size_t)m * 202 + f];
        float im = cs_out[(size_t)m * 202 + NFREQ + f];
        out = f2bf(sqrtf(re * re + im * im) * 0.005f);
    }
    magv[idx] = out;
}

// ---------------------------------------------------------------------------
// depthwise 7x7 pos conv + residual. block = (b, 16-d slice, 4-c tile+halo)
__global__ __launch_bounds__(256) void pe_conv3_kernel(
    const float* __restrict__ patch, const float* __restrict__ pw,
    float* __restrict__ hidden)
{
    int b = blockIdx.x, dc = blockIdx.y, ct = blockIdx.z;
    int d0 = dc * 16, c0 = ct * 4;
    __shared__ float pl[10 * 30 * 16];
    __shared__ float wl[49 * 16];
    int tid = threadIdx.x;
    int dd = tid & 15;
    int d = d0 + dd;

    for (int i = tid; i < 10 * 30 * 16; i += 256) {
        int ddl = i & 15, r = i >> 4;
        int l = r % 30, cr = r / 30;
        int cc = c0 + cr - 3, dl = d0 + ddl;
        pl[i] = (cc >= 0 && cc < CH && dl < 200)
                    ? patch[((size_t)(b * CH + cc) * LLEN + l) * 200 + dl] : 0.f;
    }
    for (int i = tid; i < 49 * 16; i += 256) {
        int k = i >> 4, dl = d0 + (i & 15);
        wl[i] = (dl < 200) ? pw[(size_t)dl * 49 + k] : 0.f;
    }
    __syncthreads();

    float wreg[49];
#pragma unroll
    for (int k = 0; k < 49; k++) wreg[k] = wl[k * 16 + dd];

    for (int o = tid; o < 4 * 30 * 16; o += 256) {
        int r2 = o >> 4;
        int l = r2 % 30, ci = r2 / 30;
        int c = c0 + ci;
        if (c >= CH) continue;
        float acc = pl[((ci + 3) * 30 + l) * 16 + dd];
#pragma unroll
        for (int i = 0; i < 7; i++) {
#pragma unroll
            for (int j = 0; j < 7; j++) {
                int ll = l + j - 3;
                if (ll < 0 || ll >= LLEN) continue;
                acc = fmaf(pl[((ci + i) * 30 + ll) * 16 + dd], wreg[i * 7 + j], acc);
            }
        }
        if (d < 200) hidden[((size_t)(b * CH + c) * LLEN + l) * 200 + d] = acc;
    }
}

// ---------------------------------------------------------------------------
__global__ __launch_bounds__(64) void add_rmsnorm_kernel(
    const float* __restrict__ hidden, float* __restrict__ residual,
    const float* __restrict__ wn, float* __restrict__ u,
    short* __restrict__ ubf, int first)
{
    int m = blockIdx.x;
    int lane = threadIdx.x;
    const float* hr = hidden + (size_t)m * 200;
    float* rr = residual + (size_t)m * 200;
    float v[4];
    float ss = 0.f;
#pragma unroll
    for (int i = 0; i < 4; i++) {
        int k = lane + i * 64;
        float xv = 0.f;
        if (k < 200) {
            xv = hr[k] + (first ? 0.f : rr[k]);
            rr[k] = xv;
        }
        v[i] = xv;
        ss = fmaf(xv, xv, ss);
    }
#pragma unroll
    for (int o = 32; o; o >>= 1) ss += __shfl_xor(ss, o, 64);
    float rstd = rsqrtf(ss * (1.f / 200.f) + EPS);
#pragma unroll
    for (int i = 0; i < 4; i++) {
        int k = lane + i * 64;
        float val = v[i] * rstd * ((k < 200) ? wn[k] : 0.f);
        if (k < 200 && u) u[(size_t)m * 200 + k] = val;
        if (ubf) {
            if (k < 200) ubf[(size_t)m * 224 + k] = f2bf(val);
            else if (k < 224) ubf[(size_t)m * 224 + k] = 0;
        }
    }
}

// ---------------------------------------------------------------------------
// Fused: residual += hidden; u = rmsnorm*wn -> ubf; dt GEMV fp32.
__global__ __launch_bounds__(256) void norm_dt_kernel(
    const float* __restrict__ hidden, float* __restrict__ residual,
    const float* __restrict__ wn, short* __restrict__ ubf,
    const float* __restrict__ Win, const float* __restrict__ dt_bias,
    float* __restrict__ dtb, int layer, int first)
{
    int m = blockIdx.x;
    int tid = threadIdx.x;
    __shared__ float su[200];
    __shared__ float rs[4];
    float xv = 0.f;
    if (tid < 200) {
        xv = hidden[(size_t)m * 200 + tid] + (first ? 0.f : residual[(size_t)m * 200 + tid]);
        residual[(size_t)m * 200 + tid] = xv;
    }
    float ss = xv * xv;
#pragma unroll
    for (int o = 32; o; o >>= 1) ss += __shfl_xor(ss, o, 64);
    int lane = tid & 63, w = tid >> 6;
    if (lane == 0) rs[w] = ss;
    __syncthreads();
    float rstd = rsqrtf((rs[0] + rs[1] + rs[2] + rs[3]) * (1.f / 200.f) + EPS);
    if (tid < 200) {
        float val = xv * rstd * wn[tid];
        su[tid] = val;
        ubf[(size_t)m * 224 + tid] = f2bf(val);
    } else if (tid < 224) {
        ubf[(size_t)m * 224 + tid] = 0;
    }
    __syncthreads();
    int h = tid >> 5, l = tid & 31;
    const float* wr = Win + (size_t)layer * D_IN_PROJ * 200 + (size_t)(928 + h) * 200;
    float s = 0.f;
    for (int k = l; k < 200; k += 32) s = fmaf(su[k], wr[k], s);
    s += __shfl_xor(s, 16, 32);
    s += __shfl_xor(s, 8, 32);
    s += __shfl_xor(s, 4, 32);
    s += __shfl_xor(s, 2, 32);
    s += __shfl_xor(s, 1, 32);
    if (l == 0) {
        float raw = s + dt_bias[layer * NHEADS + h];
        dtb[(size_t)m * NHEADS + h] = (raw > 20.f) ? raw : log1pf(expf(raw));
    }
}

// fp32 dt GEMV (fallback)
__global__ __launch_bounds__(256) void dt_gemv_kernel(
    const float* __restrict__ u, const float* __restrict__ Win,
    const float* __restrict__ dt_bias, float* __restrict__ dtb, int layer)
{
    int tid = threadIdx.x;
    int tok = blockIdx.x * 4 + (tid >> 6);
    int head = (tid >> 3) & 7;
    int l8 = tid & 7;
    const float* ur = u + (size_t)tok * 200;
    const float* wr = Win + (size_t)layer * D_IN_PROJ * 200 + (size_t)(928 + head) * 200;
    float s = 0.f;
    for (int k = l8; k < 200; k += 8) s = fmaf(ur[k], wr[k], s);
    s += __shfl_xor(s, 1, 64);
    s += __shfl_xor(s, 2, 64);
    s += __shfl_xor(s, 4, 64);
    if (l8 == 0) {
        float raw = s + dt_bias[layer * NHEADS + head];
        dtb[(size_t)tok * NHEADS + head] = (raw > 20.f) ? raw : log1pf(expf(raw));
    }
}

// ---------------------------------------------------------------------------
// xBC = silu(causal depthwise conv4), t-tiled
__global__ __launch_bounds__(256) void dtconv2_kernel(
    const float* __restrict__ zxbcdt, const float* __restrict__ cw,
    const float* __restrict__ cb, float* __restrict__ xBC, int layer)
{
    int b = blockIdx.x, tt = blockIdx.y;
    int t0 = tt * 8;
    __shared__ float zs[11][528];
    const float* cwl = cw + (size_t)layer * CONV_DIM * 4;
    const float* cbl = cb + (size_t)layer * CONV_DIM;
    for (int i = threadIdx.x; i < 11 * 528; i += 256) {
        int r = i / 528, ch = i - r * 528;
        int t = t0 - 3 + r;
        zs[r][ch] = (t >= 0 && t < SEQ)
                        ? zxbcdt[(size_t)(b * SEQ + t) * D_IN_PROJ + D_INNER + ch] : 0.f;
    }
    __syncthreads();
    for (int o = threadIdx.x; o < 8 * 528; o += 256) {
        int tr = o / 528, ch = o - tr * 528;
        int t = t0 + tr;
        if (t >= SEQ) continue;
        float acc = cbl[ch];
#pragma unroll
        for (int k = 0; k < 4; k++)
            acc = fmaf(zs[tr + k][ch], cwl[ch * 4 + k], acc);
        xBC[(size_t)(b * SEQ + t) * CONV_DIM + ch] = acc / (1.f + expf(-acc));
    }
}

// ---------------------------------------------------------------------------
// Pair-unrolled SSD pass 1 (fast path, lchunk EVEN). 1 barrier / 2 steps.
__global__ __launch_bounds__(512) void ssd_state2_kernel(
    const float* __restrict__ xBC, const float* __restrict__ dtb,
    const float* __restrict__ A_log, float* __restrict__ Sbuf,
    float* __restrict__ Pd, int layer, int lchunk, int nchunk)
{
    int b = blockIdx.x, c = blockIdx.y;
    int tid = threadIdx.x;
    int h = tid >> 6, p = tid & 63;
    float A = -expf(A_log[layer * NHEADS + h]);

    __shared__ float sh[2][2][544];   // [buf][tok][x(400)|B(64)|C(64)|dt(8)|pad]
    int t0 = c * lchunk, tend = t0 + lchunk;

    {   // prologue: stage pair (t0, t0+1) into buf 0
        const float* base = xBC + (size_t)(b * SEQ + t0) * CONV_DIM;
        float ra = base[tid];
        float rb = base[512 + tid];
        float rc = (tid < 32) ? base[1024 + tid] : 0.f;
        float rdt = (tid < 16)
            ? dtb[(size_t)(b * SEQ + t0 + (tid >> 3)) * NHEADS + (tid & 7)] : 0.f;
        sh[0][0][tid] = ra;
        if (tid < 16) sh[0][0][512 + tid] = rb;
        else sh[0][1][tid - 16] = rb;
        if (tid < 32) sh[0][1][496 + tid] = rc;
        if (tid < 16) sh[0][tid >> 3][528 + (tid & 7)] = rdt;
    }
    __syncthreads();

    float s[64];
#pragma unroll
    for (int n = 0; n < 64; n++) s[n] = 0.f;
    float pacc = 1.f;

    for (int t = t0; t < tend; t += 2) {
        int buf = ((t - t0) >> 1) & 1, nb = buf ^ 1;
        float ra = 0.f, rb = 0.f, rc = 0.f, rdt = 0.f;
        bool pf = (t + 2 < tend);
        if (pf) {
            const float* base = xBC + (size_t)(b * SEQ + t + 2) * CONV_DIM;
            ra = base[tid];
            rb = base[512 + tid];
            if (tid < 32) rc = base[1024 + tid];
            if (tid < 16)
                rdt = dtb[(size_t)(b * SEQ + t + 2 + (tid >> 3)) * NHEADS + (tid & 7)];
        }
        // token t
        {
            float dtv = sh[buf][0][528 + h];
            float xp  = (p < HEADDIM) ? sh[buf][0][h * HEADDIM + p] : 0.f;
            float dA = __expf(dtv * A);
            float u  = dtv * xp;
            pacc *= dA;
            const float4* B4 = (const float4*)&sh[buf][0][D_INNER];
#pragma unroll
            for (int n4 = 0; n4 < 16; n4++) {
                float4 bq = B4[n4];
                s[4 * n4 + 0] = fmaf(s[4 * n4 + 0], dA, u * bq.x);
                s[4 * n4 + 1] = fmaf(s[4 * n4 + 1], dA, u * bq.y);
                s[4 * n4 + 2] = fmaf(s[4 * n4 + 2], dA, u * bq.z);
                s[4 * n4 + 3] = fmaf(s[4 * n4 + 3], dA, u * bq.w);
            }
        }
        // token t+1
        {
            float dtv = sh[buf][1][528 + h];
            float xp  = (p < HEADDIM) ? sh[buf][1][h * HEADDIM + p] : 0.f;
            float dA = __expf(dtv * A);
            float u  = dtv * xp;
            pacc *= dA;
            const float4* B4 = (const float4*)&sh[buf][1][D_INNER];
#pragma unroll
            for (int n4 = 0; n4 < 16; n4++) {
                float4 bq = B4[n4];
                s[4 * n4 + 0] = fmaf(s[4 * n4 + 0], dA, u * bq.x);
                s[4 * n4 + 1] = fmaf(s[4 * n4 + 1], dA, u * bq.y);
                s[4 * n4 + 2] = fmaf(s[4 * n4 + 2], dA, u * bq.z);
                s[4 * n4 + 3] = fmaf(s[4 * n4 + 3], dA, u * bq.w);
            }
        }
        if (pf) {
            sh[nb][0][tid] = ra;
            if (tid < 16) sh[nb][0][512 + tid] = rb;
            else sh[nb][1][tid - 16] = rb;
            if (tid < 32) sh[nb][1][496 + tid] = rc;
            if (tid < 16) sh[nb][tid >> 3][528 + (tid & 7)] = rdt;
        }
        __syncthreads();
    }

    if (p < HEADDIM) {
        float* Sb = Sbuf + ((size_t)((b * NHEADS + h) * nchunk + c)) * (HEADDIM * 64)
                    + p * 64;
#pragma unroll
        for (int n4 = 0; n4 < 16; n4++)
            ((float4*)Sb)[n4] = make_float4(s[4 * n4], s[4 * n4 + 1],
                                            s[4 * n4 + 2], s[4 * n4 + 3]);
    }
    if (p == 0) Pd[(b * NHEADS + h) * nchunk + c] = pacc;
}

// single-step pass 1 (fallback, any lchunk)
__global__ __launch_bounds__(512) void ssd_state_kernel(
    const float* __restrict__ xBC, const float* __restrict__ dtb,
    const float* __restrict__ A_log, float* __restrict__ Sbuf,
    float* __restrict__ Pd, int layer, int lchunk, int nchunk)
{
    int b = blockIdx.x, c = blockIdx.y;
    int tid = threadIdx.x;
    int h = tid >> 6, p = tid & 63;
    float A = -expf(A_log[layer * NHEADS + h]);

    __shared__ float sh[2][544];
    int t0 = c * lchunk, tend = t0 + lchunk;

    {
        const float* base = xBC + (size_t)(b * SEQ + t0) * CONV_DIM;
        sh[0][tid] = base[tid];
        if (tid < 24) {
            int e2 = 512 + tid;
            sh[0][e2] = (e2 < 528) ? base[e2]
                                   : dtb[(size_t)(b * SEQ + t0) * NHEADS + (e2 - 528)];
        }
    }
    __syncthreads();

    float s[64];
#pragma unroll
    for (int n = 0; n < 64; n++) s[n] = 0.f;
    float pacc = 1.f;

    for (int t = t0; t < tend; t++) {
        int cur = (t - t0) & 1, nxt = cur ^ 1;
        float pf0 = 0.f, pf1 = 0.f;
        if (t + 1 < tend) {
            const float* base = xBC + (size_t)(b * SEQ + t + 1) * CONV_DIM;
            pf0 = base[tid];
            if (tid < 24) {
                int e2 = 512 + tid;
                pf1 = (e2 < 528) ? base[e2]
                                 : dtb[(size_t)(b * SEQ + t + 1) * NHEADS + (e2 - 528)];
            }
        }
        float dtv = sh[cur][528 + h];
        float xp  = (p < HEADDIM) ? sh[cur][h * HEADDIM + p] : 0.f;
        float dA = __expf(dtv * A);
        float u  = dtv * xp;
        pacc *= dA;
        const float4* B4 = (const float4*)&sh[cur][D_INNER];
#pragma unroll
        for (int n4 = 0; n4 < 16; n4++) {
            float4 bq = B4[n4];
            s[4 * n4 + 0] = fmaf(s[4 * n4 + 0], dA, u * bq.x);
            s[4 * n4 + 1] = fmaf(s[4 * n4 + 1], dA, u * bq.y);
            s[4 * n4 + 2] = fmaf(s[4 * n4 + 2], dA, u * bq.z);
            s[4 * n4 + 3] = fmaf(s[4 * n4 + 3], dA, u * bq.w);
        }
        if (t + 1 < tend) {
            sh[nxt][tid] = pf0;
            if (tid < 24) sh[nxt][512 + tid] = pf1;
        }
        __syncthreads();
    }

    if (p < HEADDIM) {
        float* Sb = Sbuf + ((size_t)((b * NHEADS + h) * nchunk + c)) * (HEADDIM * 64)
                    + p * 64;
#pragma unroll
        for (int n4 = 0; n4 < 16; n4++)
            ((float4*)Sb)[n4] = make_float4(s[4 * n4], s[4 * n4 + 1],
                                            s[4 * n4 + 2], s[4 * n4 + 3]);
    }
    if (p == 0) Pd[(b * NHEADS + h) * nchunk + c] = pacc;
}

__global__ __launch_bounds__(256) void ssd_scan2_kernel(
    float* __restrict__ Sbuf, const float* __restrict__ Pd, int nchunk)
{
    int bh = blockIdx.x;
    float* base = Sbuf + (size_t)bh * nchunk * (HEADDIM * 64);
    const float* pd = Pd + bh * nchunk;
    for (int e = threadIdx.x; e < HEADDIM * 64; e += 256) {
        float cur = 0.f;
        for (int c = 0; c < nchunk; c++) {
            float l = base[(size_t)c * (HEADDIM * 64) + e];
            base[(size_t)c * (HEADDIM * 64) + e] = cur;
            cur = fmaf(pd[c], cur, l);
        }
    }
}

// ---------------------------------------------------------------------------
// Pair-unrolled fused pass 3 (fast path, lchunk EVEN). 1 barrier / 2 steps.
// recurrence + D-add + gate + rmsnorm + bf16 pack -> ybf[tok][416].
__global__ __launch_bounds__(512) void ssd_out_fused2_kernel(
    const float* __restrict__ xBC, const float* __restrict__ dtb,
    const float* __restrict__ zxbcdt, const float* __restrict__ A_log,
    const float* __restrict__ Dv, const float* __restrict__ Sbuf,
    const float* __restrict__ gw, short* __restrict__ ybf,
    int layer, int lchunk, int nchunk)
{
    int b = blockIdx.x, c = blockIdx.y;
    int tid = threadIdx.x;
    int h = tid >> 6, p = tid & 63;
    float A = -expf(A_log[layer * NHEADS + h]);
    float Dh = Dv[layer * NHEADS + h];
    float gval = (p < HEADDIM) ? gw[(size_t)layer * D_INNER + h * HEADDIM + p] : 0.f;

    __shared__ float sh[2][2][544];
    __shared__ float shz[2][2][400];
    __shared__ float red[2][2][8];    // [buf][tok][head]
    int t0 = c * lchunk, tend = t0 + lchunk;

    {   // prologue: pair (t0, t0+1) -> buf 0
        const float* base = xBC + (size_t)(b * SEQ + t0) * CONV_DIM;
        float ra = base[tid];
        float rb = base[512 + tid];
        float rc = (tid < 32) ? base[1024 + tid] : 0.f;
        float rdt = (tid < 16)
            ? dtb[(size_t)(b * SEQ + t0 + (tid >> 3)) * NHEADS + (tid & 7)] : 0.f;
        float rz0 = 0.f, rz1 = 0.f;
        if (tid < 400) {
            rz0 = zxbcdt[(size_t)(b * SEQ + t0) * D_IN_PROJ + tid];
            rz1 = zxbcdt[(size_t)(b * SEQ + t0 + 1) * D_IN_PROJ + tid];
        }
        sh[0][0][tid] = ra;
        if (tid < 16) sh[0][0][512 + tid] = rb;
        else sh[0][1][tid - 16] = rb;
        if (tid < 32) sh[0][1][496 + tid] = rc;
        if (tid < 16) sh[0][tid >> 3][528 + (tid & 7)] = rdt;
        if (tid < 400) { shz[0][0][tid] = rz0; shz[0][1][tid] = rz1; }
    }

    float s[64];
    if (p < HEADDIM) {
        const float* Sb = Sbuf + ((size_t)((b * NHEADS + h) * nchunk + c)) * (HEADDIM * 64)
                          + p * 64;
#pragma unroll
        for (int n4 = 0; n4 < 16; n4++) {
            float4 v = ((const float4*)Sb)[n4];
            s[4 * n4] = v.x; s[4 * n4 + 1] = v.y; s[4 * n4 + 2] = v.z; s[4 * n4 + 3] = v.w;
        }
    } else {
#pragma unroll
        for (int n = 0; n < 64; n++) s[n] = 0.f;
    }
    __syncthreads();

    for (int t = t0; t < tend; t += 2) {
        int buf = ((t - t0) >> 1) & 1, nb = buf ^ 1;
        float ra = 0.f, rb = 0.f, rc = 0.f, rdt = 0.f, rz0 = 0.f, rz1 = 0.f;
        bool pf = (t + 2 < tend);
        if (pf) {
            const float* base = xBC + (size_t)(b * SEQ + t + 2) * CONV_DIM;
            ra = base[tid];
            rb = base[512 + tid];
            if (tid < 32) rc = base[1024 + tid];
            if (tid < 16)
                rdt = dtb[(size_t)(b * SEQ + t + 2 + (tid >> 3)) * NHEADS + (tid & 7)];
            if (tid < 400) {
                rz0 = zxbcdt[(size_t)(b * SEQ + t + 2) * D_IN_PROJ + tid];
                rz1 = zxbcdt[(size_t)(b * SEQ + t + 3) * D_IN_PROJ + tid];
            }
        }
        // token t
        float g0 = 0.f;
        {
            float dtv = sh[buf][0][528 + h];
            float xp  = (p < HEADDIM) ? sh[buf][0][h * HEADDIM + p] : 0.f;
            float dA = __expf(dtv * A);
            float u  = dtv * xp;
            const float4* B4 = (const float4*)&sh[buf][0][D_INNER];
            const float4* C4 = (const float4*)&sh[buf][0][D_INNER + D_STATE];
            float y0 = 0.f, y1 = 0.f, y2 = 0.f, y3 = 0.f;
#pragma unroll
            for (int n4 = 0; n4 < 16; n4++) {
                float4 bq = B4[n4];
                float4 cq = C4[n4];
                float t0v = fmaf(s[4 * n4 + 0], dA, u * bq.x);
                float t1v = fmaf(s[4 * n4 + 1], dA, u * bq.y);
                float t2v = fmaf(s[4 * n4 + 2], dA, u * bq.z);
                float t3v = fmaf(s[4 * n4 + 3], dA, u * bq.w);
                s[4 * n4 + 0] = t0v; s[4 * n4 + 1] = t1v;
                s[4 * n4 + 2] = t2v; s[4 * n4 + 3] = t3v;
                y0 = fmaf(t0v, cq.x, y0);
                y1 = fmaf(t1v, cq.y, y1);
                y2 = fmaf(t2v, cq.z, y2);
                y3 = fmaf(t3v, cq.w, y3);
            }
            if (p < HEADDIM) {
                float yv = fmaf(xp, Dh, (y0 + y1) + (y2 + y3));
                float zv = shz[buf][0][h * HEADDIM + p];
                g0 = yv * (zv / (1.f + expf(-zv)));
            }
        }
        // token t+1
        float g1 = 0.f;
        {
            float dtv = sh[buf][1][528 + h];
            float xp  = (p < HEADDIM) ? sh[buf][1][h * HEADDIM + p] : 0.f;
            float dA = __expf(dtv * A);
            float u  = dtv * xp;
            const float4* B4 = (const float4*)&sh[buf][1][D_INNER];
            const float4* C4 = (const float4*)&sh[buf][1][D_INNER + D_STATE];
            float y0 = 0.f, y1 = 0.f, y2 = 0.f, y3 = 0.f;
#pragma unroll
            for (int n4 = 0; n4 < 16; n4++) {
                float4 bq = B4[n4];
                float4 cq = C4[n4];
                float t0v = fmaf(s[4 * n4 + 0], dA, u * bq.x);
                float t1v = fmaf(s[4 * n4 + 1], dA, u * bq.y);
                float t2v = fmaf(s[4 * n4 + 2], dA, u * bq.z);
                float t3v = fmaf(s[4 * n4 + 3], dA, u * bq.w);
                s[4 * n4 + 0] = t0v; s[4 * n4 + 1] = t1v;
                s[4 * n4 + 2] = t2v; s[4 * n4 + 3] = t3v;
                y0 = fmaf(t0v, cq.x, y0);
                y1 = fmaf(t1v, cq.y, y1);
                y2 = fmaf(t2v, cq.z, y2);
                y3 = fmaf(t3v, cq.w, y3);
            }
            if (p < HEADDIM) {
                float yv = fmaf(xp, Dh, (y0 + y1) + (y2 + y3));
                float zv = shz[buf][1][h * HEADDIM + p];
                g1 = yv * (zv / (1.f + expf(-zv)));
            }
        }
        // partial sq-sums for both tokens (independent butterflies, ILP 2)
        float gs0 = g0 * g0, gs1 = g1 * g1;
#pragma unroll
        for (int o = 32; o; o >>= 1) {
            gs0 += __shfl_xor(gs0, o, 64);
            gs1 += __shfl_xor(gs1, o, 64);
        }
        if (p == 0) { red[buf][0][h] = gs0; red[buf][1][h] = gs1; }
        // stage next pair
        if (pf) {
            sh[nb][0][tid] = ra;
            if (tid < 16) sh[nb][0][512 + tid] = rb;
            else sh[nb][1][tid - 16] = rb;
            if (tid < 32) sh[nb][1][496 + tid] = rc;
            if (tid < 16) sh[nb][tid >> 3][528 + (tid & 7)] = rdt;
            if (tid < 400) { shz[nb][0][tid] = rz0; shz[nb][1][tid] = rz1; }
        }
        __syncthreads();
        // outputs for t and t+1 (g values in regs, red[buf] now complete)
        float tot0 = (red[buf][0][0] + red[buf][0][1]) + (red[buf][0][2] + red[buf][0][3]) +
                     (red[buf][0][4] + red[buf][0][5]) + (red[buf][0][6] + red[buf][0][7]);
        float tot1 = (red[buf][1][0] + red[buf][1][1]) + (red[buf][1][2] + red[buf][1][3]) +
                     (red[buf][1][4] + red[buf][1][5]) + (red[buf][1][6] + red[buf][1][7]);
        float rstd0 = rsqrtf(tot0 * (1.f / D_INNER) + EPS);
        float rstd1 = rsqrtf(tot1 * (1.f / D_INNER) + EPS);
        size_t row0 = (size_t)(b * SEQ + t) * 416;
        size_t row1 = (size_t)(b * SEQ + t + 1) * 416;
        if (p < HEADDIM) {
            ybf[row0 + h * HEADDIM + p] = f2bf(g0 * rstd0 * gval);
            ybf[row1 + h * HEADDIM + p] = f2bf(g1 * rstd1 * gval);
        } else {
            int widx = h * 14 + (p - HEADDIM);
            if (widx < 16) {
                ybf[row0 + 400 + widx] = 0;
                ybf[row1 + 400 + widx] = 0;
            }
        }
    }
}

// Pass 3 (fallback, fp32 y out, single-step)
__global__ __launch_bounds__(512) void ssd_out_kernel(
    const float* __restrict__ xBC, const float* __restrict__ dtb,
    const float* __restrict__ A_log, const float* __restrict__ Dv,
    const float* __restrict__ Sbuf, float* __restrict__ y,
    int layer, int lchunk, int nchunk)
{
    int b = blockIdx.x, c = blockIdx.y;
    int tid = threadIdx.x;
    int h = tid >> 6, p = tid & 63;
    float A = -expf(A_log[layer * NHEADS + h]);
    float Dh = Dv[layer * NHEADS + h];

    __shared__ float sh[2][544];
    int t0 = c * lchunk, tend = t0 + lchunk;

    {
        const float* base = xBC + (size_t)(b * SEQ + t0) * CONV_DIM;
        sh[0][tid] = base[tid];
        if (tid < 24) {
            int e2 = 512 + tid;
            sh[0][e2] = (e2 < 528) ? base[e2]
                                   : dtb[(size_t)(b * SEQ + t0) * NHEADS + (e2 - 528)];
        }
    }

    float s[64];
    if (p < HEADDIM) {
        const float* Sb = Sbuf + ((size_t)((b * NHEADS + h) * nchunk + c)) * (HEADDIM * 64)
                          + p * 64;
#pragma unroll
        for (int n4 = 0; n4 < 16; n4++) {
            float4 v = ((const float4*)Sb)[n4];
            s[4 * n4] = v.x; s[4 * n4 + 1] = v.y; s[4 * n4 + 2] = v.z; s[4 * n4 + 3] = v.w;
        }
    } else {
#pragma unroll
        for (int n = 0; n < 64; n++) s[n] = 0.f;
    }
    __syncthreads();

    for (int t = t0; t < tend; t++) {
        int cur = (t - t0) & 1, nxt = cur ^ 1;
        float pf0 = 0.f, pf1 = 0.f;
        if (t + 1 < tend) {
            const float* base = xBC + (size_t)(b * SEQ + t + 1) * CONV_DIM;
            pf0 = base[tid];
            if (tid < 24) {
                int e2 = 512 + tid;
                pf1 = (e2 < 528) ? base[e2]
                                 : dtb[(size_t)(b * SEQ + t + 1) * NHEADS + (e2 - 528)];
            }
        }
        float dtv = sh[cur][528 + h];
        float xp  = (p < HEADDIM) ? sh[cur][h * HEADDIM + p] : 0.f;
        float dA = __expf(dtv * A);
        float u  = dtv * xp;
        const float4* B4 = (const float4*)&sh[cur][D_INNER];
        const float4* C4 = (const float4*)&sh[cur][D_INNER + D_STATE];
        float y0 = 0.f, y1 = 0.f, y2 = 0.f, y3 = 0.f;
#pragma unroll
        for (int n4 = 0; n4 < 16; n4++) {
            float4 bq = B4[n4];
            float4 cq = C4[n4];
            float t0v = fmaf(s[4 * n4 + 0], dA, u * bq.x);
            float t1v = fmaf(s[4 * n4 + 1], dA, u * bq.y);
            float t2v = fmaf(s[4 * n4 + 2], dA, u * bq.z);
            float t3v = fmaf(s[4 * n4 + 3], dA, u * bq.w);
            s[4 * n4 + 0] = t0v; s[4 * n4 + 1] = t1v;
            s[4 * n4 + 2] = t2v; s[4 * n4 + 3] = t3v;
            y0 = fmaf(t0v, cq.x, y0);
            y1 = fmaf(t1v, cq.y, y1);
            y2 = fmaf(t2v, cq.z, y2);
            y3 = fmaf(t3v, cq.w, y3);
        }
        if (p < HEADDIM) {
            float yv = (y0 + y1) + (y2 + y3);
            y[(size_t)(b * SEQ + t) * D_INNER + h * HEADDIM + p] = fmaf(xp, Dh, yv);
        }
        if (t + 1 < tend) {
            sh[nxt][tid] = pf0;
            if (tid < 24) sh[nxt][512 + tid] = pf1;
        }
        __syncthreads();
    }
}

// ---------------------------------------------------------------------------
// fallback gate+norm
__global__ __launch_bounds__(256) void gate_norm_kernel(
    float* __restrict__ y, const float* __restrict__ zxbcdt,
    const float* __restrict__ gw, short* __restrict__ ybf, int layer)
{
    int m = blockIdx.x;
    __shared__ float buf[D_INNER];
    __shared__ float red[4];
    const float* z = zxbcdt + (size_t)m * D_IN_PROJ;
    float* yr = y + (size_t)m * D_INNER;
    const float* gwl = gw + (size_t)layer * D_INNER;
    float ss = 0.f;
    for (int k = threadIdx.x; k < D_INNER; k += 256) {
        float zv = z[k];
        float sz = zv / (1.f + expf(-zv));
        float g = yr[k] * sz;
        buf[k] = g;
        ss = fmaf(g, g, ss);
    }
    int lane = threadIdx.x & 63, w = threadIdx.x >> 6;
#pragma unroll
    for (int o = 32; o; o >>= 1) ss += __shfl_xor(ss, o, 64);
    if (lane == 0) red[w] = ss;
    __syncthreads();
    float tot = red[0] + red[1] + red[2] + red[3];
    float rstd = rsqrtf(tot * (1.f / D_INNER) + EPS);
    for (int k = threadIdx.x; k < 416; k += 256) {
        if (k < D_INNER) {
            float v = buf[k] * rstd * gwl[k];
            yr[k] = v;
            if (ybf) ybf[(size_t)m * 416 + k] = f2bf(v);
        } else if (ybf) {
            ybf[(size_t)m * 416 + k] = 0;
        }
    }
}

// ---------------------------------------------------------------------------
extern "C" void kernel_launch(void* const* d_in, const int* in_sizes, int n_in,
                              void* d_out, int out_size, void* d_ws, size_t ws_size,
                              hipStream_t stream)
{
    const float* x         = (const float*)d_in[0];
    const float* pe_conv_w = (const float*)d_in[1];
    const float* proj_in_w = (const float*)d_in[2];
    const float* gn_g      = (const float*)d_in[3];
    const float* gn_b      = (const float*)d_in[4];
    const float* spec_w    = (const float*)d_in[5];
    const float* norm_w    = (const float*)d_in[6];
    const float* in_proj_w = (const float*)d_in[7];
    const float* conv_w    = (const float*)d_in[8];
    const float* conv_b    = (const float*)d_in[9];
    const float* dt_bias   = (const float*)d_in[10];
    const float* A_log     = (const float*)d_in[11];
    const float* Dv        = (const float*)d_in[12];
    const float* gnorm_w   = (const float*)d_in[13];
    const float* out_proj_w= (const float*)d_in[14];
    const float* norm_f_w  = (const float*)d_in[15];
    const float* head_w    = (const float*)d_in[16];
    const float* head_b    = (const float*)d_in[17];
    float* out = (float*)d_out;
    float* ws  = (float*)d_ws;

    // fp32 region (both paths)
    float* residual = ws;                       // 1,824,000
    float* hidden   = ws + 1824000;             // 1,824,000
    float* ubuf     = ws + 3648000;             // 1,824,000
    float* zxbcdt   = ws + 5472000;             // 8,536,320
    float* xBC      = ws + 14008320;            // 4,815,360
    float* dtb      = ws + 18823680;            // 72,960
    float* ybuf     = ws + 18896640;            // 3,648,000 -> ends 22,544,640

    const size_t needA = 35029088ull * sizeof(float);   // ~140.1 MB
    int fast = (ws_size >= needA) ? 1 : 0;

    int nchunk, lchunk;
    float *Sbuf, *Pd;
    short *w_in_bf = nullptr, *w_out_bf = nullptr, *w_head_bf = nullptr,
          *w_spec_bf = nullptr, *csmat_bf = nullptr, *x_bf = nullptr,
          *ubuf_bf = nullptr, *ybuf_bf = nullptr, *magb_bf = nullptr;
    if (fast) {
        nchunk = 15; lchunk = 38;               // lchunk EVEN (pair kernels)
        Sbuf = ws + 22544640;                   // 6,144,000
        Pd   = ws + 28688640;                   // 1,920
        short* pool = (short*)(ws + 28690560);
        w_in_bf   = pool;                       // 2,515,968
        w_out_bf  = pool + 2515968;             //   998,400
        w_head_bf = pool + 3514368;             //    44,800
        w_spec_bf = pool + 3559168;             //    25,600
        csmat_bf  = pool + 3584768;             //    45,248
        x_bf      = pool + 3630016;             // 2,042,880
        ubuf_bf   = pool + 5672896;             // 2,042,880
        ybuf_bf   = pool + 7715776;             // 3,793,920
        magb_bf   = pool + 11509696;            // 1,167,360
    } else {
        nchunk = 6; lchunk = 95;
        Sbuf = ws + 1824000;
        Pd   = ws + 5470000;
    }

    // pre-layer aliases (dead layer buffers)
    float* traw  = ybuf;
    float* patch = zxbcdt;
    float* csmat = xBC;
    float* csout = xBC + 50000;
    float* magb  = xBC + 2000000;
    float* stats = dtb;

    // ---- weight / input casts (fast) ----
    if (fast) {
        cast_pad_kernel<<<(12 * 936 * 224 + 255) / 256, 256, 0, stream>>>(
            in_proj_w, w_in_bf, 12 * 936, 200, 224);
        cast_pad_kernel<<<(12 * 200 * 416 + 255) / 256, 256, 0, stream>>>(
            out_proj_w, w_out_bf, 12 * 200, 400, 416);
        cast_pad_kernel<<<(200 * 224 + 255) / 256, 256, 0, stream>>>(
            head_w, w_head_bf, 200, 200, 224);
        cast_pad_kernel<<<(200 * 128 + 255) / 256, 256, 0, stream>>>(
            spec_w, w_spec_bf, 200, 101, 128);
        cast_pad_kernel<<<(9120 * 224 + 255) / 256, 256, 0, stream>>>(
            x, x_bf, 9120, 200, 224);
        dft_init_bf_kernel<<<(202 * 224 + 255) / 256, 256, 0, stream>>>(csmat_bf);
    } else {
        dft_init_kernel<<<(202 * 200 + 255) / 256, 256, 0, stream>>>(csmat);
    }

    // ---- patch embed ----
    time_conv_kernel<<<NTOK, 256, 0, stream>>>(x, proj_in_w, traw);
    gn_stats_kernel<<<80, 256, 0, stream>>>(traw, stats);
    gn_gelu_kernel<<<(NTOK * 200 + 255) / 256, 256, 0, stream>>>(traw, stats, gn_g, gn_b, patch);
    if (fast) {
        gemm_bf16<<<dim3(2, 72), 256, 0, stream>>>(x_bf, csmat_bf, nullptr, csout,
                                                   NTOK, 202, 224, 0);
        mag_bf_kernel<<<(NTOK * 128 + 255) / 256, 256, 0, stream>>>(csout, magb_bf);
        gemm_bf16<<<dim3(2, 72), 256, 0, stream>>>(magb_bf, w_spec_bf, nullptr, patch,
                                                   NTOK, 200, 128, 1);
    } else {
        gemm_nt<<<dim3(2, 72), 256, 0, stream>>>(x, csmat, nullptr, csout, NTOK, 202, 200, 0);
        mag_kernel<<<(NTOK * NFREQ + 255) / 256, 256, 0, stream>>>(csout, magb);
        gemm_nt<<<dim3(2, 72), 256, 0, stream>>>(magb, spec_w, nullptr, patch,
                                                 NTOK, 200, NFREQ, 1);
    }
    pe_conv3_kernel<<<dim3(16, 13, 5), 256, 0, stream>>>(patch, pe_conv_w, hidden);

    // ---- layers ----
    for (int i = 0; i < N_LAYER; i++) {
        if (fast) {
            norm_dt_kernel<<<NTOK, 256, 0, stream>>>(hidden, residual, norm_w + i * 200,
                                                     ubuf_bf, in_proj_w, dt_bias, dtb,
                                                     i, (i == 0) ? 1 : 0);
            gemm_bf16<<<dim3(8, 72), 256, 0, stream>>>(
                ubuf_bf, w_in_bf + (size_t)i * 936 * 224, nullptr, zxbcdt,
                NTOK, D_IN_PROJ, 224, 0);
        } else {
            add_rmsnorm_kernel<<<NTOK, 64, 0, stream>>>(hidden, residual, norm_w + i * 200,
                                                        ubuf, nullptr, (i == 0) ? 1 : 0);
            dt_gemv_kernel<<<NTOK / 4, 256, 0, stream>>>(ubuf, in_proj_w, dt_bias, dtb, i);
            gemm_nt<<<dim3(8, 72), 256, 0, stream>>>(
                ubuf, in_proj_w + (size_t)i * D_IN_PROJ * 200, nullptr, zxbcdt,
                NTOK, D_IN_PROJ, 200, 0);
        }
        dtconv2_kernel<<<dim3(16, 72), 256, 0, stream>>>(zxbcdt, conv_w, conv_b, xBC, i);
        {
            dim3 g(BATCH, nchunk);
            if (fast) {
                ssd_state2_kernel<<<g, 512, 0, stream>>>(xBC, dtb, A_log, Sbuf, Pd,
                                                         i, lchunk, nchunk);
                ssd_scan2_kernel<<<BATCH * NHEADS, 256, 0, stream>>>(Sbuf, Pd, nchunk);
                ssd_out_fused2_kernel<<<g, 512, 0, stream>>>(
                    xBC, dtb, zxbcdt, A_log, Dv, Sbuf, gnorm_w, ybuf_bf, i, lchunk, nchunk);
                gemm_bf16<<<dim3(2, 72), 256, 0, stream>>>(
                    ybuf_bf, w_out_bf + (size_t)i * 200 * 416, nullptr, hidden,
                    NTOK, 200, 416, 0);
            } else {
                ssd_state_kernel<<<g, 512, 0, stream>>>(xBC, dtb, A_log, Sbuf, Pd,
                                                        i, lchunk, nchunk);
                ssd_scan2_kernel<<<BATCH * NHEADS, 256, 0, stream>>>(Sbuf, Pd, nchunk);
                ssd_out_kernel<<<g, 512, 0, stream>>>(xBC, dtb, A_log, Dv, Sbuf, ybuf,
                                                      i, lchunk, nchunk);
                gate_norm_kernel<<<NTOK, 256, 0, stream>>>(ybuf, zxbcdt, gnorm_w, nullptr, i);
                gemm_nt<<<dim3(2, 72), 256, 0, stream>>>(
                    ybuf, out_proj_w + (size_t)i * 200 * D_INNER, nullptr, hidden,
                    NTOK, 200, D_INNER, 0);
            }
        }
    }

    // ---- final norm + head ----
    add_rmsnorm_kernel<<<NTOK, 64, 0, stream>>>(hidden, residual, norm_f_w, ubuf,
                                                fast ? ubuf_bf : nullptr, 0);
    if (fast) {
        gemm_bf16<<<dim3(2, 72), 256, 0, stream>>>(ubuf_bf, w_head_bf, head_b, out,
                                                   NTOK, 200, 224, 0);
    } else {
        gemm_nt<<<dim3(2, 72), 256, 0, stream>>>(ubuf, head_w, head_b, out,
                                                 NTOK, 200, 200, 0);
    }
}